// Round 1
// baseline (6777.585 us; speedup 1.0000x reference)
//
#include <hip/hip_runtime.h>
#include <hip/hip_bf16.h>

#define D_   256
#define NH_  8
#define NL_  4
#define NP_  4
#define DFF_ 1024
#define BS_  8
#define NQ_  900
#define HD_  32
#define LS_  13294

static const int NE   = BS_ * NQ_ * D_;   // 1,843,200
static const int NEb  = NQ_ * D_;         //   230,400
static const int AWb  = NQ_ * 128;        //   115,200

typedef __hip_bfloat16 bf16;

__device__ __forceinline__ float to_f(bf16 x) { return __bfloat162float(x); }
__device__ __forceinline__ float ld(const void* p, size_t i, int f32) {
    return f32 ? ((const float*)p)[i] : __bfloat162float(((const bf16*)p)[i]);
}
__device__ __forceinline__ void st_out(void* p, size_t i, int f32, float v) {
    if (f32) ((float*)p)[i] = v;
    else ((bf16*)p)[i] = __float2bfloat16(v);
}

// ---------------------------------------------------------------- dtype probe
__global__ __launch_bounds__(256) void probe_kernel(const unsigned short* __restrict__ t,
                                                    int* __restrict__ flag) {
    __shared__ int c;
    if (threadIdx.x == 0) c = 0;
    __syncthreads();
    unsigned short v = t[2 * threadIdx.x];   // even bf16-view slots
    int e = (v >> 7) & 0xFF;
    if (e < 90 || e > 140) atomicAdd(&c, 1); // implausible exponent for N(0,1)
    __syncthreads();
    if (threadIdx.x == 0) flag[0] = (c > 64) ? 1 : 0;  // 1 => storage is f32
}

// ---------------------------------------------------------------- prep: qps = tgt + qpos
__global__ __launch_bounds__(256) void prep_kernel(const void* __restrict__ tgt,
                                                   const void* __restrict__ qpos,
                                                   size_t ebase,
                                                   bf16* __restrict__ qps,
                                                   const int* __restrict__ flag) {
    int f = *flag;
    int e = blockIdx.x * 256 + threadIdx.x;
    qps[e] = __float2bfloat16(ld(tgt, ebase + e, f) + ld(qpos, ebase + e, f));
}

// ---------------------------------------------------------------- GEMM: C[M,N] = A[M,K] @ W[N,K]^T + bias
// a_dyn: 0 = A ws bf16; 1 = A external flag-typed; 2 = A ws f32.  aeb = element base for A.
template <bool RELU>
__global__ __launch_bounds__(256) void gemm_kernel(const void* __restrict__ A, int a_dyn, size_t aeb,
                                                   const void* __restrict__ W,
                                                   const void* __restrict__ bias,
                                                   void* __restrict__ C, int c_f32,
                                                   int M, int N, int K,
                                                   const int* __restrict__ flag) {
    __shared__ float As[16][65];
    __shared__ float Ws[16][65];
    int f = *flag;
    int a_f32 = (a_dyn == 2) || (a_dyn == 1 && f);
    int tid = threadIdx.x;
    int tx = tid & 15, ty = tid >> 4;
    int row0 = blockIdx.y * 64, col0 = blockIdx.x * 64;
    float acc[4][4] = {};
    for (int k0 = 0; k0 < K; k0 += 16) {
#pragma unroll
        for (int t = 0; t < 4; t++) {
            int e = tid + t * 256;
            int m = e >> 4, kk = e & 15;
            int gr = row0 + m;
            As[kk][m] = (gr < M) ? ld(A, aeb + (size_t)gr * K + k0 + kk, a_f32) : 0.f;
            int gc = col0 + m;  // N multiple of 64
            Ws[kk][m] = ld(W, (size_t)gc * K + k0 + kk, f);
        }
        __syncthreads();
#pragma unroll
        for (int kk = 0; kk < 16; kk++) {
            float a[4], b[4];
#pragma unroll
            for (int i = 0; i < 4; i++) a[i] = As[kk][ty + 16 * i];
#pragma unroll
            for (int j = 0; j < 4; j++) b[j] = Ws[kk][tx + 16 * j];
#pragma unroll
            for (int i = 0; i < 4; i++)
#pragma unroll
                for (int j = 0; j < 4; j++) acc[i][j] += a[i] * b[j];
        }
        __syncthreads();
    }
#pragma unroll
    for (int i = 0; i < 4; i++) {
        int r = row0 + ty + 16 * i;
        if (r >= M) continue;
#pragma unroll
        for (int j = 0; j < 4; j++) {
            int c = col0 + tx + 16 * j;
            float v = acc[i][j] + ld(bias, c, f);
            if (RELU) v = fmaxf(v, 0.f);
            if (c_f32) ((float*)C)[(size_t)r * N + c] = v;
            else ((bf16*)C)[(size_t)r * N + c] = __float2bfloat16(v);
        }
    }
}

// ---------------------------------------------------------------- attention (ws bf16; one wave per (b,h,query))
// grid = nB * H * L blocks; batch decomposed from blockIdx.
template <int HD>
__global__ __launch_bounds__(64) void attn_kernel(const bf16* __restrict__ Q,
                                                  const bf16* __restrict__ K,
                                                  const bf16* __restrict__ V,
                                                  bf16* __restrict__ O,
                                                  int H, int L, float scale) {
    int bid = blockIdx.x;
    int b = bid / (H * L);
    int rem = bid - b * H * L;
    int i = rem % L;
    int h = rem / L;
    const int dm = H * HD;
    size_t boff = (size_t)b * L * dm;
    __shared__ float qs[HD];
    __shared__ float ps[64];
    int lane = threadIdx.x;
    const bf16* qp = Q + boff + (size_t)i * dm + h * HD;
    if (lane < HD) qs[lane] = to_f(qp[lane]);
    __syncthreads();

    float m = -1e30f, s = 0.f;
    for (int j = lane; j < L; j += 64) {
        const bf16* kp = K + boff + (size_t)j * dm + h * HD;
        float dot = 0.f;
#pragma unroll
        for (int d = 0; d < HD; d++) dot += qs[d] * to_f(kp[d]);
        dot *= scale;
        float mn = fmaxf(m, dot);
        s = s * __expf(m - mn) + __expf(dot - mn);
        m = mn;
    }
#pragma unroll
    for (int o = 32; o; o >>= 1) {
        float m2 = __shfl_xor(m, o);
        float s2 = __shfl_xor(s, o);
        float mn = fmaxf(m, m2);
        s = s * __expf(m - mn) + s2 * __expf(m2 - mn);
        m = mn;
    }
    float inv_s = 1.f / s;

    float acc = 0.f;
    for (int j0 = 0; j0 < L; j0 += 64) {
        int j = j0 + lane;
        float p = 0.f;
        if (j < L) {
            const bf16* kp = K + boff + (size_t)j * dm + h * HD;
            float dot = 0.f;
#pragma unroll
            for (int d = 0; d < HD; d++) dot += qs[d] * to_f(kp[d]);
            p = __expf(dot * scale - m);
        }
        __syncthreads();
        ps[lane] = p;
        __syncthreads();
        if (lane < HD) {
            int jend = min(64, L - j0);
            const bf16* vp = V + boff + (size_t)j0 * dm + h * HD + lane;
            for (int jj = 0; jj < jend; jj++) acc += ps[jj] * to_f(vp[(size_t)jj * dm]);
        }
    }
    if (lane < HD) O[boff + (size_t)i * dm + h * HD + lane] = __float2bfloat16(acc * inv_s);
}

// ---------------------------------------------------------------- pairing
// grid = nB*NQ blocks; second[] stores GLOBAL partner row (b*NQ + j).
__global__ __launch_bounds__(64) void find_second_kernel(const void* __restrict__ gious,
                                                         const void* __restrict__ cxcys,
                                                         size_t ebase,
                                                         int* __restrict__ second,
                                                         int* __restrict__ sel,
                                                         const int* __restrict__ flag) {
    int f = *flag;
    int gi = blockIdx.x;
    int b = gi / NQ_;
    int i = gi - b * NQ_;
    size_t rb = ebase + (size_t)b * NQ_ * NQ_ + (size_t)i * NQ_;
    int lane = threadIdx.x;
    float best = -1e30f;
    int bidx = 1 << 30;
    for (int j = lane; j < NQ_; j += 64) {
        if (j == i) continue;
        float v = ld(gious, rb + j, f);
        if (v > best) { best = v; bidx = j; }
    }
#pragma unroll
    for (int o = 32; o; o >>= 1) {
        float v2 = __shfl_xor(best, o);
        int i2 = __shfl_xor(bidx, o);
        if (v2 > best || (v2 == best && i2 < bidx)) { best = v2; bidx = i2; }
    }
    if (lane == 0) {
        second[gi] = b * NQ_ + bidx;
        float c = ld(cxcys, rb - (size_t)i * NQ_ + (size_t)i * NQ_ + bidx
                              - ebase + ebase, f);  // == cxcys[ebase + b*NQ*NQ + i*NQ + bidx]
        sel[gi] = (c == 0.f) ? 1 : 0;
    }
}

__global__ __launch_bounds__(256) void build_pair_kernel(const bf16* __restrict__ X,
                                                         const bf16* __restrict__ Y,
                                                         const int* __restrict__ second,
                                                         const int* __restrict__ sel,
                                                         bf16* __restrict__ out2) {
    int e = blockIdx.x * 256 + threadIdx.x;
    int d = e & 255;
    int i = e >> 8;
    int s = sel[i];
    int j = second[i];
    bf16 a = X[(size_t)i * 256 + d];
    bf16 c = Y[(size_t)j * 256 + d];
    size_t o = (size_t)i * 512 + d;
    out2[o]       = s ? a : c;
    out2[o + 256] = s ? c : a;
}

// ---------------------------------------------------------------- block reduction (256 threads)
__device__ __forceinline__ float block_sum_256(float v, float* sm) {
#pragma unroll
    for (int o = 32; o; o >>= 1) v += __shfl_down(v, o);
    int w = threadIdx.x >> 6, lane = threadIdx.x & 63;
    if (lane == 0) sm[w] = v;
    __syncthreads();
    float r = sm[0] + sm[1] + sm[2] + sm[3];
    __syncthreads();
    return r;
}

__global__ __launch_bounds__(256) void ln_pair_kernel(const void* __restrict__ tgt,
                                                      const void* __restrict__ qpos,
                                                      size_t ebase,
                                                      const bf16* __restrict__ tgt2,
                                                      const bf16* __restrict__ tgt3full,
                                                      const int* __restrict__ sel,
                                                      const void* __restrict__ g1, const void* __restrict__ b1,
                                                      const void* __restrict__ g12, const void* __restrict__ b12,
                                                      float* __restrict__ xbuf,
                                                      bf16* __restrict__ query_d,
                                                      const int* __restrict__ flag) {
    __shared__ float sm[4];
    int f = *flag;
    int i = blockIdx.x, d = threadIdx.x;
    size_t base = (size_t)i * 256;
    float t = ld(tgt, ebase + base + d, f);
    float a1 = t + to_f(tgt2[base + d]);
    int s = sel[i];
    float t3 = to_f(tgt3full[(size_t)i * 512 + (s ? 0 : 256) + d]);
    float a2 = t + t3;
    float m1 = block_sum_256(a1, sm) * (1.f / 256.f);
    float m2 = block_sum_256(a2, sm) * (1.f / 256.f);
    float d1 = a1 - m1, d2 = a2 - m2;
    float v1 = block_sum_256(d1 * d1, sm) * (1.f / 256.f);
    float v2 = block_sum_256(d2 * d2, sm) * (1.f / 256.f);
    float o1 = d1 * rsqrtf(v1 + 1e-5f) * ld(g1, d, f) + ld(b1, d, f);
    float o2 = d2 * rsqrtf(v2 + 1e-5f) * ld(g12, d, f) + ld(b12, d, f);
    float xv = o1 + o2;
    xbuf[base + d] = xv;
    query_d[base + d] = __float2bfloat16(xv + ld(qpos, ebase + base + d, f));
}

// out_mode: 1 = ws f32 (oeb=0), 0 = d_out flag-typed at element base oeb
__global__ __launch_bounds__(256) void ln_add_kernel(const float* __restrict__ A,
                                                     const bf16* __restrict__ Badd,
                                                     const void* __restrict__ g, const void* __restrict__ be,
                                                     void* __restrict__ out, int out_mode, size_t oeb,
                                                     const int* __restrict__ flag) {
    __shared__ float sm[4];
    int f = *flag;
    int i = blockIdx.x, d = threadIdx.x;
    size_t base = (size_t)i * 256;
    float v = A[base + d] + to_f(Badd[base + d]);
    float m = block_sum_256(v, sm) * (1.f / 256.f);
    float dv = v - m;
    float var = block_sum_256(dv * dv, sm) * (1.f / 256.f);
    float o = dv * rsqrtf(var + 1e-5f) * ld(g, d, f) + ld(be, d, f);
    if (out_mode == 1) ((float*)out)[base + d] = o;
    else st_out(out, oeb + base + d, f, o);
}

// ---------------------------------------------------------------- deformable attention pieces
__global__ __launch_bounds__(128) void aw_softmax_kernel(float* __restrict__ aw,
                                                         void* __restrict__ out_aw, size_t oeb,
                                                         const int* __restrict__ flag) {
    int f = *flag;
    int i = blockIdx.x, t = threadIdx.x;
    size_t idx = (size_t)i * 128 + t;
    float v = aw[idx];
    float mx = v;
#pragma unroll
    for (int o = 8; o; o >>= 1) mx = fmaxf(mx, __shfl_xor(mx, o, 16));
    float e = __expf(v - mx);
    float s = e;
#pragma unroll
    for (int o = 8; o; o >>= 1) s += __shfl_xor(s, o, 16);
    float r = e / s;
    aw[idx] = r;
    st_out(out_aw, oeb + idx, f, r);
}

__global__ __launch_bounds__(256) void loc_kernel(const void* __restrict__ refp, size_t rbase,
                                                  const bf16* __restrict__ off,
                                                  float* __restrict__ locbuf,
                                                  void* __restrict__ out_loc, size_t oeb,
                                                  const int* __restrict__ flag) {
    int f = *flag;
    int e = blockIdx.x * 256 + threadIdx.x;  // [rows, H,L,P,2]
    int c = e & 1;
    int l = (e >> 3) & 3;
    int i = e >> 8;
    const float norm[4] = {100.f, 50.f, 25.f, 13.f};  // W == H per level
    float rv = ld(refp, rbase + ((size_t)i * 4 + l) * 2 + c, f);
    float lv = rv + to_f(off[e]) / norm[l];
    locbuf[e] = lv;
    st_out(out_loc, oeb + e, f, lv);
}

// Fused bilinear-sample + value-projection + attention-weighting.
// grid rows may span batches: b = q / NQ_ selects the src slab.
__global__ __launch_bounds__(256) void deform_fused_kernel(const void* __restrict__ src, size_t sbase,
                                                           const void* __restrict__ vw,
                                                           const void* __restrict__ vb,
                                                           const float* __restrict__ locb,
                                                           const float* __restrict__ awb,
                                                           float* __restrict__ samp,
                                                           const int* __restrict__ flag) {
    int f = *flag;
    int q = blockIdx.x;
    int b = q / NQ_;
    size_t srow = sbase + (size_t)b * LS_ * 256;
    int t = threadIdx.x;
    __shared__ float G[8][257];
    __shared__ int   rowi[128][4];
    __shared__ float wc[128][4];
    __shared__ float wv_s[128];
    __shared__ float aw_s[128];
#pragma unroll
    for (int h = 0; h < 8; h++) G[h][t] = 0.f;
    if (t < 128) {
        const int HW[4] = {100, 50, 25, 13};
        const int ST[4] = {0, 10000, 12500, 13125};
        int le = t;                       // h*16 + l*4 + p
        int l = (le >> 2) & 3;
        int W = HW[l], H = W, st = ST[l];
        float lx = locb[(size_t)q * 256 + le * 2];
        float ly = locb[(size_t)q * 256 + le * 2 + 1];
        float x = lx * W - 0.5f, y = ly * H - 0.5f;
        float xf = floorf(x), yf = floorf(y);
        int x0 = (int)xf, y0 = (int)yf;
        float wx1 = x - xf, wy1 = y - yf;
        float wx0 = 1.f - wx1, wy0 = 1.f - wy1;
        bool xv0 = (x0 >= 0) && (x0 < W), xv1 = (x0 + 1 >= 0) && (x0 + 1 < W);
        bool yv0 = (y0 >= 0) && (y0 < H), yv1 = (y0 + 1 >= 0) && (y0 + 1 < H);
        int cx0 = min(max(x0, 0), W - 1), cx1 = min(max(x0 + 1, 0), W - 1);
        int cy0 = min(max(y0, 0), H - 1), cy1 = min(max(y0 + 1, 0), H - 1);
        rowi[le][0] = st + cy0 * W + cx0;  wc[le][0] = (xv0 && yv0) ? wx0 * wy0 : 0.f;
        rowi[le][1] = st + cy0 * W + cx1;  wc[le][1] = (xv1 && yv0) ? wx1 * wy0 : 0.f;
        rowi[le][2] = st + cy1 * W + cx0;  wc[le][2] = (xv0 && yv1) ? wx0 * wy1 : 0.f;
        rowi[le][3] = st + cy1 * W + cx1;  wc[le][3] = (xv1 && yv1) ? wx1 * wy1 : 0.f;
        wv_s[le] = wc[le][0] + wc[le][1] + wc[le][2] + wc[le][3];
        aw_s[le] = awb[(size_t)q * 128 + le];
    }
    __syncthreads();
    for (int le = 0; le < 128; le++) {
        float a = aw_s[le];
        float w0 = wc[le][0], w1 = wc[le][1], w2 = wc[le][2], w3 = wc[le][3];
        float v = 0.f;
        if (w0 != 0.f) v += w0 * ld(src, srow + (size_t)rowi[le][0] * 256 + t, f);
        if (w1 != 0.f) v += w1 * ld(src, srow + (size_t)rowi[le][1] * 256 + t, f);
        if (w2 != 0.f) v += w2 * ld(src, srow + (size_t)rowi[le][2] * 256 + t, f);
        if (w3 != 0.f) v += w3 * ld(src, srow + (size_t)rowi[le][3] * 256 + t, f);
        G[le >> 4][t] += a * v;
    }
    __syncthreads();
    int c = t, h = c >> 5;
    float bscale = 0.f;
#pragma unroll
    for (int r = 0; r < 16; r++) bscale += aw_s[h * 16 + r] * wv_s[h * 16 + r];
    float acc = bscale * ld(vb, c, f);
    for (int k = 0; k < 256; k++) acc += G[h][k] * ld(vw, (size_t)c * 256 + k, f);
    samp[(size_t)q * 256 + c] = acc;
}

// ================================================================ launch
extern "C" void kernel_launch(void* const* d_in, const int* in_sizes, int n_in,
                              void* d_out, int out_size, void* d_ws, size_t ws_size,
                              hipStream_t stream) {
    (void)in_sizes; (void)n_in; (void)out_size;
    void* out = d_out;
    const dim3 blk256(256);

    // ---------------- fully-batched path (needs 55,353,856 B of ws) ----------------
    if (ws_size >= 55353856ull) {
        char* base = (char*)d_ws;
        int*   flag   = (int*)base;                           // 256 B
        float* xbuf   = (float*)(base + 256);                 // NE f32   7,372,800
        bf16*  query  = (bf16*)(base + 7373056);              // NE bf16  3,686,400
        bf16*  qps    = (bf16*)(base + 11059456);             // NE bf16
        bf16*  tgt2   = (bf16*)(base + 14745856);             // NE bf16
        int*   second = (int*)(base + 18432256);              // 28,800 B
        int*   sel    = second + BS_ * NQ_;                   // 28,800 B
        char*  A      = base + 18489856;                      // arena, peak 36,864,000 B

        const int M = BS_ * NQ_;              // 7200
        const int gy = (M + 63) / 64;         // 113

        probe_kernel<<<1, blk256, 0, stream>>>((const unsigned short*)d_in[0], flag);
        prep_kernel<<<NE / 256, blk256, 0, stream>>>(d_in[0], d_in[1], 0, qps, flag);

        // ---- stage A (arena: 4 x 3,686,400 B)
        bf16* Q1   = (bf16*)A;
        bf16* K1   = (bf16*)(A + 3686400);
        bf16* V1   = (bf16*)(A + 7372800);
        bf16* att1 = (bf16*)(A + 11059200);
        gemm_kernel<false><<<dim3(4, gy), blk256, 0, stream>>>(qps, 0, 0, d_in[8], d_in[9], Q1, 0, M, 256, 256, flag);
        gemm_kernel<false><<<dim3(4, gy), blk256, 0, stream>>>(qps, 0, 0, d_in[10], d_in[11], K1, 0, M, 256, 256, flag);
        gemm_kernel<false><<<dim3(4, gy), blk256, 0, stream>>>(d_in[0], 1, 0, d_in[12], d_in[13], V1, 0, M, 256, 256, flag);
        attn_kernel<32><<<BS_ * NH_ * NQ_, 64, 0, stream>>>(Q1, K1, V1, att1, NH_, NQ_, 0.17677669529663687f);
        gemm_kernel<false><<<dim3(4, gy), blk256, 0, stream>>>(att1, 0, 0, d_in[14], d_in[15], tgt2, 0, M, 256, 256, flag);

        // ---- stage B (arena: 4 x 7,372,800 B)
        bf16* pairX = (bf16*)A;               // then att2
        bf16* Q2    = (bf16*)(A + 7372800);   // then tgt3
        bf16* K2    = (bf16*)(A + 14745600);
        bf16* V2    = (bf16*)(A + 22118400);
        find_second_kernel<<<M, 64, 0, stream>>>(d_in[7], d_in[6], 0, second, sel, flag);
        build_pair_kernel<<<M, blk256, 0, stream>>>(qps, qps, second, sel, pairX);
        gemm_kernel<false><<<dim3(8, gy), blk256, 0, stream>>>(pairX, 0, 0, d_in[16], d_in[17], Q2, 0, M, 512, 512, flag);
        build_pair_kernel<<<M, blk256, 0, stream>>>(qps, tgt2, second, sel, pairX);
        gemm_kernel<false><<<dim3(8, gy), blk256, 0, stream>>>(pairX, 0, 0, d_in[18], d_in[19], K2, 0, M, 512, 512, flag);
        build_pair_kernel<<<M, blk256, 0, stream>>>(tgt2, tgt2, second, sel, pairX);
        gemm_kernel<false><<<dim3(8, gy), blk256, 0, stream>>>(pairX, 0, 0, d_in[20], d_in[21], V2, 0, M, 512, 512, flag);
        attn_kernel<64><<<BS_ * NH_ * NQ_, 64, 0, stream>>>(Q2, K2, V2, pairX, NH_, NQ_, 0.125f);
        gemm_kernel<false><<<dim3(8, gy), blk256, 0, stream>>>(pairX, 0, 0, d_in[22], d_in[23], Q2, 0, M, 512, 512, flag);

        ln_pair_kernel<<<M, blk256, 0, stream>>>(d_in[0], d_in[1], 0, tgt2, Q2, sel,
                                                 d_in[32], d_in[33], d_in[34], d_in[35], xbuf, query, flag);

        // ---- stage C (arena: offb | awb | locb | samp)
        bf16*  offb = (bf16*)A;                        //  3,686,400 B
        float* awb  = (float*)(A + 3686400);           //  3,686,400 B
        float* locb = (float*)(A + 7372800);           //  7,372,800 B
        float* samp = (float*)(A + 14745600);          //  7,372,800 B (lives into stage D)
        gemm_kernel<false><<<dim3(4, gy), blk256, 0, stream>>>(query, 0, 0, d_in[26], d_in[27], offb, 0, M, 256, 256, flag);
        gemm_kernel<false><<<dim3(2, gy), blk256, 0, stream>>>(query, 0, 0, d_in[28], d_in[29], awb, 1, M, 128, 256, flag);
        aw_softmax_kernel<<<M, 128, 0, stream>>>(awb, out, (size_t)2 * NE, flag);
        loc_kernel<<<M, blk256, 0, stream>>>(d_in[2], 0, offb, locb, out, (size_t)NE, flag);
        deform_fused_kernel<<<M, blk256, 0, stream>>>(d_in[3], 0, d_in[24], d_in[25], locb, awb, samp, flag);

        // ---- stage D (ca | x2 | ffn | [samp] | h1; peak arena 36,864,000 B)
        bf16*  ca  = (bf16*)A;                         //  3,686,400 B
        float* x2  = (float*)(A + 3686400);            //  7,372,800 B
        bf16*  ffn = (bf16*)(A + 11059200);            //  3,686,400 B
        bf16*  h1  = (bf16*)(A + 22118400);            // 14,745,600 B (after samp)
        gemm_kernel<false><<<dim3(4, gy), blk256, 0, stream>>>(samp, 2, 0, d_in[30], d_in[31], ca, 0, M, 256, 256, flag);
        ln_add_kernel<<<M, blk256, 0, stream>>>(xbuf, ca, d_in[32], d_in[33], x2, 1, 0, flag);
        gemm_kernel<true><<<dim3(16, gy), blk256, 0, stream>>>(x2, 2, 0, d_in[38], d_in[39], h1, 0, M, 1024, 256, flag);
        gemm_kernel<false><<<dim3(4, gy), blk256, 0, stream>>>(h1, 0, 0, d_in[40], d_in[41], ffn, 0, M, 256, 1024, flag);
        ln_add_kernel<<<M, blk256, 0, stream>>>(x2, ffn, d_in[36], d_in[37], out, 0, 0, flag);
        return;
    }

    // ---------------- fallback: per-batch loop (needs 6,920,448 B of ws) ----------------
    {
        char* base = (char*)d_ws;
        int*   flag   = (int*)base;                         // 256 B
        float* xbuf   = (float*)(base + 256);               // NEb f32   921,600 B
        bf16*  query  = (bf16*)(base + 256 + 921600);       // NEb bf16  460,800 B
        bf16*  qps    = (bf16*)(base + 256 + 1382400);      // NEb bf16
        bf16*  tgt2   = (bf16*)(base + 256 + 1843200);      // NEb bf16
        int*   second = (int*)(base + 256 + 2304000);       // 3,600 B
        int*   sel    = second + NQ_;                       // 3,600 B
        char*  A      = base + 2312448;                     // arena, peak 4,608,000 B

        const int gyb = (NQ_ + 63) / 64;   // 15

        probe_kernel<<<1, blk256, 0, stream>>>((const unsigned short*)d_in[0], flag);

        for (int b = 0; b < BS_; b++) {
            const size_t o_tgt  = (size_t)b * NEb;
            const size_t o_refp = (size_t)b * NQ_ * 8;
            const size_t o_src  = (size_t)b * LS_ * 256;
            const size_t o_gc   = (size_t)b * NQ_ * NQ_;
            const size_t o_outx = (size_t)b * NEb;
            const size_t o_loc  = (size_t)NE + (size_t)b * NEb;
            const size_t o_aw   = (size_t)2 * NE + (size_t)b * AWb;

            // ---- stage A
            bf16* Q1   = (bf16*)A;
            bf16* K1   = (bf16*)(A + 460800);
            bf16* V1   = (bf16*)(A + 921600);
            bf16* att1 = (bf16*)(A + 1382400);
            prep_kernel<<<NEb / 256, blk256, 0, stream>>>(d_in[0], d_in[1], o_tgt, qps, flag);
            gemm_kernel<false><<<dim3(4, gyb), blk256, 0, stream>>>(qps, 0, 0, d_in[8], d_in[9], Q1, 0, NQ_, 256, 256, flag);
            gemm_kernel<false><<<dim3(4, gyb), blk256, 0, stream>>>(qps, 0, 0, d_in[10], d_in[11], K1, 0, NQ_, 256, 256, flag);
            gemm_kernel<false><<<dim3(4, gyb), blk256, 0, stream>>>(d_in[0], 1, o_tgt, d_in[12], d_in[13], V1, 0, NQ_, 256, 256, flag);
            attn_kernel<32><<<NH_ * NQ_, 64, 0, stream>>>(Q1, K1, V1, att1, NH_, NQ_, 0.17677669529663687f);
            gemm_kernel<false><<<dim3(4, gyb), blk256, 0, stream>>>(att1, 0, 0, d_in[14], d_in[15], tgt2, 0, NQ_, 256, 256, flag);

            // ---- stage B
            bf16* pairX = (bf16*)A;
            bf16* Q2    = (bf16*)(A + 921600);
            bf16* K2    = (bf16*)(A + 1843200);
            bf16* V2    = (bf16*)(A + 2764800);
            find_second_kernel<<<NQ_, 64, 0, stream>>>(d_in[7], d_in[6], o_gc, second, sel, flag);
            build_pair_kernel<<<NQ_, blk256, 0, stream>>>(qps, qps, second, sel, pairX);
            gemm_kernel<false><<<dim3(8, gyb), blk256, 0, stream>>>(pairX, 0, 0, d_in[16], d_in[17], Q2, 0, NQ_, 512, 512, flag);
            build_pair_kernel<<<NQ_, blk256, 0, stream>>>(qps, tgt2, second, sel, pairX);
            gemm_kernel<false><<<dim3(8, gyb), blk256, 0, stream>>>(pairX, 0, 0, d_in[18], d_in[19], K2, 0, NQ_, 512, 512, flag);
            build_pair_kernel<<<NQ_, blk256, 0, stream>>>(tgt2, tgt2, second, sel, pairX);
            gemm_kernel<false><<<dim3(8, gyb), blk256, 0, stream>>>(pairX, 0, 0, d_in[20], d_in[21], V2, 0, NQ_, 512, 512, flag);
            attn_kernel<64><<<NH_ * NQ_, 64, 0, stream>>>(Q2, K2, V2, pairX, NH_, NQ_, 0.125f);
            gemm_kernel<false><<<dim3(8, gyb), blk256, 0, stream>>>(pairX, 0, 0, d_in[22], d_in[23], Q2, 0, NQ_, 512, 512, flag);

            ln_pair_kernel<<<NQ_, blk256, 0, stream>>>(d_in[0], d_in[1], o_tgt, tgt2, Q2, sel,
                                                       d_in[32], d_in[33], d_in[34], d_in[35], xbuf, query, flag);

            // ---- stage C
            bf16*  offb = (bf16*)A;
            float* awb  = (float*)(A + 460800);
            float* locb = (float*)(A + 921600);
            float* samp = (float*)(A + 1843200);
            gemm_kernel<false><<<dim3(4, gyb), blk256, 0, stream>>>(query, 0, 0, d_in[26], d_in[27], offb, 0, NQ_, 256, 256, flag);
            gemm_kernel<false><<<dim3(2, gyb), blk256, 0, stream>>>(query, 0, 0, d_in[28], d_in[29], awb, 1, NQ_, 128, 256, flag);
            aw_softmax_kernel<<<NQ_, 128, 0, stream>>>(awb, out, o_aw, flag);
            loc_kernel<<<NQ_, blk256, 0, stream>>>(d_in[2], o_refp, offb, locb, out, o_loc, flag);
            deform_fused_kernel<<<NQ_, blk256, 0, stream>>>(d_in[3], o_src, d_in[24], d_in[25], locb, awb, samp, flag);

            // ---- stage D
            bf16*  ca  = (bf16*)A;
            float* x2  = (float*)(A + 460800);
            bf16*  ffn = (bf16*)(A + 1382400);
            bf16*  h1  = (bf16*)(A + 2764800);
            gemm_kernel<false><<<dim3(4, gyb), blk256, 0, stream>>>(samp, 2, 0, d_in[30], d_in[31], ca, 0, NQ_, 256, 256, flag);
            ln_add_kernel<<<NQ_, blk256, 0, stream>>>(xbuf, ca, d_in[32], d_in[33], x2, 1, 0, flag);
            gemm_kernel<true><<<dim3(16, gyb), blk256, 0, stream>>>(x2, 2, 0, d_in[38], d_in[39], h1, 0, NQ_, 1024, 256, flag);
            gemm_kernel<false><<<dim3(4, gyb), blk256, 0, stream>>>(h1, 0, 0, d_in[40], d_in[41], ffn, 0, NQ_, 256, 1024, flag);
            ln_add_kernel<<<NQ_, blk256, 0, stream>>>(x2, ffn, d_in[36], d_in[37], out, 0, o_outx, flag);
        }
    }
}

// Round 2
// 3593.096 us; speedup vs baseline: 1.8863x; 1.8863x over previous
//
#include <hip/hip_runtime.h>
#include <hip/hip_bf16.h>

#define D_   256
#define NH_  8
#define NL_  4
#define NP_  4
#define DFF_ 1024
#define BS_  8
#define NQ_  900
#define HD_  32
#define LS_  13294

static const int NE   = BS_ * NQ_ * D_;   // 1,843,200
static const int NEb  = NQ_ * D_;         //   230,400
static const int AWb  = NQ_ * 128;        //   115,200

typedef __hip_bfloat16 bf16;

__device__ __forceinline__ float to_f(bf16 x) { return __bfloat162float(x); }
__device__ __forceinline__ float us_to_f(unsigned short u) {
    return __uint_as_float((unsigned)u << 16);   // bf16 -> f32 is a shift
}
__device__ __forceinline__ float ld(const void* p, size_t i, int f32) {
    return f32 ? ((const float*)p)[i] : __bfloat162float(((const bf16*)p)[i]);
}
__device__ __forceinline__ void st_out(void* p, size_t i, int f32, float v) {
    if (f32) ((float*)p)[i] = v;
    else ((bf16*)p)[i] = __float2bfloat16(v);
}

// ---------------------------------------------------------------- dtype probe
__global__ __launch_bounds__(256) void probe_kernel(const unsigned short* __restrict__ t,
                                                    int* __restrict__ flag) {
    __shared__ int c;
    if (threadIdx.x == 0) c = 0;
    __syncthreads();
    unsigned short v = t[2 * threadIdx.x];   // even bf16-view slots
    int e = (v >> 7) & 0xFF;
    if (e < 90 || e > 140) atomicAdd(&c, 1); // implausible exponent for N(0,1)
    __syncthreads();
    if (threadIdx.x == 0) flag[0] = (c > 64) ? 1 : 0;  // 1 => storage is f32
}

// ---------------------------------------------------------------- prep: qps = tgt + qpos
__global__ __launch_bounds__(256) void prep_kernel(const void* __restrict__ tgt,
                                                   const void* __restrict__ qpos,
                                                   size_t ebase,
                                                   bf16* __restrict__ qps,
                                                   const int* __restrict__ flag) {
    int f = *flag;
    int e = blockIdx.x * 256 + threadIdx.x;
    qps[e] = __float2bfloat16(ld(tgt, ebase + e, f) + ld(qpos, ebase + e, f));
}

// ---------------------------------------------------------------- GEMM: C[M,N] = A[M,K] @ W[N,K]^T + bias
// a_dyn: 0 = A ws bf16; 1 = A external flag-typed; 2 = A ws f32.  aeb = element base for A.
template <bool RELU>
__global__ __launch_bounds__(256) void gemm_kernel(const void* __restrict__ A, int a_dyn, size_t aeb,
                                                   const void* __restrict__ W,
                                                   const void* __restrict__ bias,
                                                   void* __restrict__ C, int c_f32,
                                                   int M, int N, int K,
                                                   const int* __restrict__ flag) {
    __shared__ float As[16][65];
    __shared__ float Ws[16][65];
    int f = *flag;
    int a_f32 = (a_dyn == 2) || (a_dyn == 1 && f);
    int tid = threadIdx.x;
    int tx = tid & 15, ty = tid >> 4;
    int row0 = blockIdx.y * 64, col0 = blockIdx.x * 64;
    float acc[4][4] = {};
    for (int k0 = 0; k0 < K; k0 += 16) {
#pragma unroll
        for (int t = 0; t < 4; t++) {
            int e = tid + t * 256;
            int m = e >> 4, kk = e & 15;
            int gr = row0 + m;
            As[kk][m] = (gr < M) ? ld(A, aeb + (size_t)gr * K + k0 + kk, a_f32) : 0.f;
            int gc = col0 + m;  // N multiple of 64
            Ws[kk][m] = ld(W, (size_t)gc * K + k0 + kk, f);
        }
        __syncthreads();
#pragma unroll
        for (int kk = 0; kk < 16; kk++) {
            float a[4], b[4];
#pragma unroll
            for (int i = 0; i < 4; i++) a[i] = As[kk][ty + 16 * i];
#pragma unroll
            for (int j = 0; j < 4; j++) b[j] = Ws[kk][tx + 16 * j];
#pragma unroll
            for (int i = 0; i < 4; i++)
#pragma unroll
                for (int j = 0; j < 4; j++) acc[i][j] += a[i] * b[j];
        }
        __syncthreads();
    }
#pragma unroll
    for (int i = 0; i < 4; i++) {
        int r = row0 + ty + 16 * i;
        if (r >= M) continue;
#pragma unroll
        for (int j = 0; j < 4; j++) {
            int c = col0 + tx + 16 * j;
            float v = acc[i][j] + ld(bias, c, f);
            if (RELU) v = fmaxf(v, 0.f);
            if (c_f32) ((float*)C)[(size_t)r * N + c] = v;
            else ((bf16*)C)[(size_t)r * N + c] = __float2bfloat16(v);
        }
    }
}

// ---------------------------------------------------------------- tiled flash attention
// Block: 256 threads = one (b,h) x 64-query tile. 4 lanes per query, CH=HD/4 dims/lane.
// K/V staged in LDS (f32) in 32-key tiles with coalesced ushort4 loads.
// grid: (ceil(L/64), H, nB)
template <int HD>
__global__ __launch_bounds__(256) void attn_tiled_kernel(const bf16* __restrict__ Q,
                                                         const bf16* __restrict__ K,
                                                         const bf16* __restrict__ V,
                                                         bf16* __restrict__ O,
                                                         int H, int L, float scale) {
    constexpr int CH = HD / 4;                 // dims per lane (8 or 16)
    constexpr int TK = 32;                     // keys per LDS tile
    constexpr int PER = (TK * HD) / 256;       // bf16 elems staged per thread (4 or 8)
    const int dm = H * HD;
    __shared__ float Ks[TK][HD];
    __shared__ float Vs[TK][HD];
    int tile = blockIdx.x, h = blockIdx.y, b = blockIdx.z;
    size_t hb = (size_t)b * L * dm + h * HD;   // row j of this (b,h) at hb + j*dm
    int tid = threadIdx.x;
    int lane = tid & 63, wave = tid >> 6;
    int qi = wave * 16 + (lane >> 2);          // local query 0..63
    int q = tile * 64 + qi;
    int c = (lane & 3) * CH;                   // dim chunk start
    int qrow = min(q, L - 1);
    float qreg[CH];
    {
        const bf16* qp = Q + hb + (size_t)qrow * dm + c;
#pragma unroll
        for (int d = 0; d < CH; d++) qreg[d] = to_f(qp[d]);
    }
    float m = -1e30f, s = 0.f;
    float acc[CH] = {};
    int e0 = tid * PER;
    int srow = e0 / HD, scol = e0 % HD;

    for (int j0 = 0; j0 < L; j0 += TK) {
        __syncthreads();   // protect prior-iteration reads
        {
            int gr = j0 + srow;
            if (gr >= L) gr = L - 1;           // clamp; masked in compute
            const unsigned short* kp = (const unsigned short*)(K + hb + (size_t)gr * dm + scol);
            const unsigned short* vp = (const unsigned short*)(V + hb + (size_t)gr * dm + scol);
#pragma unroll
            for (int i = 0; i < PER; i += 4) {
                ushort4 ku = *(const ushort4*)(kp + i);
                ushort4 vu = *(const ushort4*)(vp + i);
                Ks[srow][scol + i + 0] = us_to_f(ku.x);
                Ks[srow][scol + i + 1] = us_to_f(ku.y);
                Ks[srow][scol + i + 2] = us_to_f(ku.z);
                Ks[srow][scol + i + 3] = us_to_f(ku.w);
                Vs[srow][scol + i + 0] = us_to_f(vu.x);
                Vs[srow][scol + i + 1] = us_to_f(vu.y);
                Vs[srow][scol + i + 2] = us_to_f(vu.z);
                Vs[srow][scol + i + 3] = us_to_f(vu.w);
            }
        }
        __syncthreads();
#pragma unroll 4
        for (int j = 0; j < TK; j++) {
            float dt = 0.f;
#pragma unroll
            for (int d = 0; d < CH; d++) dt += qreg[d] * Ks[j][c + d];
            dt += __shfl_xor(dt, 1);
            dt += __shfl_xor(dt, 2);
            float sc = (j0 + j < L) ? dt * scale : -1e30f;
            float mn = fmaxf(m, sc);
            float corr = __expf(m - mn);
            float p = __expf(sc - mn);
            s = s * corr + p;
            m = mn;
#pragma unroll
            for (int d = 0; d < CH; d++) acc[d] = acc[d] * corr + p * Vs[j][c + d];
        }
    }
    if (q < L) {
        float inv = 1.f / s;
        bf16* op = O + hb + (size_t)q * dm + c;
#pragma unroll
        for (int d = 0; d < CH; d++) op[d] = __float2bfloat16(acc[d] * inv);
    }
}

// ---------------------------------------------------------------- pairing
// grid = nB*NQ blocks; second[] stores GLOBAL partner row (b*NQ + j).
__global__ __launch_bounds__(64) void find_second_kernel(const void* __restrict__ gious,
                                                         const void* __restrict__ cxcys,
                                                         size_t ebase,
                                                         int* __restrict__ second,
                                                         int* __restrict__ sel,
                                                         const int* __restrict__ flag) {
    int f = *flag;
    int gi = blockIdx.x;
    int b = gi / NQ_;
    int i = gi - b * NQ_;
    size_t rb = ebase + (size_t)b * NQ_ * NQ_ + (size_t)i * NQ_;
    int lane = threadIdx.x;
    float best = -1e30f;
    int bidx = 1 << 30;
    for (int j = lane; j < NQ_; j += 64) {
        if (j == i) continue;
        float v = ld(gious, rb + j, f);
        if (v > best) { best = v; bidx = j; }
    }
#pragma unroll
    for (int o = 32; o; o >>= 1) {
        float v2 = __shfl_xor(best, o);
        int i2 = __shfl_xor(bidx, o);
        if (v2 > best || (v2 == best && i2 < bidx)) { best = v2; bidx = i2; }
    }
    if (lane == 0) {
        second[gi] = b * NQ_ + bidx;
        float c = ld(cxcys, rb + bidx, f);
        sel[gi] = (c == 0.f) ? 1 : 0;
    }
}

__global__ __launch_bounds__(256) void build_pair_kernel(const bf16* __restrict__ X,
                                                         const bf16* __restrict__ Y,
                                                         const int* __restrict__ second,
                                                         const int* __restrict__ sel,
                                                         bf16* __restrict__ out2) {
    int e = blockIdx.x * 256 + threadIdx.x;
    int d = e & 255;
    int i = e >> 8;
    int s = sel[i];
    int j = second[i];
    bf16 a = X[(size_t)i * 256 + d];
    bf16 c = Y[(size_t)j * 256 + d];
    size_t o = (size_t)i * 512 + d;
    out2[o]       = s ? a : c;
    out2[o + 256] = s ? c : a;
}

// ---------------------------------------------------------------- block reduction (256 threads)
__device__ __forceinline__ float block_sum_256(float v, float* sm) {
#pragma unroll
    for (int o = 32; o; o >>= 1) v += __shfl_down(v, o);
    int w = threadIdx.x >> 6, lane = threadIdx.x & 63;
    if (lane == 0) sm[w] = v;
    __syncthreads();
    float r = sm[0] + sm[1] + sm[2] + sm[3];
    __syncthreads();
    return r;
}

__global__ __launch_bounds__(256) void ln_pair_kernel(const void* __restrict__ tgt,
                                                      const void* __restrict__ qpos,
                                                      size_t ebase,
                                                      const bf16* __restrict__ tgt2,
                                                      const bf16* __restrict__ tgt3full,
                                                      const int* __restrict__ sel,
                                                      const void* __restrict__ g1, const void* __restrict__ b1,
                                                      const void* __restrict__ g12, const void* __restrict__ b12,
                                                      float* __restrict__ xbuf,
                                                      bf16* __restrict__ query_d,
                                                      const int* __restrict__ flag) {
    __shared__ float sm[4];
    int f = *flag;
    int i = blockIdx.x, d = threadIdx.x;
    size_t base = (size_t)i * 256;
    float t = ld(tgt, ebase + base + d, f);
    float a1 = t + to_f(tgt2[base + d]);
    int s = sel[i];
    float t3 = to_f(tgt3full[(size_t)i * 512 + (s ? 0 : 256) + d]);
    float a2 = t + t3;
    float m1 = block_sum_256(a1, sm) * (1.f / 256.f);
    float m2 = block_sum_256(a2, sm) * (1.f / 256.f);
    float d1 = a1 - m1, d2 = a2 - m2;
    float v1 = block_sum_256(d1 * d1, sm) * (1.f / 256.f);
    float v2 = block_sum_256(d2 * d2, sm) * (1.f / 256.f);
    float o1 = d1 * rsqrtf(v1 + 1e-5f) * ld(g1, d, f) + ld(b1, d, f);
    float o2 = d2 * rsqrtf(v2 + 1e-5f) * ld(g12, d, f) + ld(b12, d, f);
    float xv = o1 + o2;
    xbuf[base + d] = xv;
    query_d[base + d] = __float2bfloat16(xv + ld(qpos, ebase + base + d, f));
}

// out_mode: 1 = ws f32 (oeb=0), 0 = d_out flag-typed at element base oeb
__global__ __launch_bounds__(256) void ln_add_kernel(const float* __restrict__ A,
                                                     const bf16* __restrict__ Badd,
                                                     const void* __restrict__ g, const void* __restrict__ be,
                                                     void* __restrict__ out, int out_mode, size_t oeb,
                                                     const int* __restrict__ flag) {
    __shared__ float sm[4];
    int f = *flag;
    int i = blockIdx.x, d = threadIdx.x;
    size_t base = (size_t)i * 256;
    float v = A[base + d] + to_f(Badd[base + d]);
    float m = block_sum_256(v, sm) * (1.f / 256.f);
    float dv = v - m;
    float var = block_sum_256(dv * dv, sm) * (1.f / 256.f);
    float o = dv * rsqrtf(var + 1e-5f) * ld(g, d, f) + ld(be, d, f);
    if (out_mode == 1) ((float*)out)[base + d] = o;
    else st_out(out, oeb + base + d, f, o);
}

// ---------------------------------------------------------------- deformable attention pieces
__global__ __launch_bounds__(128) void aw_softmax_kernel(float* __restrict__ aw,
                                                         void* __restrict__ out_aw, size_t oeb,
                                                         const int* __restrict__ flag) {
    int f = *flag;
    int i = blockIdx.x, t = threadIdx.x;
    size_t idx = (size_t)i * 128 + t;
    float v = aw[idx];
    float mx = v;
#pragma unroll
    for (int o = 8; o; o >>= 1) mx = fmaxf(mx, __shfl_xor(mx, o, 16));
    float e = __expf(v - mx);
    float s = e;
#pragma unroll
    for (int o = 8; o; o >>= 1) s += __shfl_xor(s, o, 16);
    float r = e / s;
    aw[idx] = r;
    st_out(out_aw, oeb + idx, f, r);
}

__global__ __launch_bounds__(256) void loc_kernel(const void* __restrict__ refp, size_t rbase,
                                                  const bf16* __restrict__ off,
                                                  float* __restrict__ locbuf,
                                                  void* __restrict__ out_loc, size_t oeb,
                                                  const int* __restrict__ flag) {
    int f = *flag;
    int e = blockIdx.x * 256 + threadIdx.x;  // [rows, H,L,P,2]
    int c = e & 1;
    int l = (e >> 3) & 3;
    int i = e >> 8;
    const float norm[4] = {100.f, 50.f, 25.f, 13.f};  // W == H per level
    float rv = ld(refp, rbase + ((size_t)i * 4 + l) * 2 + c, f);
    float lv = rv + to_f(off[e]) / norm[l];
    locbuf[e] = lv;
    st_out(out_loc, oeb + e, f, lv);
}

// Fused bilinear-sample + value-projection + attention-weighting.
// grid rows may span batches: b = q / NQ_ selects the src slab.
__global__ __launch_bounds__(256) void deform_fused_kernel(const void* __restrict__ src, size_t sbase,
                                                           const void* __restrict__ vw,
                                                           const void* __restrict__ vb,
                                                           const float* __restrict__ locb,
                                                           const float* __restrict__ awb,
                                                           float* __restrict__ samp,
                                                           const int* __restrict__ flag) {
    int f = *flag;
    int q = blockIdx.x;
    int b = q / NQ_;
    size_t srow = sbase + (size_t)b * LS_ * 256;
    int t = threadIdx.x;
    __shared__ float G[8][257];
    __shared__ int   rowi[128][4];
    __shared__ float wc[128][4];
    __shared__ float wv_s[128];
    __shared__ float aw_s[128];
#pragma unroll
    for (int h = 0; h < 8; h++) G[h][t] = 0.f;
    if (t < 128) {
        const int HW[4] = {100, 50, 25, 13};
        const int ST[4] = {0, 10000, 12500, 13125};
        int le = t;                       // h*16 + l*4 + p
        int l = (le >> 2) & 3;
        int W = HW[l], H = W, st = ST[l];
        float lx = locb[(size_t)q * 256 + le * 2];
        float ly = locb[(size_t)q * 256 + le * 2 + 1];
        float x = lx * W - 0.5f, y = ly * H - 0.5f;
        float xf = floorf(x), yf = floorf(y);
        int x0 = (int)xf, y0 = (int)yf;
        float wx1 = x - xf, wy1 = y - yf;
        float wx0 = 1.f - wx1, wy0 = 1.f - wy1;
        bool xv0 = (x0 >= 0) && (x0 < W), xv1 = (x0 + 1 >= 0) && (x0 + 1 < W);
        bool yv0 = (y0 >= 0) && (y0 < H), yv1 = (y0 + 1 >= 0) && (y0 + 1 < H);
        int cx0 = min(max(x0, 0), W - 1), cx1 = min(max(x0 + 1, 0), W - 1);
        int cy0 = min(max(y0, 0), H - 1), cy1 = min(max(y0 + 1, 0), H - 1);
        rowi[le][0] = st + cy0 * W + cx0;  wc[le][0] = (xv0 && yv0) ? wx0 * wy0 : 0.f;
        rowi[le][1] = st + cy0 * W + cx1;  wc[le][1] = (xv1 && yv0) ? wx1 * wy0 : 0.f;
        rowi[le][2] = st + cy1 * W + cx0;  wc[le][2] = (xv0 && yv1) ? wx0 * wy1 : 0.f;
        rowi[le][3] = st + cy1 * W + cx1;  wc[le][3] = (xv1 && yv1) ? wx1 * wy1 : 0.f;
        wv_s[le] = wc[le][0] + wc[le][1] + wc[le][2] + wc[le][3];
        aw_s[le] = awb[(size_t)q * 128 + le];
    }
    __syncthreads();
    for (int le = 0; le < 128; le++) {
        float a = aw_s[le];
        float w0 = wc[le][0], w1 = wc[le][1], w2 = wc[le][2], w3 = wc[le][3];
        float v = 0.f;
        if (w0 != 0.f) v += w0 * ld(src, srow + (size_t)rowi[le][0] * 256 + t, f);
        if (w1 != 0.f) v += w1 * ld(src, srow + (size_t)rowi[le][1] * 256 + t, f);
        if (w2 != 0.f) v += w2 * ld(src, srow + (size_t)rowi[le][2] * 256 + t, f);
        if (w3 != 0.f) v += w3 * ld(src, srow + (size_t)rowi[le][3] * 256 + t, f);
        G[le >> 4][t] += a * v;
    }
    __syncthreads();
    int c = t, h = c >> 5;
    float bscale = 0.f;
#pragma unroll
    for (int r = 0; r < 16; r++) bscale += aw_s[h * 16 + r] * wv_s[h * 16 + r];
    float acc = bscale * ld(vb, c, f);
    for (int k = 0; k < 256; k++) acc += G[h][k] * ld(vw, (size_t)c * 256 + k, f);
    samp[(size_t)q * 256 + c] = acc;
}

// ================================================================ launch
extern "C" void kernel_launch(void* const* d_in, const int* in_sizes, int n_in,
                              void* d_out, int out_size, void* d_ws, size_t ws_size,
                              hipStream_t stream) {
    (void)in_sizes; (void)n_in; (void)out_size;
    void* out = d_out;
    const dim3 blk256(256);
    const int nQT = (NQ_ + 63) / 64;   // 15 query tiles for attention

    // ---------------- fully-batched path (needs 55,353,856 B of ws) ----------------
    if (ws_size >= 55353856ull) {
        char* base = (char*)d_ws;
        int*   flag   = (int*)base;                           // 256 B
        float* xbuf   = (float*)(base + 256);                 // NE f32   7,372,800
        bf16*  query  = (bf16*)(base + 7373056);              // NE bf16  3,686,400
        bf16*  qps    = (bf16*)(base + 11059456);             // NE bf16
        bf16*  tgt2   = (bf16*)(base + 14745856);             // NE bf16
        int*   second = (int*)(base + 18432256);              // 28,800 B
        int*   sel    = second + BS_ * NQ_;                   // 28,800 B
        char*  A      = base + 18489856;                      // arena, peak 36,864,000 B

        const int M = BS_ * NQ_;              // 7200
        const int gy = (M + 63) / 64;         // 113

        probe_kernel<<<1, blk256, 0, stream>>>((const unsigned short*)d_in[0], flag);
        prep_kernel<<<NE / 256, blk256, 0, stream>>>(d_in[0], d_in[1], 0, qps, flag);

        // ---- stage A (arena: 4 x 3,686,400 B)
        bf16* Q1   = (bf16*)A;
        bf16* K1   = (bf16*)(A + 3686400);
        bf16* V1   = (bf16*)(A + 7372800);
        bf16* att1 = (bf16*)(A + 11059200);
        gemm_kernel<false><<<dim3(4, gy), blk256, 0, stream>>>(qps, 0, 0, d_in[8], d_in[9], Q1, 0, M, 256, 256, flag);
        gemm_kernel<false><<<dim3(4, gy), blk256, 0, stream>>>(qps, 0, 0, d_in[10], d_in[11], K1, 0, M, 256, 256, flag);
        gemm_kernel<false><<<dim3(4, gy), blk256, 0, stream>>>(d_in[0], 1, 0, d_in[12], d_in[13], V1, 0, M, 256, 256, flag);
        attn_tiled_kernel<32><<<dim3(nQT, NH_, BS_), blk256, 0, stream>>>(Q1, K1, V1, att1, NH_, NQ_, 0.17677669529663687f);
        gemm_kernel<false><<<dim3(4, gy), blk256, 0, stream>>>(att1, 0, 0, d_in[14], d_in[15], tgt2, 0, M, 256, 256, flag);

        // ---- stage B (arena: 4 x 7,372,800 B)
        bf16* pairX = (bf16*)A;               // then att2
        bf16* Q2    = (bf16*)(A + 7372800);   // then tgt3
        bf16* K2    = (bf16*)(A + 14745600);
        bf16* V2    = (bf16*)(A + 22118400);
        find_second_kernel<<<M, 64, 0, stream>>>(d_in[7], d_in[6], 0, second, sel, flag);
        build_pair_kernel<<<M, blk256, 0, stream>>>(qps, qps, second, sel, pairX);
        gemm_kernel<false><<<dim3(8, gy), blk256, 0, stream>>>(pairX, 0, 0, d_in[16], d_in[17], Q2, 0, M, 512, 512, flag);
        build_pair_kernel<<<M, blk256, 0, stream>>>(qps, tgt2, second, sel, pairX);
        gemm_kernel<false><<<dim3(8, gy), blk256, 0, stream>>>(pairX, 0, 0, d_in[18], d_in[19], K2, 0, M, 512, 512, flag);
        build_pair_kernel<<<M, blk256, 0, stream>>>(tgt2, tgt2, second, sel, pairX);
        gemm_kernel<false><<<dim3(8, gy), blk256, 0, stream>>>(pairX, 0, 0, d_in[20], d_in[21], V2, 0, M, 512, 512, flag);
        attn_tiled_kernel<64><<<dim3(nQT, NH_, BS_), blk256, 0, stream>>>(Q2, K2, V2, pairX, NH_, NQ_, 0.125f);
        gemm_kernel<false><<<dim3(8, gy), blk256, 0, stream>>>(pairX, 0, 0, d_in[22], d_in[23], Q2, 0, M, 512, 512, flag);

        ln_pair_kernel<<<M, blk256, 0, stream>>>(d_in[0], d_in[1], 0, tgt2, Q2, sel,
                                                 d_in[32], d_in[33], d_in[34], d_in[35], xbuf, query, flag);

        // ---- stage C (arena: offb | awb | locb | samp)
        bf16*  offb = (bf16*)A;                        //  3,686,400 B
        float* awb  = (float*)(A + 3686400);           //  3,686,400 B
        float* locb = (float*)(A + 7372800);           //  7,372,800 B
        float* samp = (float*)(A + 14745600);          //  7,372,800 B (lives into stage D)
        gemm_kernel<false><<<dim3(4, gy), blk256, 0, stream>>>(query, 0, 0, d_in[26], d_in[27], offb, 0, M, 256, 256, flag);
        gemm_kernel<false><<<dim3(2, gy), blk256, 0, stream>>>(query, 0, 0, d_in[28], d_in[29], awb, 1, M, 128, 256, flag);
        aw_softmax_kernel<<<M, 128, 0, stream>>>(awb, out, (size_t)2 * NE, flag);
        loc_kernel<<<M, blk256, 0, stream>>>(d_in[2], 0, offb, locb, out, (size_t)NE, flag);
        deform_fused_kernel<<<M, blk256, 0, stream>>>(d_in[3], 0, d_in[24], d_in[25], locb, awb, samp, flag);

        // ---- stage D (ca | x2 | ffn | [samp] | h1; peak arena 36,864,000 B)
        bf16*  ca  = (bf16*)A;                         //  3,686,400 B
        float* x2  = (float*)(A + 3686400);            //  7,372,800 B
        bf16*  ffn = (bf16*)(A + 11059200);            //  3,686,400 B
        bf16*  h1  = (bf16*)(A + 22118400);            // 14,745,600 B (after samp)
        gemm_kernel<false><<<dim3(4, gy), blk256, 0, stream>>>(samp, 2, 0, d_in[30], d_in[31], ca, 0, M, 256, 256, flag);
        ln_add_kernel<<<M, blk256, 0, stream>>>(xbuf, ca, d_in[32], d_in[33], x2, 1, 0, flag);
        gemm_kernel<true><<<dim3(16, gy), blk256, 0, stream>>>(x2, 2, 0, d_in[38], d_in[39], h1, 0, M, 1024, 256, flag);
        gemm_kernel<false><<<dim3(4, gy), blk256, 0, stream>>>(h1, 0, 0, d_in[40], d_in[41], ffn, 0, M, 256, 1024, flag);
        ln_add_kernel<<<M, blk256, 0, stream>>>(x2, ffn, d_in[36], d_in[37], out, 0, 0, flag);
        return;
    }

    // ---------------- fallback: per-batch loop (needs 6,920,448 B of ws) ----------------
    {
        char* base = (char*)d_ws;
        int*   flag   = (int*)base;                         // 256 B
        float* xbuf   = (float*)(base + 256);               // NEb f32   921,600 B
        bf16*  query  = (bf16*)(base + 256 + 921600);       // NEb bf16  460,800 B
        bf16*  qps    = (bf16*)(base + 256 + 1382400);      // NEb bf16
        bf16*  tgt2   = (bf16*)(base + 256 + 1843200);      // NEb bf16
        int*   second = (int*)(base + 256 + 2304000);       // 3,600 B
        int*   sel    = second + NQ_;                       // 3,600 B
        char*  A      = base + 2312448;                     // arena, peak 4,608,000 B

        const int gyb = (NQ_ + 63) / 64;   // 15

        probe_kernel<<<1, blk256, 0, stream>>>((const unsigned short*)d_in[0], flag);

        for (int b = 0; b < BS_; b++) {
            const size_t o_tgt  = (size_t)b * NEb;
            const size_t o_refp = (size_t)b * NQ_ * 8;
            const size_t o_src  = (size_t)b * LS_ * 256;
            const size_t o_gc   = (size_t)b * NQ_ * NQ_;
            const size_t o_outx = (size_t)b * NEb;
            const size_t o_loc  = (size_t)NE + (size_t)b * NEb;
            const size_t o_aw   = (size_t)2 * NE + (size_t)b * AWb;

            // ---- stage A
            bf16* Q1   = (bf16*)A;
            bf16* K1   = (bf16*)(A + 460800);
            bf16* V1   = (bf16*)(A + 921600);
            bf16* att1 = (bf16*)(A + 1382400);
            prep_kernel<<<NEb / 256, blk256, 0, stream>>>(d_in[0], d_in[1], o_tgt, qps, flag);
            gemm_kernel<false><<<dim3(4, gyb), blk256, 0, stream>>>(qps, 0, 0, d_in[8], d_in[9], Q1, 0, NQ_, 256, 256, flag);
            gemm_kernel<false><<<dim3(4, gyb), blk256, 0, stream>>>(qps, 0, 0, d_in[10], d_in[11], K1, 0, NQ_, 256, 256, flag);
            gemm_kernel<false><<<dim3(4, gyb), blk256, 0, stream>>>(d_in[0], 1, o_tgt, d_in[12], d_in[13], V1, 0, NQ_, 256, 256, flag);
            attn_tiled_kernel<32><<<dim3(gyb, NH_, 1), blk256, 0, stream>>>(Q1, K1, V1, att1, NH_, NQ_, 0.17677669529663687f);
            gemm_kernel<false><<<dim3(4, gyb), blk256, 0, stream>>>(att1, 0, 0, d_in[14], d_in[15], tgt2, 0, NQ_, 256, 256, flag);

            // ---- stage B
            bf16* pairX = (bf16*)A;
            bf16* Q2    = (bf16*)(A + 921600);
            bf16* K2    = (bf16*)(A + 1843200);
            bf16* V2    = (bf16*)(A + 2764800);
            find_second_kernel<<<NQ_, 64, 0, stream>>>(d_in[7], d_in[6], o_gc, second, sel, flag);
            build_pair_kernel<<<NQ_, blk256, 0, stream>>>(qps, qps, second, sel, pairX);
            gemm_kernel<false><<<dim3(8, gyb), blk256, 0, stream>>>(pairX, 0, 0, d_in[16], d_in[17], Q2, 0, NQ_, 512, 512, flag);
            build_pair_kernel<<<NQ_, blk256, 0, stream>>>(qps, tgt2, second, sel, pairX);
            gemm_kernel<false><<<dim3(8, gyb), blk256, 0, stream>>>(pairX, 0, 0, d_in[18], d_in[19], K2, 0, NQ_, 512, 512, flag);
            build_pair_kernel<<<NQ_, blk256, 0, stream>>>(tgt2, tgt2, second, sel, pairX);
            gemm_kernel<false><<<dim3(8, gyb), blk256, 0, stream>>>(pairX, 0, 0, d_in[20], d_in[21], V2, 0, NQ_, 512, 512, flag);
            attn_tiled_kernel<64><<<dim3(gyb, NH_, 1), blk256, 0, stream>>>(Q2, K2, V2, pairX, NH_, NQ_, 0.125f);
            gemm_kernel<false><<<dim3(8, gyb), blk256, 0, stream>>>(pairX, 0, 0, d_in[22], d_in[23], Q2, 0, NQ_, 512, 512, flag);

            ln_pair_kernel<<<NQ_, blk256, 0, stream>>>(d_in[0], d_in[1], o_tgt, tgt2, Q2, sel,
                                                       d_in[32], d_in[33], d_in[34], d_in[35], xbuf, query, flag);

            // ---- stage C
            bf16*  offb = (bf16*)A;
            float* awb  = (float*)(A + 460800);
            float* locb = (float*)(A + 921600);
            float* samp = (float*)(A + 1843200);
            gemm_kernel<false><<<dim3(4, gyb), blk256, 0, stream>>>(query, 0, 0, d_in[26], d_in[27], offb, 0, NQ_, 256, 256, flag);
            gemm_kernel<false><<<dim3(2, gyb), blk256, 0, stream>>>(query, 0, 0, d_in[28], d_in[29], awb, 1, NQ_, 128, 256, flag);
            aw_softmax_kernel<<<NQ_, 128, 0, stream>>>(awb, out, o_aw, flag);
            loc_kernel<<<NQ_, blk256, 0, stream>>>(d_in[2], o_refp, offb, locb, out, o_loc, flag);
            deform_fused_kernel<<<NQ_, blk256, 0, stream>>>(d_in[3], o_src, d_in[24], d_in[25], locb, awb, samp, flag);

            // ---- stage D
            bf16*  ca  = (bf16*)A;
            float* x2  = (float*)(A + 460800);
            bf16*  ffn = (bf16*)(A + 1382400);
            bf16*  h1  = (bf16*)(A + 2764800);
            gemm_kernel<false><<<dim3(4, gyb), blk256, 0, stream>>>(samp, 2, 0, d_in[30], d_in[31], ca, 0, NQ_, 256, 256, flag);
            ln_add_kernel<<<NQ_, blk256, 0, stream>>>(xbuf, ca, d_in[32], d_in[33], x2, 1, 0, flag);
            gemm_kernel<true><<<dim3(16, gyb), blk256, 0, stream>>>(x2, 2, 0, d_in[38], d_in[39], h1, 0, NQ_, 1024, 256, flag);
            gemm_kernel<false><<<dim3(4, gyb), blk256, 0, stream>>>(h1, 0, 0, d_in[40], d_in[41], ffn, 0, NQ_, 256, 1024, flag);
            ln_add_kernel<<<NQ_, blk256, 0, stream>>>(x2, ffn, d_in[36], d_in[37], out, 0, o_outx, flag);
        }
    }
}

// Round 3
// 2367.228 us; speedup vs baseline: 2.8631x; 1.5178x over previous
//
#include <hip/hip_runtime.h>
#include <hip/hip_bf16.h>

#define D_   256
#define NH_  8
#define NL_  4
#define NP_  4
#define DFF_ 1024
#define BS_  8
#define NQ_  900
#define HD_  32
#define LS_  13294

static const int NE   = BS_ * NQ_ * D_;   // 1,843,200
static const int NEb  = NQ_ * D_;         //   230,400
static const int AWb  = NQ_ * 128;        //   115,200

typedef __hip_bfloat16 bf16;

__device__ __forceinline__ float to_f(bf16 x) { return __bfloat162float(x); }
__device__ __forceinline__ float us_to_f(unsigned short u) {
    return __uint_as_float((unsigned)u << 16);   // bf16 -> f32 is a shift
}
__device__ __forceinline__ float ld(const void* p, size_t i, int f32) {
    return f32 ? ((const float*)p)[i] : __bfloat162float(((const bf16*)p)[i]);
}
__device__ __forceinline__ void st_out(void* p, size_t i, int f32, float v) {
    if (f32) ((float*)p)[i] = v;
    else ((bf16*)p)[i] = __float2bfloat16(v);
}

// ---------------------------------------------------------------- dtype probe
__global__ __launch_bounds__(256) void probe_kernel(const unsigned short* __restrict__ t,
                                                    int* __restrict__ flag) {
    __shared__ int c;
    if (threadIdx.x == 0) c = 0;
    __syncthreads();
    unsigned short v = t[2 * threadIdx.x];   // even bf16-view slots
    int e = (v >> 7) & 0xFF;
    if (e < 90 || e > 140) atomicAdd(&c, 1); // implausible exponent for N(0,1)
    __syncthreads();
    if (threadIdx.x == 0) flag[0] = (c > 64) ? 1 : 0;  // 1 => storage is f32
}

// ---------------------------------------------------------------- prep: qps = tgt + qpos
__global__ __launch_bounds__(256) void prep_kernel(const void* __restrict__ tgt,
                                                   const void* __restrict__ qpos,
                                                   size_t ebase,
                                                   bf16* __restrict__ qps,
                                                   const int* __restrict__ flag) {
    int f = *flag;
    int e = blockIdx.x * 256 + threadIdx.x;
    qps[e] = __float2bfloat16(ld(tgt, ebase + e, f) + ld(qpos, ebase + e, f));
}

// ---------------------------------------------------------------- GEMM: C[M,N] = A[M,K] @ W[N,K]^T + bias
// a_dyn: 0 = A ws bf16; 1 = A external flag-typed; 2 = A ws f32.  aeb = element base for A.
template <bool RELU>
__global__ __launch_bounds__(256) void gemm_kernel(const void* __restrict__ A, int a_dyn, size_t aeb,
                                                   const void* __restrict__ W,
                                                   const void* __restrict__ bias,
                                                   void* __restrict__ C, int c_f32,
                                                   int M, int N, int K,
                                                   const int* __restrict__ flag) {
    __shared__ float As[16][65];
    __shared__ float Ws[16][65];
    int f = *flag;
    int a_f32 = (a_dyn == 2) || (a_dyn == 1 && f);
    int tid = threadIdx.x;
    int tx = tid & 15, ty = tid >> 4;
    int row0 = blockIdx.y * 64, col0 = blockIdx.x * 64;
    float acc[4][4] = {};
    for (int k0 = 0; k0 < K; k0 += 16) {
#pragma unroll
        for (int t = 0; t < 4; t++) {
            int e = tid + t * 256;
            int m = e >> 4, kk = e & 15;
            int gr = row0 + m;
            As[kk][m] = (gr < M) ? ld(A, aeb + (size_t)gr * K + k0 + kk, a_f32) : 0.f;
            int gc = col0 + m;  // N multiple of 64
            Ws[kk][m] = ld(W, (size_t)gc * K + k0 + kk, f);
        }
        __syncthreads();
#pragma unroll
        for (int kk = 0; kk < 16; kk++) {
            float a[4], b[4];
#pragma unroll
            for (int i = 0; i < 4; i++) a[i] = As[kk][ty + 16 * i];
#pragma unroll
            for (int j = 0; j < 4; j++) b[j] = Ws[kk][tx + 16 * j];
#pragma unroll
            for (int i = 0; i < 4; i++)
#pragma unroll
                for (int j = 0; j < 4; j++) acc[i][j] += a[i] * b[j];
        }
        __syncthreads();
    }
#pragma unroll
    for (int i = 0; i < 4; i++) {
        int r = row0 + ty + 16 * i;
        if (r >= M) continue;
#pragma unroll
        for (int j = 0; j < 4; j++) {
            int c = col0 + tx + 16 * j;
            float v = acc[i][j] + ld(bias, c, f);
            if (RELU) v = fmaxf(v, 0.f);
            if (c_f32) ((float*)C)[(size_t)r * N + c] = v;
            else ((bf16*)C)[(size_t)r * N + c] = __float2bfloat16(v);
        }
    }
}

// ---------------------------------------------------------------- tiled flash attention
// Block: 256 threads = one (b,h) x 64-query tile. 4 lanes per query, CH=HD/4 dims/lane.
// K/V staged in LDS (f32) in 32-key tiles with coalesced ushort4 loads.
// grid: (ceil(L/64), H, nB)
template <int HD>
__global__ __launch_bounds__(256) void attn_tiled_kernel(const bf16* __restrict__ Q,
                                                         const bf16* __restrict__ K,
                                                         const bf16* __restrict__ V,
                                                         bf16* __restrict__ O,
                                                         int H, int L, float scale) {
    constexpr int CH = HD / 4;                 // dims per lane (8 or 16)
    constexpr int TK = 32;                     // keys per LDS tile
    constexpr int PER = (TK * HD) / 256;       // bf16 elems staged per thread (4 or 8)
    const int dm = H * HD;
    __shared__ float Ks[TK][HD];
    __shared__ float Vs[TK][HD];
    int tile = blockIdx.x, h = blockIdx.y, b = blockIdx.z;
    size_t hb = (size_t)b * L * dm + h * HD;   // row j of this (b,h) at hb + j*dm
    int tid = threadIdx.x;
    int lane = tid & 63, wave = tid >> 6;
    int qi = wave * 16 + (lane >> 2);          // local query 0..63
    int q = tile * 64 + qi;
    int c = (lane & 3) * CH;                   // dim chunk start
    int qrow = min(q, L - 1);
    float qreg[CH];
    {
        const bf16* qp = Q + hb + (size_t)qrow * dm + c;
#pragma unroll
        for (int d = 0; d < CH; d++) qreg[d] = to_f(qp[d]);
    }
    float m = -1e30f, s = 0.f;
    float acc[CH] = {};
    int e0 = tid * PER;
    int srow = e0 / HD, scol = e0 % HD;

    for (int j0 = 0; j0 < L; j0 += TK) {
        __syncthreads();   // protect prior-iteration reads
        {
            int gr = j0 + srow;
            if (gr >= L) gr = L - 1;           // clamp; masked in compute
            const unsigned short* kp = (const unsigned short*)(K + hb + (size_t)gr * dm + scol);
            const unsigned short* vp = (const unsigned short*)(V + hb + (size_t)gr * dm + scol);
#pragma unroll
            for (int i = 0; i < PER; i += 4) {
                ushort4 ku = *(const ushort4*)(kp + i);
                ushort4 vu = *(const ushort4*)(vp + i);
                Ks[srow][scol + i + 0] = us_to_f(ku.x);
                Ks[srow][scol + i + 1] = us_to_f(ku.y);
                Ks[srow][scol + i + 2] = us_to_f(ku.z);
                Ks[srow][scol + i + 3] = us_to_f(ku.w);
                Vs[srow][scol + i + 0] = us_to_f(vu.x);
                Vs[srow][scol + i + 1] = us_to_f(vu.y);
                Vs[srow][scol + i + 2] = us_to_f(vu.z);
                Vs[srow][scol + i + 3] = us_to_f(vu.w);
            }
        }
        __syncthreads();
#pragma unroll 4
        for (int j = 0; j < TK; j++) {
            float dt = 0.f;
#pragma unroll
            for (int d = 0; d < CH; d++) dt += qreg[d] * Ks[j][c + d];
            dt += __shfl_xor(dt, 1);
            dt += __shfl_xor(dt, 2);
            float sc = (j0 + j < L) ? dt * scale : -1e30f;
            float mn = fmaxf(m, sc);
            float corr = __expf(m - mn);
            float p = __expf(sc - mn);
            s = s * corr + p;
            m = mn;
#pragma unroll
            for (int d = 0; d < CH; d++) acc[d] = acc[d] * corr + p * Vs[j][c + d];
        }
    }
    if (q < L) {
        float inv = 1.f / s;
        bf16* op = O + hb + (size_t)q * dm + c;
#pragma unroll
        for (int d = 0; d < CH; d++) op[d] = __float2bfloat16(acc[d] * inv);
    }
}

// ---------------------------------------------------------------- pairing
// grid = nB*NQ blocks; second[] stores GLOBAL partner row (b*NQ + j).
__global__ __launch_bounds__(64) void find_second_kernel(const void* __restrict__ gious,
                                                         const void* __restrict__ cxcys,
                                                         size_t ebase,
                                                         int* __restrict__ second,
                                                         int* __restrict__ sel,
                                                         const int* __restrict__ flag) {
    int f = *flag;
    int gi = blockIdx.x;
    int b = gi / NQ_;
    int i = gi - b * NQ_;
    size_t rb = ebase + (size_t)b * NQ_ * NQ_ + (size_t)i * NQ_;
    int lane = threadIdx.x;
    float best = -1e30f;
    int bidx = 1 << 30;
    for (int j = lane; j < NQ_; j += 64) {
        if (j == i) continue;
        float v = ld(gious, rb + j, f);
        if (v > best) { best = v; bidx = j; }
    }
#pragma unroll
    for (int o = 32; o; o >>= 1) {
        float v2 = __shfl_xor(best, o);
        int i2 = __shfl_xor(bidx, o);
        if (v2 > best || (v2 == best && i2 < bidx)) { best = v2; bidx = i2; }
    }
    if (lane == 0) {
        second[gi] = b * NQ_ + bidx;
        float c = ld(cxcys, rb + bidx, f);
        sel[gi] = (c == 0.f) ? 1 : 0;
    }
}

__global__ __launch_bounds__(256) void build_pair_kernel(const bf16* __restrict__ X,
                                                         const bf16* __restrict__ Y,
                                                         const int* __restrict__ second,
                                                         const int* __restrict__ sel,
                                                         bf16* __restrict__ out2) {
    int e = blockIdx.x * 256 + threadIdx.x;
    int d = e & 255;
    int i = e >> 8;
    int s = sel[i];
    int j = second[i];
    bf16 a = X[(size_t)i * 256 + d];
    bf16 c = Y[(size_t)j * 256 + d];
    size_t o = (size_t)i * 512 + d;
    out2[o]       = s ? a : c;
    out2[o + 256] = s ? c : a;
}

// ---------------------------------------------------------------- block reduction (256 threads)
__device__ __forceinline__ float block_sum_256(float v, float* sm) {
#pragma unroll
    for (int o = 32; o; o >>= 1) v += __shfl_down(v, o);
    int w = threadIdx.x >> 6, lane = threadIdx.x & 63;
    if (lane == 0) sm[w] = v;
    __syncthreads();
    float r = sm[0] + sm[1] + sm[2] + sm[3];
    __syncthreads();
    return r;
}

__global__ __launch_bounds__(256) void ln_pair_kernel(const void* __restrict__ tgt,
                                                      const void* __restrict__ qpos,
                                                      size_t ebase,
                                                      const bf16* __restrict__ tgt2,
                                                      const bf16* __restrict__ tgt3full,
                                                      const int* __restrict__ sel,
                                                      const void* __restrict__ g1, const void* __restrict__ b1,
                                                      const void* __restrict__ g12, const void* __restrict__ b12,
                                                      float* __restrict__ xbuf,
                                                      bf16* __restrict__ query_d,
                                                      const int* __restrict__ flag) {
    __shared__ float sm[4];
    int f = *flag;
    int i = blockIdx.x, d = threadIdx.x;
    size_t base = (size_t)i * 256;
    float t = ld(tgt, ebase + base + d, f);
    float a1 = t + to_f(tgt2[base + d]);
    int s = sel[i];
    float t3 = to_f(tgt3full[(size_t)i * 512 + (s ? 0 : 256) + d]);
    float a2 = t + t3;
    float m1 = block_sum_256(a1, sm) * (1.f / 256.f);
    float m2 = block_sum_256(a2, sm) * (1.f / 256.f);
    float d1 = a1 - m1, d2 = a2 - m2;
    float v1 = block_sum_256(d1 * d1, sm) * (1.f / 256.f);
    float v2 = block_sum_256(d2 * d2, sm) * (1.f / 256.f);
    float o1 = d1 * rsqrtf(v1 + 1e-5f) * ld(g1, d, f) + ld(b1, d, f);
    float o2 = d2 * rsqrtf(v2 + 1e-5f) * ld(g12, d, f) + ld(b12, d, f);
    float xv = o1 + o2;
    xbuf[base + d] = xv;
    query_d[base + d] = __float2bfloat16(xv + ld(qpos, ebase + base + d, f));
}

// out_mode: 1 = ws f32 (oeb=0), 0 = d_out flag-typed at element base oeb
__global__ __launch_bounds__(256) void ln_add_kernel(const float* __restrict__ A,
                                                     const bf16* __restrict__ Badd,
                                                     const void* __restrict__ g, const void* __restrict__ be,
                                                     void* __restrict__ out, int out_mode, size_t oeb,
                                                     const int* __restrict__ flag) {
    __shared__ float sm[4];
    int f = *flag;
    int i = blockIdx.x, d = threadIdx.x;
    size_t base = (size_t)i * 256;
    float v = A[base + d] + to_f(Badd[base + d]);
    float m = block_sum_256(v, sm) * (1.f / 256.f);
    float dv = v - m;
    float var = block_sum_256(dv * dv, sm) * (1.f / 256.f);
    float o = dv * rsqrtf(var + 1e-5f) * ld(g, d, f) + ld(be, d, f);
    if (out_mode == 1) ((float*)out)[base + d] = o;
    else st_out(out, oeb + base + d, f, o);
}

// ---------------------------------------------------------------- deformable attention pieces
__global__ __launch_bounds__(128) void aw_softmax_kernel(float* __restrict__ aw,
                                                         void* __restrict__ out_aw, size_t oeb,
                                                         const int* __restrict__ flag) {
    int f = *flag;
    int i = blockIdx.x, t = threadIdx.x;
    size_t idx = (size_t)i * 128 + t;
    float v = aw[idx];
    float mx = v;
#pragma unroll
    for (int o = 8; o; o >>= 1) mx = fmaxf(mx, __shfl_xor(mx, o, 16));
    float e = __expf(v - mx);
    float s = e;
#pragma unroll
    for (int o = 8; o; o >>= 1) s += __shfl_xor(s, o, 16);
    float r = e / s;
    aw[idx] = r;
    st_out(out_aw, oeb + idx, f, r);
}

__global__ __launch_bounds__(256) void loc_kernel(const void* __restrict__ refp, size_t rbase,
                                                  const bf16* __restrict__ off,
                                                  float* __restrict__ locbuf,
                                                  void* __restrict__ out_loc, size_t oeb,
                                                  const int* __restrict__ flag) {
    int f = *flag;
    int e = blockIdx.x * 256 + threadIdx.x;  // [rows, H,L,P,2]
    int c = e & 1;
    int l = (e >> 3) & 3;
    int i = e >> 8;
    const float norm[4] = {100.f, 50.f, 25.f, 13.f};  // W == H per level
    float rv = ld(refp, rbase + ((size_t)i * 4 + l) * 2 + c, f);
    float lv = rv + to_f(off[e]) / norm[l];
    locbuf[e] = lv;
    st_out(out_loc, oeb + e, f, lv);
}

// one-time transpose of the value-projection weight into f32 [k][c] layout
__global__ __launch_bounds__(256) void transpose_vw_kernel(const void* __restrict__ vw,
                                                           float* __restrict__ vwt,
                                                           const int* __restrict__ flag) {
    int f = *flag;
    int e = blockIdx.x * 256 + threadIdx.x;   // 65536
    int k = e >> 8, c = e & 255;
    vwt[(size_t)k * 256 + c] = ld(vw, (size_t)c * 256 + k, f);
}

// Fused bilinear-sample + value-projection + attention-weighting.
// grid rows may span batches: b = q / NQ_ selects the src slab.
// Gather accumulates in REGISTERS (h-outer loop) so global loads pipeline;
// projection reads pre-transposed vwt (coalesced, L2-resident).
__global__ __launch_bounds__(256) void deform_fused_kernel(const void* __restrict__ src, size_t sbase,
                                                           const float* __restrict__ vwt,
                                                           const void* __restrict__ vb,
                                                           const float* __restrict__ locb,
                                                           const float* __restrict__ awb,
                                                           float* __restrict__ samp,
                                                           const int* __restrict__ flag) {
    int f = *flag;
    int q = blockIdx.x;
    int b = q / NQ_;
    size_t srow = sbase + (size_t)b * LS_ * 256;
    int t = threadIdx.x;
    __shared__ float G[8][257];
    __shared__ int   rowi[128][4];
    __shared__ float wc[128][4];
    __shared__ float wv_s[128];
    __shared__ float aw_s[128];
    if (t < 128) {
        const int HW[4] = {100, 50, 25, 13};
        const int ST[4] = {0, 10000, 12500, 13125};
        int le = t;                       // h*16 + l*4 + p
        int l = (le >> 2) & 3;
        int W = HW[l], H = W, st = ST[l];
        float lx = locb[(size_t)q * 256 + le * 2];
        float ly = locb[(size_t)q * 256 + le * 2 + 1];
        float x = lx * W - 0.5f, y = ly * H - 0.5f;
        float xf = floorf(x), yf = floorf(y);
        int x0 = (int)xf, y0 = (int)yf;
        float wx1 = x - xf, wy1 = y - yf;
        float wx0 = 1.f - wx1, wy0 = 1.f - wy1;
        bool xv0 = (x0 >= 0) && (x0 < W), xv1 = (x0 + 1 >= 0) && (x0 + 1 < W);
        bool yv0 = (y0 >= 0) && (y0 < H), yv1 = (y0 + 1 >= 0) && (y0 + 1 < H);
        int cx0 = min(max(x0, 0), W - 1), cx1 = min(max(x0 + 1, 0), W - 1);
        int cy0 = min(max(y0, 0), H - 1), cy1 = min(max(y0 + 1, 0), H - 1);
        rowi[le][0] = st + cy0 * W + cx0;  wc[le][0] = (xv0 && yv0) ? wx0 * wy0 : 0.f;
        rowi[le][1] = st + cy0 * W + cx1;  wc[le][1] = (xv1 && yv0) ? wx1 * wy0 : 0.f;
        rowi[le][2] = st + cy1 * W + cx0;  wc[le][2] = (xv0 && yv1) ? wx0 * wy1 : 0.f;
        rowi[le][3] = st + cy1 * W + cx1;  wc[le][3] = (xv1 && yv1) ? wx1 * wy1 : 0.f;
        wv_s[le] = wc[le][0] + wc[le][1] + wc[le][2] + wc[le][3];
        aw_s[le] = awb[(size_t)q * 128 + le];
    }
    __syncthreads();
#pragma unroll
    for (int h = 0; h < 8; h++) {
        float g = 0.f;
#pragma unroll 4
        for (int le2 = 0; le2 < 16; le2++) {
            int le = h * 16 + le2;
            float a  = aw_s[le];
            float w0 = wc[le][0], w1 = wc[le][1], w2 = wc[le][2], w3 = wc[le][3];
            // indices are pre-clamped: unconditional loads (weight 0 kills OOB terms)
            float v = w0 * ld(src, srow + (size_t)rowi[le][0] * 256 + t, f)
                    + w1 * ld(src, srow + (size_t)rowi[le][1] * 256 + t, f)
                    + w2 * ld(src, srow + (size_t)rowi[le][2] * 256 + t, f)
                    + w3 * ld(src, srow + (size_t)rowi[le][3] * 256 + t, f);
            g += a * v;
        }
        G[h][t] = g;
    }
    __syncthreads();
    int c = t, h = c >> 5;
    float bscale = 0.f;
#pragma unroll
    for (int r = 0; r < 16; r++) bscale += aw_s[h * 16 + r] * wv_s[h * 16 + r];
    float acc = bscale * ld(vb, c, f);
#pragma unroll 8
    for (int k = 0; k < 256; k++) acc += G[h][k] * vwt[(size_t)k * 256 + c];
    samp[(size_t)q * 256 + c] = acc;
}

// ================================================================ launch
extern "C" void kernel_launch(void* const* d_in, const int* in_sizes, int n_in,
                              void* d_out, int out_size, void* d_ws, size_t ws_size,
                              hipStream_t stream) {
    (void)in_sizes; (void)n_in; (void)out_size;
    void* out = d_out;
    const dim3 blk256(256);
    const int nQT = (NQ_ + 63) / 64;   // 15 query tiles for attention

    // ---------------- fully-batched path (needs 55,353,856 B of ws) ----------------
    if (ws_size >= 55353856ull) {
        char* base = (char*)d_ws;
        int*   flag   = (int*)base;                           // 256 B
        float* xbuf   = (float*)(base + 256);                 // NE f32   7,372,800
        bf16*  query  = (bf16*)(base + 7373056);              // NE bf16  3,686,400
        bf16*  qps    = (bf16*)(base + 11059456);             // NE bf16
        bf16*  tgt2   = (bf16*)(base + 14745856);             // NE bf16
        int*   second = (int*)(base + 18432256);              // 28,800 B
        int*   sel    = second + BS_ * NQ_;                   // 28,800 B
        char*  A      = base + 18489856;                      // arena, peak 36,864,000 B

        const int M = BS_ * NQ_;              // 7200
        const int gy = (M + 63) / 64;         // 113

        probe_kernel<<<1, blk256, 0, stream>>>((const unsigned short*)d_in[0], flag);
        prep_kernel<<<NE / 256, blk256, 0, stream>>>(d_in[0], d_in[1], 0, qps, flag);

        // ---- stage A (arena: 4 x 3,686,400 B)
        bf16* Q1   = (bf16*)A;
        bf16* K1   = (bf16*)(A + 3686400);
        bf16* V1   = (bf16*)(A + 7372800);
        bf16* att1 = (bf16*)(A + 11059200);
        gemm_kernel<false><<<dim3(4, gy), blk256, 0, stream>>>(qps, 0, 0, d_in[8], d_in[9], Q1, 0, M, 256, 256, flag);
        gemm_kernel<false><<<dim3(4, gy), blk256, 0, stream>>>(qps, 0, 0, d_in[10], d_in[11], K1, 0, M, 256, 256, flag);
        gemm_kernel<false><<<dim3(4, gy), blk256, 0, stream>>>(d_in[0], 1, 0, d_in[12], d_in[13], V1, 0, M, 256, 256, flag);
        attn_tiled_kernel<32><<<dim3(nQT, NH_, BS_), blk256, 0, stream>>>(Q1, K1, V1, att1, NH_, NQ_, 0.17677669529663687f);
        gemm_kernel<false><<<dim3(4, gy), blk256, 0, stream>>>(att1, 0, 0, d_in[14], d_in[15], tgt2, 0, M, 256, 256, flag);

        // ---- stage B (arena: 4 x 7,372,800 B)
        bf16* pairX = (bf16*)A;               // then att2
        bf16* Q2    = (bf16*)(A + 7372800);   // then tgt3
        bf16* K2    = (bf16*)(A + 14745600);
        bf16* V2    = (bf16*)(A + 22118400);
        find_second_kernel<<<M, 64, 0, stream>>>(d_in[7], d_in[6], 0, second, sel, flag);
        build_pair_kernel<<<M, blk256, 0, stream>>>(qps, qps, second, sel, pairX);
        gemm_kernel<false><<<dim3(8, gy), blk256, 0, stream>>>(pairX, 0, 0, d_in[16], d_in[17], Q2, 0, M, 512, 512, flag);
        build_pair_kernel<<<M, blk256, 0, stream>>>(qps, tgt2, second, sel, pairX);
        gemm_kernel<false><<<dim3(8, gy), blk256, 0, stream>>>(pairX, 0, 0, d_in[18], d_in[19], K2, 0, M, 512, 512, flag);
        build_pair_kernel<<<M, blk256, 0, stream>>>(tgt2, tgt2, second, sel, pairX);
        gemm_kernel<false><<<dim3(8, gy), blk256, 0, stream>>>(pairX, 0, 0, d_in[20], d_in[21], V2, 0, M, 512, 512, flag);
        attn_tiled_kernel<64><<<dim3(nQT, NH_, BS_), blk256, 0, stream>>>(Q2, K2, V2, pairX, NH_, NQ_, 0.125f);
        gemm_kernel<false><<<dim3(8, gy), blk256, 0, stream>>>(pairX, 0, 0, d_in[22], d_in[23], Q2, 0, M, 512, 512, flag);

        ln_pair_kernel<<<M, blk256, 0, stream>>>(d_in[0], d_in[1], 0, tgt2, Q2, sel,
                                                 d_in[32], d_in[33], d_in[34], d_in[35], xbuf, query, flag);

        // ---- stage C (arena: offb | awb | locb | samp | vwt)
        bf16*  offb = (bf16*)A;                        //  3,686,400 B
        float* awb  = (float*)(A + 3686400);           //  3,686,400 B
        float* locb = (float*)(A + 7372800);           //  7,372,800 B
        float* samp = (float*)(A + 14745600);          //  7,372,800 B (lives into stage D)
        float* vwt  = (float*)(A + 22118400);          //    262,144 B (dead before h1 is written)
        gemm_kernel<false><<<dim3(4, gy), blk256, 0, stream>>>(query, 0, 0, d_in[26], d_in[27], offb, 0, M, 256, 256, flag);
        gemm_kernel<false><<<dim3(2, gy), blk256, 0, stream>>>(query, 0, 0, d_in[28], d_in[29], awb, 1, M, 128, 256, flag);
        aw_softmax_kernel<<<M, 128, 0, stream>>>(awb, out, (size_t)2 * NE, flag);
        loc_kernel<<<M, blk256, 0, stream>>>(d_in[2], 0, offb, locb, out, (size_t)NE, flag);
        transpose_vw_kernel<<<256, blk256, 0, stream>>>(d_in[24], vwt, flag);
        deform_fused_kernel<<<M, blk256, 0, stream>>>(d_in[3], 0, vwt, d_in[25], locb, awb, samp, flag);

        // ---- stage D (ca | x2 | ffn | [samp] | h1; peak arena 36,864,000 B)
        bf16*  ca  = (bf16*)A;                         //  3,686,400 B
        float* x2  = (float*)(A + 3686400);            //  7,372,800 B
        bf16*  ffn = (bf16*)(A + 11059200);            //  3,686,400 B
        bf16*  h1  = (bf16*)(A + 22118400);            // 14,745,600 B (after samp/vwt dead)
        gemm_kernel<false><<<dim3(4, gy), blk256, 0, stream>>>(samp, 2, 0, d_in[30], d_in[31], ca, 0, M, 256, 256, flag);
        ln_add_kernel<<<M, blk256, 0, stream>>>(xbuf, ca, d_in[32], d_in[33], x2, 1, 0, flag);
        gemm_kernel<true><<<dim3(16, gy), blk256, 0, stream>>>(x2, 2, 0, d_in[38], d_in[39], h1, 0, M, 1024, 256, flag);
        gemm_kernel<false><<<dim3(4, gy), blk256, 0, stream>>>(h1, 0, 0, d_in[40], d_in[41], ffn, 0, M, 256, 1024, flag);
        ln_add_kernel<<<M, blk256, 0, stream>>>(x2, ffn, d_in[36], d_in[37], out, 0, 0, flag);
        return;
    }

    // ---------------- fallback: per-batch loop (needs 6,920,448 B of ws) ----------------
    {
        char* base = (char*)d_ws;
        int*   flag   = (int*)base;                         // 256 B
        float* xbuf   = (float*)(base + 256);               // NEb f32   921,600 B
        bf16*  query  = (bf16*)(base + 256 + 921600);       // NEb bf16  460,800 B
        bf16*  qps    = (bf16*)(base + 256 + 1382400);      // NEb bf16
        bf16*  tgt2   = (bf16*)(base + 256 + 1843200);      // NEb bf16
        int*   second = (int*)(base + 256 + 2304000);       // 3,600 B
        int*   sel    = second + NQ_;                       // 3,600 B
        char*  A      = base + 2312448;                     // arena, peak 4,608,000 B

        const int gyb = (NQ_ + 63) / 64;   // 15

        probe_kernel<<<1, blk256, 0, stream>>>((const unsigned short*)d_in[0], flag);

        for (int b = 0; b < BS_; b++) {
            const size_t o_tgt  = (size_t)b * NEb;
            const size_t o_refp = (size_t)b * NQ_ * 8;
            const size_t o_src  = (size_t)b * LS_ * 256;
            const size_t o_gc   = (size_t)b * NQ_ * NQ_;
            const size_t o_outx = (size_t)b * NEb;
            const size_t o_loc  = (size_t)NE + (size_t)b * NEb;
            const size_t o_aw   = (size_t)2 * NE + (size_t)b * AWb;

            // ---- stage A
            bf16* Q1   = (bf16*)A;
            bf16* K1   = (bf16*)(A + 460800);
            bf16* V1   = (bf16*)(A + 921600);
            bf16* att1 = (bf16*)(A + 1382400);
            prep_kernel<<<NEb / 256, blk256, 0, stream>>>(d_in[0], d_in[1], o_tgt, qps, flag);
            gemm_kernel<false><<<dim3(4, gyb), blk256, 0, stream>>>(qps, 0, 0, d_in[8], d_in[9], Q1, 0, NQ_, 256, 256, flag);
            gemm_kernel<false><<<dim3(4, gyb), blk256, 0, stream>>>(qps, 0, 0, d_in[10], d_in[11], K1, 0, NQ_, 256, 256, flag);
            gemm_kernel<false><<<dim3(4, gyb), blk256, 0, stream>>>(d_in[0], 1, o_tgt, d_in[12], d_in[13], V1, 0, NQ_, 256, 256, flag);
            attn_tiled_kernel<32><<<dim3(gyb, NH_, 1), blk256, 0, stream>>>(Q1, K1, V1, att1, NH_, NQ_, 0.17677669529663687f);
            gemm_kernel<false><<<dim3(4, gyb), blk256, 0, stream>>>(att1, 0, 0, d_in[14], d_in[15], tgt2, 0, NQ_, 256, 256, flag);

            // ---- stage B
            bf16* pairX = (bf16*)A;
            bf16* Q2    = (bf16*)(A + 921600);
            bf16* K2    = (bf16*)(A + 1843200);
            bf16* V2    = (bf16*)(A + 2764800);
            find_second_kernel<<<NQ_, 64, 0, stream>>>(d_in[7], d_in[6], o_gc, second, sel, flag);
            build_pair_kernel<<<NQ_, blk256, 0, stream>>>(qps, qps, second, sel, pairX);
            gemm_kernel<false><<<dim3(8, gyb), blk256, 0, stream>>>(pairX, 0, 0, d_in[16], d_in[17], Q2, 0, NQ_, 512, 512, flag);
            build_pair_kernel<<<NQ_, blk256, 0, stream>>>(qps, tgt2, second, sel, pairX);
            gemm_kernel<false><<<dim3(8, gyb), blk256, 0, stream>>>(pairX, 0, 0, d_in[18], d_in[19], K2, 0, NQ_, 512, 512, flag);
            build_pair_kernel<<<NQ_, blk256, 0, stream>>>(tgt2, tgt2, second, sel, pairX);
            gemm_kernel<false><<<dim3(8, gyb), blk256, 0, stream>>>(pairX, 0, 0, d_in[20], d_in[21], V2, 0, NQ_, 512, 512, flag);
            attn_tiled_kernel<64><<<dim3(gyb, NH_, 1), blk256, 0, stream>>>(Q2, K2, V2, pairX, NH_, NQ_, 0.125f);
            gemm_kernel<false><<<dim3(8, gyb), blk256, 0, stream>>>(pairX, 0, 0, d_in[22], d_in[23], Q2, 0, NQ_, 512, 512, flag);

            ln_pair_kernel<<<NQ_, blk256, 0, stream>>>(d_in[0], d_in[1], o_tgt, tgt2, Q2, sel,
                                                       d_in[32], d_in[33], d_in[34], d_in[35], xbuf, query, flag);

            // ---- stage C
            bf16*  offb = (bf16*)A;
            float* awb  = (float*)(A + 460800);
            float* locb = (float*)(A + 921600);
            float* samp = (float*)(A + 1843200);
            float* vwt  = (float*)(A + 2764800);        // 262,144 B, dead before stage D h1
            gemm_kernel<false><<<dim3(4, gyb), blk256, 0, stream>>>(query, 0, 0, d_in[26], d_in[27], offb, 0, NQ_, 256, 256, flag);
            gemm_kernel<false><<<dim3(2, gyb), blk256, 0, stream>>>(query, 0, 0, d_in[28], d_in[29], awb, 1, NQ_, 128, 256, flag);
            aw_softmax_kernel<<<NQ_, 128, 0, stream>>>(awb, out, o_aw, flag);
            loc_kernel<<<NQ_, blk256, 0, stream>>>(d_in[2], o_refp, offb, locb, out, o_loc, flag);
            transpose_vw_kernel<<<256, blk256, 0, stream>>>(d_in[24], vwt, flag);
            deform_fused_kernel<<<NQ_, blk256, 0, stream>>>(d_in[3], o_src, vwt, d_in[25], locb, awb, samp, flag);

            // ---- stage D
            bf16*  ca  = (bf16*)A;
            float* x2  = (float*)(A + 460800);
            bf16*  ffn = (bf16*)(A + 1382400);
            bf16*  h1  = (bf16*)(A + 2764800);
            gemm_kernel<false><<<dim3(4, gyb), blk256, 0, stream>>>(samp, 2, 0, d_in[30], d_in[31], ca, 0, NQ_, 256, 256, flag);
            ln_add_kernel<<<NQ_, blk256, 0, stream>>>(xbuf, ca, d_in[32], d_in[33], x2, 1, 0, flag);
            gemm_kernel<true><<<dim3(16, gyb), blk256, 0, stream>>>(x2, 2, 0, d_in[38], d_in[39], h1, 0, NQ_, 1024, 256, flag);
            gemm_kernel<false><<<dim3(4, gyb), blk256, 0, stream>>>(h1, 0, 0, d_in[40], d_in[41], ffn, 0, NQ_, 256, 1024, flag);
            ln_add_kernel<<<NQ_, blk256, 0, stream>>>(x2, ffn, d_in[36], d_in[37], out, 0, o_outx, flag);
        }
    }
}

// Round 4
// 2051.477 us; speedup vs baseline: 3.3038x; 1.1539x over previous
//
#include <hip/hip_runtime.h>
#include <hip/hip_bf16.h>

#define D_   256
#define NH_  8
#define NL_  4
#define NP_  4
#define DFF_ 1024
#define BS_  8
#define NQ_  900
#define HD_  32
#define LS_  13294

static const int NE   = BS_ * NQ_ * D_;   // 1,843,200
static const int NEb  = NQ_ * D_;         //   230,400
static const int AWb  = NQ_ * 128;        //   115,200

typedef __hip_bfloat16 bf16;

__device__ __forceinline__ float to_f(bf16 x) { return __bfloat162float(x); }
__device__ __forceinline__ float us_to_f(unsigned short u) {
    return __uint_as_float((unsigned)u << 16);   // bf16 -> f32 is a shift
}
__device__ __forceinline__ float ld(const void* p, size_t i, int f32) {
    return f32 ? ((const float*)p)[i] : __bfloat162float(((const bf16*)p)[i]);
}
__device__ __forceinline__ void st_out(void* p, size_t i, int f32, float v) {
    if (f32) ((float*)p)[i] = v;
    else ((bf16*)p)[i] = __float2bfloat16(v);
}

// ---------------------------------------------------------------- dtype probe
__global__ __launch_bounds__(256) void probe_kernel(const unsigned short* __restrict__ t,
                                                    int* __restrict__ flag) {
    __shared__ int c;
    if (threadIdx.x == 0) c = 0;
    __syncthreads();
    unsigned short v = t[2 * threadIdx.x];   // even bf16-view slots
    int e = (v >> 7) & 0xFF;
    if (e < 90 || e > 140) atomicAdd(&c, 1); // implausible exponent for N(0,1)
    __syncthreads();
    if (threadIdx.x == 0) flag[0] = (c > 64) ? 1 : 0;  // 1 => storage is f32
}

// ---------------------------------------------------------------- prep: qps = tgt + qpos
__global__ __launch_bounds__(256) void prep_kernel(const void* __restrict__ tgt,
                                                   const void* __restrict__ qpos,
                                                   size_t ebase,
                                                   bf16* __restrict__ qps,
                                                   const int* __restrict__ flag) {
    int f = *flag;
    int e = blockIdx.x * 256 + threadIdx.x;
    qps[e] = __float2bfloat16(ld(tgt, ebase + e, f) + ld(qpos, ebase + e, f));
}

// ---------------------------------------------------------------- GEMM: C[M,N] = A[M,K] @ W[N,K]^T + bias
// a_dyn: 0 = A ws bf16; 1 = A external flag-typed; 2 = A ws f32.  aeb = element base for A.
// thread tile: rows ty*4..+3, cols tx*4..+3; float4 LDS reads (rows padded to 68 = 16B-aligned)
template <bool RELU>
__global__ __launch_bounds__(256) void gemm_kernel(const void* __restrict__ A, int a_dyn, size_t aeb,
                                                   const void* __restrict__ W,
                                                   const void* __restrict__ bias,
                                                   void* __restrict__ C, int c_f32,
                                                   int M, int N, int K,
                                                   const int* __restrict__ flag) {
    __shared__ float As[16][68];
    __shared__ float Ws[16][68];
    int f = *flag;
    int a_f32 = (a_dyn == 2) || (a_dyn == 1 && f);
    int tid = threadIdx.x;
    int tx = tid & 15, ty = tid >> 4;
    int row0 = blockIdx.y * 64, col0 = blockIdx.x * 64;
    float acc[4][4] = {};
    for (int k0 = 0; k0 < K; k0 += 16) {
#pragma unroll
        for (int t = 0; t < 4; t++) {
            int e = tid + t * 256;
            int m = e >> 4, kk = e & 15;
            int gr = row0 + m;
            As[kk][m] = (gr < M) ? ld(A, aeb + (size_t)gr * K + k0 + kk, a_f32) : 0.f;
            int gc = col0 + m;  // N multiple of 64
            Ws[kk][m] = ld(W, (size_t)gc * K + k0 + kk, f);
        }
        __syncthreads();
#pragma unroll
        for (int kk = 0; kk < 16; kk++) {
            float4 a4 = *(const float4*)&As[kk][ty * 4];
            float4 b4 = *(const float4*)&Ws[kk][tx * 4];
            float a[4] = {a4.x, a4.y, a4.z, a4.w};
            float b[4] = {b4.x, b4.y, b4.z, b4.w};
#pragma unroll
            for (int i = 0; i < 4; i++)
#pragma unroll
                for (int j = 0; j < 4; j++) acc[i][j] += a[i] * b[j];
        }
        __syncthreads();
    }
    int cbase = col0 + tx * 4;
    float bs[4];
#pragma unroll
    for (int j = 0; j < 4; j++) bs[j] = ld(bias, cbase + j, f);
#pragma unroll
    for (int i = 0; i < 4; i++) {
        int r = row0 + ty * 4 + i;
        if (r >= M) continue;
        float v[4];
#pragma unroll
        for (int j = 0; j < 4; j++) {
            v[j] = acc[i][j] + bs[j];
            if (RELU) v[j] = fmaxf(v[j], 0.f);
        }
        if (c_f32) {
            *(float4*)&((float*)C)[(size_t)r * N + cbase] = make_float4(v[0], v[1], v[2], v[3]);
        } else {
            ushort4 h;
            h.x = __bfloat16_as_ushort(__float2bfloat16(v[0]));
            h.y = __bfloat16_as_ushort(__float2bfloat16(v[1]));
            h.z = __bfloat16_as_ushort(__float2bfloat16(v[2]));
            h.w = __bfloat16_as_ushort(__float2bfloat16(v[3]));
            *(ushort4*)&((bf16*)C)[(size_t)r * N + cbase] = h;
        }
    }
}

// ---------------------------------------------------------------- tiled flash attention (two-phase)
// Block: 256 threads = one (b,h) x 64-query tile. 4 lanes per query, CH=HD/4 dims/lane.
// K/V staged in LDS (f32) in 32-key tiles: thread t writes float4 chunks t, t+256 (conflict-free).
// Per tile: phase 1 = all 32 scores (float4 K reads); one rescale; phase 2 = PV (float4 V reads).
// grid: (ceil(L/64), H, nB)
template <int HD>
__global__ __launch_bounds__(256) void attn_tiled_kernel(const bf16* __restrict__ Q,
                                                         const bf16* __restrict__ K,
                                                         const bf16* __restrict__ V,
                                                         bf16* __restrict__ O,
                                                         int H, int L, float scale) {
    constexpr int CH  = HD / 4;                // dims per lane (8 or 16)
    constexpr int CH4 = CH / 4;                // float4s per lane chunk (2 or 4)
    constexpr int TK  = 32;                    // keys per LDS tile
    constexpr int NC4 = TK * HD / 4;           // float4 chunks per tile (256 or 512)
    const int dm = H * HD;
    __shared__ float Ks[TK][HD];
    __shared__ float Vs[TK][HD];
    int tile = blockIdx.x, h = blockIdx.y, b = blockIdx.z;
    size_t hb = (size_t)b * L * dm + h * HD;   // row j of this (b,h) at hb + j*dm
    int tid = threadIdx.x;
    int lane = tid & 63, wave = tid >> 6;
    int qi = wave * 16 + (lane >> 2);          // local query 0..63
    int q = tile * 64 + qi;
    int c = (lane & 3) * CH;                   // dim chunk start
    int qrow = min(q, L - 1);
    float qreg[CH];
    {
        const bf16* qp = Q + hb + (size_t)qrow * dm + c;
#pragma unroll
        for (int d = 0; d < CH; d++) qreg[d] = to_f(qp[d]);
    }
    float m = -1e30f, s = 0.f;
    float acc[CH] = {};

    for (int j0 = 0; j0 < L; j0 += TK) {
        __syncthreads();   // protect prior-iteration reads
#pragma unroll
        for (int ci = tid; ci < NC4; ci += 256) {
            int e0 = ci * 4;
            int srow = e0 / HD, scol = e0 % HD;
            int gr = j0 + srow;
            if (gr >= L) gr = L - 1;           // clamp; masked in compute
            ushort4 ku = *(const ushort4*)(K + hb + (size_t)gr * dm + scol);
            ushort4 vu = *(const ushort4*)(V + hb + (size_t)gr * dm + scol);
            *(float4*)&Ks[srow][scol] = make_float4(us_to_f(ku.x), us_to_f(ku.y), us_to_f(ku.z), us_to_f(ku.w));
            *(float4*)&Vs[srow][scol] = make_float4(us_to_f(vu.x), us_to_f(vu.y), us_to_f(vu.z), us_to_f(vu.w));
        }
        __syncthreads();

        // ---- phase 1: scores for all TK keys
        float sc[TK];
        float tmax = -1e30f;
#pragma unroll
        for (int j = 0; j < TK; j++) {
            float dt = 0.f;
#pragma unroll
            for (int d4 = 0; d4 < CH4; d4++) {
                float4 kv = *(const float4*)&Ks[j][c + d4 * 4];
                dt += qreg[d4 * 4 + 0] * kv.x + qreg[d4 * 4 + 1] * kv.y
                    + qreg[d4 * 4 + 2] * kv.z + qreg[d4 * 4 + 3] * kv.w;
            }
            dt += __shfl_xor(dt, 1);
            dt += __shfl_xor(dt, 2);
            sc[j] = (j0 + j < L) ? dt * scale : -1e30f;
            tmax = fmaxf(tmax, sc[j]);
        }

        // ---- single rescale per tile
        float mn = fmaxf(m, tmax);
        float corr = __expf(m - mn);
        m = mn;
        float ssum = 0.f;
#pragma unroll
        for (int j = 0; j < TK; j++) {
            sc[j] = __expf(sc[j] - m);         // p_j (0 for masked)
            ssum += sc[j];
        }
        s = s * corr + ssum;
#pragma unroll
        for (int d = 0; d < CH; d++) acc[d] *= corr;

        // ---- phase 2: PV
#pragma unroll
        for (int j = 0; j < TK; j++) {
            float p = sc[j];
#pragma unroll
            for (int d4 = 0; d4 < CH4; d4++) {
                float4 vv = *(const float4*)&Vs[j][c + d4 * 4];
                acc[d4 * 4 + 0] += p * vv.x;
                acc[d4 * 4 + 1] += p * vv.y;
                acc[d4 * 4 + 2] += p * vv.z;
                acc[d4 * 4 + 3] += p * vv.w;
            }
        }
    }
    if (q < L) {
        float inv = 1.f / s;
        bf16* op = O + hb + (size_t)q * dm + c;
#pragma unroll
        for (int d = 0; d < CH; d++) op[d] = __float2bfloat16(acc[d] * inv);
    }
}

// ---------------------------------------------------------------- pairing
// grid = nB*NQ blocks; second[] stores GLOBAL partner row (b*NQ + j).
__global__ __launch_bounds__(64) void find_second_kernel(const void* __restrict__ gious,
                                                         const void* __restrict__ cxcys,
                                                         size_t ebase,
                                                         int* __restrict__ second,
                                                         int* __restrict__ sel,
                                                         const int* __restrict__ flag) {
    int f = *flag;
    int gi = blockIdx.x;
    int b = gi / NQ_;
    int i = gi - b * NQ_;
    size_t rb = ebase + (size_t)b * NQ_ * NQ_ + (size_t)i * NQ_;
    int lane = threadIdx.x;
    float best = -1e30f;
    int bidx = 1 << 30;
    for (int j = lane; j < NQ_; j += 64) {
        if (j == i) continue;
        float v = ld(gious, rb + j, f);
        if (v > best) { best = v; bidx = j; }
    }
#pragma unroll
    for (int o = 32; o; o >>= 1) {
        float v2 = __shfl_xor(best, o);
        int i2 = __shfl_xor(bidx, o);
        if (v2 > best || (v2 == best && i2 < bidx)) { best = v2; bidx = i2; }
    }
    if (lane == 0) {
        second[gi] = b * NQ_ + bidx;
        float c = ld(cxcys, rb + bidx, f);
        sel[gi] = (c == 0.f) ? 1 : 0;
    }
}

__global__ __launch_bounds__(256) void build_pair_kernel(const bf16* __restrict__ X,
                                                         const bf16* __restrict__ Y,
                                                         const int* __restrict__ second,
                                                         const int* __restrict__ sel,
                                                         bf16* __restrict__ out2) {
    int e = blockIdx.x * 256 + threadIdx.x;
    int d = e & 255;
    int i = e >> 8;
    int s = sel[i];
    int j = second[i];
    bf16 a = X[(size_t)i * 256 + d];
    bf16 c = Y[(size_t)j * 256 + d];
    size_t o = (size_t)i * 512 + d;
    out2[o]       = s ? a : c;
    out2[o + 256] = s ? c : a;
}

// ---------------------------------------------------------------- block reduction (256 threads)
__device__ __forceinline__ float block_sum_256(float v, float* sm) {
#pragma unroll
    for (int o = 32; o; o >>= 1) v += __shfl_down(v, o);
    int w = threadIdx.x >> 6, lane = threadIdx.x & 63;
    if (lane == 0) sm[w] = v;
    __syncthreads();
    float r = sm[0] + sm[1] + sm[2] + sm[3];
    __syncthreads();
    return r;
}

__global__ __launch_bounds__(256) void ln_pair_kernel(const void* __restrict__ tgt,
                                                      const void* __restrict__ qpos,
                                                      size_t ebase,
                                                      const bf16* __restrict__ tgt2,
                                                      const bf16* __restrict__ tgt3full,
                                                      const int* __restrict__ sel,
                                                      const void* __restrict__ g1, const void* __restrict__ b1,
                                                      const void* __restrict__ g12, const void* __restrict__ b12,
                                                      float* __restrict__ xbuf,
                                                      bf16* __restrict__ query_d,
                                                      const int* __restrict__ flag) {
    __shared__ float sm[4];
    int f = *flag;
    int i = blockIdx.x, d = threadIdx.x;
    size_t base = (size_t)i * 256;
    float t = ld(tgt, ebase + base + d, f);
    float a1 = t + to_f(tgt2[base + d]);
    int s = sel[i];
    float t3 = to_f(tgt3full[(size_t)i * 512 + (s ? 0 : 256) + d]);
    float a2 = t + t3;
    float m1 = block_sum_256(a1, sm) * (1.f / 256.f);
    float m2 = block_sum_256(a2, sm) * (1.f / 256.f);
    float d1 = a1 - m1, d2 = a2 - m2;
    float v1 = block_sum_256(d1 * d1, sm) * (1.f / 256.f);
    float v2 = block_sum_256(d2 * d2, sm) * (1.f / 256.f);
    float o1 = d1 * rsqrtf(v1 + 1e-5f) * ld(g1, d, f) + ld(b1, d, f);
    float o2 = d2 * rsqrtf(v2 + 1e-5f) * ld(g12, d, f) + ld(b12, d, f);
    float xv = o1 + o2;
    xbuf[base + d] = xv;
    query_d[base + d] = __float2bfloat16(xv + ld(qpos, ebase + base + d, f));
}

// out_mode: 1 = ws f32 (oeb=0), 0 = d_out flag-typed at element base oeb
__global__ __launch_bounds__(256) void ln_add_kernel(const float* __restrict__ A,
                                                     const bf16* __restrict__ Badd,
                                                     const void* __restrict__ g, const void* __restrict__ be,
                                                     void* __restrict__ out, int out_mode, size_t oeb,
                                                     const int* __restrict__ flag) {
    __shared__ float sm[4];
    int f = *flag;
    int i = blockIdx.x, d = threadIdx.x;
    size_t base = (size_t)i * 256;
    float v = A[base + d] + to_f(Badd[base + d]);
    float m = block_sum_256(v, sm) * (1.f / 256.f);
    float dv = v - m;
    float var = block_sum_256(dv * dv, sm) * (1.f / 256.f);
    float o = dv * rsqrtf(var + 1e-5f) * ld(g, d, f) + ld(be, d, f);
    if (out_mode == 1) ((float*)out)[base + d] = o;
    else st_out(out, oeb + base + d, f, o);
}

// ---------------------------------------------------------------- deformable attention pieces
__global__ __launch_bounds__(128) void aw_softmax_kernel(float* __restrict__ aw,
                                                         void* __restrict__ out_aw, size_t oeb,
                                                         const int* __restrict__ flag) {
    int f = *flag;
    int i = blockIdx.x, t = threadIdx.x;
    size_t idx = (size_t)i * 128 + t;
    float v = aw[idx];
    float mx = v;
#pragma unroll
    for (int o = 8; o; o >>= 1) mx = fmaxf(mx, __shfl_xor(mx, o, 16));
    float e = __expf(v - mx);
    float s = e;
#pragma unroll
    for (int o = 8; o; o >>= 1) s += __shfl_xor(s, o, 16);
    float r = e / s;
    aw[idx] = r;
    st_out(out_aw, oeb + idx, f, r);
}

__global__ __launch_bounds__(256) void loc_kernel(const void* __restrict__ refp, size_t rbase,
                                                  const bf16* __restrict__ off,
                                                  float* __restrict__ locbuf,
                                                  void* __restrict__ out_loc, size_t oeb,
                                                  const int* __restrict__ flag) {
    int f = *flag;
    int e = blockIdx.x * 256 + threadIdx.x;  // [rows, H,L,P,2]
    int c = e & 1;
    int l = (e >> 3) & 3;
    int i = e >> 8;
    const float norm[4] = {100.f, 50.f, 25.f, 13.f};  // W == H per level
    float rv = ld(refp, rbase + ((size_t)i * 4 + l) * 2 + c, f);
    float lv = rv + to_f(off[e]) / norm[l];
    locbuf[e] = lv;
    st_out(out_loc, oeb + e, f, lv);
}

// one-time transpose of the value-projection weight into f32 [k][c] layout
__global__ __launch_bounds__(256) void transpose_vw_kernel(const void* __restrict__ vw,
                                                           float* __restrict__ vwt,
                                                           const int* __restrict__ flag) {
    int f = *flag;
    int e = blockIdx.x * 256 + threadIdx.x;   // 65536
    int k = e >> 8, c = e & 255;
    vwt[(size_t)k * 256 + c] = ld(vw, (size_t)c * 256 + k, f);
}

// Fused bilinear-sample + value-projection + attention-weighting.
// grid rows may span batches: b = q / NQ_ selects the src slab.
// Gather accumulates in REGISTERS (h-outer loop) so global loads pipeline;
// projection reads pre-transposed vwt (coalesced, L2-resident).
__global__ __launch_bounds__(256) void deform_fused_kernel(const void* __restrict__ src, size_t sbase,
                                                           const float* __restrict__ vwt,
                                                           const void* __restrict__ vb,
                                                           const float* __restrict__ locb,
                                                           const float* __restrict__ awb,
                                                           float* __restrict__ samp,
                                                           const int* __restrict__ flag) {
    int f = *flag;
    int q = blockIdx.x;
    int b = q / NQ_;
    size_t srow = sbase + (size_t)b * LS_ * 256;
    int t = threadIdx.x;
    __shared__ float G[8][257];
    __shared__ int   rowi[128][4];
    __shared__ float wc[128][4];
    __shared__ float wv_s[128];
    __shared__ float aw_s[128];
    if (t < 128) {
        const int HW[4] = {100, 50, 25, 13};
        const int ST[4] = {0, 10000, 12500, 13125};
        int le = t;                       // h*16 + l*4 + p
        int l = (le >> 2) & 3;
        int W = HW[l], H = W, st = ST[l];
        float lx = locb[(size_t)q * 256 + le * 2];
        float ly = locb[(size_t)q * 256 + le * 2 + 1];
        float x = lx * W - 0.5f, y = ly * H - 0.5f;
        float xf = floorf(x), yf = floorf(y);
        int x0 = (int)xf, y0 = (int)yf;
        float wx1 = x - xf, wy1 = y - yf;
        float wx0 = 1.f - wx1, wy0 = 1.f - wy1;
        bool xv0 = (x0 >= 0) && (x0 < W), xv1 = (x0 + 1 >= 0) && (x0 + 1 < W);
        bool yv0 = (y0 >= 0) && (y0 < H), yv1 = (y0 + 1 >= 0) && (y0 + 1 < H);
        int cx0 = min(max(x0, 0), W - 1), cx1 = min(max(x0 + 1, 0), W - 1);
        int cy0 = min(max(y0, 0), H - 1), cy1 = min(max(y0 + 1, 0), H - 1);
        rowi[le][0] = st + cy0 * W + cx0;  wc[le][0] = (xv0 && yv0) ? wx0 * wy0 : 0.f;
        rowi[le][1] = st + cy0 * W + cx1;  wc[le][1] = (xv1 && yv0) ? wx1 * wy0 : 0.f;
        rowi[le][2] = st + cy1 * W + cx0;  wc[le][2] = (xv0 && yv1) ? wx0 * wy1 : 0.f;
        rowi[le][3] = st + cy1 * W + cx1;  wc[le][3] = (xv1 && yv1) ? wx1 * wy1 : 0.f;
        wv_s[le] = wc[le][0] + wc[le][1] + wc[le][2] + wc[le][3];
        aw_s[le] = awb[(size_t)q * 128 + le];
    }
    __syncthreads();
#pragma unroll
    for (int h = 0; h < 8; h++) {
        float g = 0.f;
#pragma unroll 4
        for (int le2 = 0; le2 < 16; le2++) {
            int le = h * 16 + le2;
            float a  = aw_s[le];
            float w0 = wc[le][0], w1 = wc[le][1], w2 = wc[le][2], w3 = wc[le][3];
            // indices are pre-clamped: unconditional loads (weight 0 kills OOB terms)
            float v = w0 * ld(src, srow + (size_t)rowi[le][0] * 256 + t, f)
                    + w1 * ld(src, srow + (size_t)rowi[le][1] * 256 + t, f)
                    + w2 * ld(src, srow + (size_t)rowi[le][2] * 256 + t, f)
                    + w3 * ld(src, srow + (size_t)rowi[le][3] * 256 + t, f);
            g += a * v;
        }
        G[h][t] = g;
    }
    __syncthreads();
    int c = t, h = c >> 5;
    float bscale = 0.f;
#pragma unroll
    for (int r = 0; r < 16; r++) bscale += aw_s[h * 16 + r] * wv_s[h * 16 + r];
    float acc = bscale * ld(vb, c, f);
#pragma unroll 8
    for (int k = 0; k < 256; k++) acc += G[h][k] * vwt[(size_t)k * 256 + c];
    samp[(size_t)q * 256 + c] = acc;
}

// ================================================================ launch
extern "C" void kernel_launch(void* const* d_in, const int* in_sizes, int n_in,
                              void* d_out, int out_size, void* d_ws, size_t ws_size,
                              hipStream_t stream) {
    (void)in_sizes; (void)n_in; (void)out_size;
    void* out = d_out;
    const dim3 blk256(256);
    const int nQT = (NQ_ + 63) / 64;   // 15 query tiles for attention

    // ---------------- fully-batched path (needs 55,353,856 B of ws) ----------------
    if (ws_size >= 55353856ull) {
        char* base = (char*)d_ws;
        int*   flag   = (int*)base;                           // 256 B
        float* xbuf   = (float*)(base + 256);                 // NE f32   7,372,800
        bf16*  query  = (bf16*)(base + 7373056);              // NE bf16  3,686,400
        bf16*  qps    = (bf16*)(base + 11059456);             // NE bf16
        bf16*  tgt2   = (bf16*)(base + 14745856);             // NE bf16
        int*   second = (int*)(base + 18432256);              // 28,800 B
        int*   sel    = second + BS_ * NQ_;                   // 28,800 B
        char*  A      = base + 18489856;                      // arena, peak 36,864,000 B

        const int M = BS_ * NQ_;              // 7200
        const int gy = (M + 63) / 64;         // 113

        probe_kernel<<<1, blk256, 0, stream>>>((const unsigned short*)d_in[0], flag);
        prep_kernel<<<NE / 256, blk256, 0, stream>>>(d_in[0], d_in[1], 0, qps, flag);

        // ---- stage A (arena: 4 x 3,686,400 B)
        bf16* Q1   = (bf16*)A;
        bf16* K1   = (bf16*)(A + 3686400);
        bf16* V1   = (bf16*)(A + 7372800);
        bf16* att1 = (bf16*)(A + 11059200);
        gemm_kernel<false><<<dim3(4, gy), blk256, 0, stream>>>(qps, 0, 0, d_in[8], d_in[9], Q1, 0, M, 256, 256, flag);
        gemm_kernel<false><<<dim3(4, gy), blk256, 0, stream>>>(qps, 0, 0, d_in[10], d_in[11], K1, 0, M, 256, 256, flag);
        gemm_kernel<false><<<dim3(4, gy), blk256, 0, stream>>>(d_in[0], 1, 0, d_in[12], d_in[13], V1, 0, M, 256, 256, flag);
        attn_tiled_kernel<32><<<dim3(nQT, NH_, BS_), blk256, 0, stream>>>(Q1, K1, V1, att1, NH_, NQ_, 0.17677669529663687f);
        gemm_kernel<false><<<dim3(4, gy), blk256, 0, stream>>>(att1, 0, 0, d_in[14], d_in[15], tgt2, 0, M, 256, 256, flag);

        // ---- stage B (arena: 4 x 7,372,800 B)
        bf16* pairX = (bf16*)A;               // then att2
        bf16* Q2    = (bf16*)(A + 7372800);   // then tgt3
        bf16* K2    = (bf16*)(A + 14745600);
        bf16* V2    = (bf16*)(A + 22118400);
        find_second_kernel<<<M, 64, 0, stream>>>(d_in[7], d_in[6], 0, second, sel, flag);
        build_pair_kernel<<<M, blk256, 0, stream>>>(qps, qps, second, sel, pairX);
        gemm_kernel<false><<<dim3(8, gy), blk256, 0, stream>>>(pairX, 0, 0, d_in[16], d_in[17], Q2, 0, M, 512, 512, flag);
        build_pair_kernel<<<M, blk256, 0, stream>>>(qps, tgt2, second, sel, pairX);
        gemm_kernel<false><<<dim3(8, gy), blk256, 0, stream>>>(pairX, 0, 0, d_in[18], d_in[19], K2, 0, M, 512, 512, flag);
        build_pair_kernel<<<M, blk256, 0, stream>>>(tgt2, tgt2, second, sel, pairX);
        gemm_kernel<false><<<dim3(8, gy), blk256, 0, stream>>>(pairX, 0, 0, d_in[20], d_in[21], V2, 0, M, 512, 512, flag);
        attn_tiled_kernel<64><<<dim3(nQT, NH_, BS_), blk256, 0, stream>>>(Q2, K2, V2, pairX, NH_, NQ_, 0.125f);
        gemm_kernel<false><<<dim3(8, gy), blk256, 0, stream>>>(pairX, 0, 0, d_in[22], d_in[23], Q2, 0, M, 512, 512, flag);

        ln_pair_kernel<<<M, blk256, 0, stream>>>(d_in[0], d_in[1], 0, tgt2, Q2, sel,
                                                 d_in[32], d_in[33], d_in[34], d_in[35], xbuf, query, flag);

        // ---- stage C (arena: offb | awb | locb | samp | vwt)
        bf16*  offb = (bf16*)A;                        //  3,686,400 B
        float* awb  = (float*)(A + 3686400);           //  3,686,400 B
        float* locb = (float*)(A + 7372800);           //  7,372,800 B
        float* samp = (float*)(A + 14745600);          //  7,372,800 B (lives into stage D)
        float* vwt  = (float*)(A + 22118400);          //    262,144 B (dead before h1 is written)
        gemm_kernel<false><<<dim3(4, gy), blk256, 0, stream>>>(query, 0, 0, d_in[26], d_in[27], offb, 0, M, 256, 256, flag);
        gemm_kernel<false><<<dim3(2, gy), blk256, 0, stream>>>(query, 0, 0, d_in[28], d_in[29], awb, 1, M, 128, 256, flag);
        aw_softmax_kernel<<<M, 128, 0, stream>>>(awb, out, (size_t)2 * NE, flag);
        loc_kernel<<<M, blk256, 0, stream>>>(d_in[2], 0, offb, locb, out, (size_t)NE, flag);
        transpose_vw_kernel<<<256, blk256, 0, stream>>>(d_in[24], vwt, flag);
        deform_fused_kernel<<<M, blk256, 0, stream>>>(d_in[3], 0, vwt, d_in[25], locb, awb, samp, flag);

        // ---- stage D (ca | x2 | ffn | [samp] | h1; peak arena 36,864,000 B)
        bf16*  ca  = (bf16*)A;                         //  3,686,400 B
        float* x2  = (float*)(A + 3686400);            //  7,372,800 B
        bf16*  ffn = (bf16*)(A + 11059200);            //  3,686,400 B
        bf16*  h1  = (bf16*)(A + 22118400);            // 14,745,600 B (after samp/vwt dead)
        gemm_kernel<false><<<dim3(4, gy), blk256, 0, stream>>>(samp, 2, 0, d_in[30], d_in[31], ca, 0, M, 256, 256, flag);
        ln_add_kernel<<<M, blk256, 0, stream>>>(xbuf, ca, d_in[32], d_in[33], x2, 1, 0, flag);
        gemm_kernel<true><<<dim3(16, gy), blk256, 0, stream>>>(x2, 2, 0, d_in[38], d_in[39], h1, 0, M, 1024, 256, flag);
        gemm_kernel<false><<<dim3(4, gy), blk256, 0, stream>>>(h1, 0, 0, d_in[40], d_in[41], ffn, 0, M, 256, 1024, flag);
        ln_add_kernel<<<M, blk256, 0, stream>>>(x2, ffn, d_in[36], d_in[37], out, 0, 0, flag);
        return;
    }

    // ---------------- fallback: per-batch loop (needs 6,920,448 B of ws) ----------------
    {
        char* base = (char*)d_ws;
        int*   flag   = (int*)base;                         // 256 B
        float* xbuf   = (float*)(base + 256);               // NEb f32   921,600 B
        bf16*  query  = (bf16*)(base + 256 + 921600);       // NEb bf16  460,800 B
        bf16*  qps    = (bf16*)(base + 256 + 1382400);      // NEb bf16
        bf16*  tgt2   = (bf16*)(base + 256 + 1843200);      // NEb bf16
        int*   second = (int*)(base + 256 + 2304000);       // 3,600 B
        int*   sel    = second + NQ_;                       // 3,600 B
        char*  A      = base + 2312448;                     // arena, peak 4,608,000 B

        const int gyb = (NQ_ + 63) / 64;   // 15

        probe_kernel<<<1, blk256, 0, stream>>>((const unsigned short*)d_in[0], flag);

        for (int b = 0; b < BS_; b++) {
            const size_t o_tgt  = (size_t)b * NEb;
            const size_t o_refp = (size_t)b * NQ_ * 8;
            const size_t o_src  = (size_t)b * LS_ * 256;
            const size_t o_gc   = (size_t)b * NQ_ * NQ_;
            const size_t o_outx = (size_t)b * NEb;
            const size_t o_loc  = (size_t)NE + (size_t)b * NEb;
            const size_t o_aw   = (size_t)2 * NE + (size_t)b * AWb;

            // ---- stage A
            bf16* Q1   = (bf16*)A;
            bf16* K1   = (bf16*)(A + 460800);
            bf16* V1   = (bf16*)(A + 921600);
            bf16* att1 = (bf16*)(A + 1382400);
            prep_kernel<<<NEb / 256, blk256, 0, stream>>>(d_in[0], d_in[1], o_tgt, qps, flag);
            gemm_kernel<false><<<dim3(4, gyb), blk256, 0, stream>>>(qps, 0, 0, d_in[8], d_in[9], Q1, 0, NQ_, 256, 256, flag);
            gemm_kernel<false><<<dim3(4, gyb), blk256, 0, stream>>>(qps, 0, 0, d_in[10], d_in[11], K1, 0, NQ_, 256, 256, flag);
            gemm_kernel<false><<<dim3(4, gyb), blk256, 0, stream>>>(d_in[0], 1, o_tgt, d_in[12], d_in[13], V1, 0, NQ_, 256, 256, flag);
            attn_tiled_kernel<32><<<dim3(gyb, NH_, 1), blk256, 0, stream>>>(Q1, K1, V1, att1, NH_, NQ_, 0.17677669529663687f);
            gemm_kernel<false><<<dim3(4, gyb), blk256, 0, stream>>>(att1, 0, 0, d_in[14], d_in[15], tgt2, 0, NQ_, 256, 256, flag);

            // ---- stage B
            bf16* pairX = (bf16*)A;
            bf16* Q2    = (bf16*)(A + 921600);
            bf16* K2    = (bf16*)(A + 1843200);
            bf16* V2    = (bf16*)(A + 2764800);
            find_second_kernel<<<NQ_, 64, 0, stream>>>(d_in[7], d_in[6], o_gc, second, sel, flag);
            build_pair_kernel<<<NQ_, blk256, 0, stream>>>(qps, qps, second, sel, pairX);
            gemm_kernel<false><<<dim3(8, gyb), blk256, 0, stream>>>(pairX, 0, 0, d_in[16], d_in[17], Q2, 0, NQ_, 512, 512, flag);
            build_pair_kernel<<<NQ_, blk256, 0, stream>>>(qps, tgt2, second, sel, pairX);
            gemm_kernel<false><<<dim3(8, gyb), blk256, 0, stream>>>(pairX, 0, 0, d_in[18], d_in[19], K2, 0, NQ_, 512, 512, flag);
            build_pair_kernel<<<NQ_, blk256, 0, stream>>>(tgt2, tgt2, second, sel, pairX);
            gemm_kernel<false><<<dim3(8, gyb), blk256, 0, stream>>>(pairX, 0, 0, d_in[20], d_in[21], V2, 0, NQ_, 512, 512, flag);
            attn_tiled_kernel<64><<<dim3(gyb, NH_, 1), blk256, 0, stream>>>(Q2, K2, V2, pairX, NH_, NQ_, 0.125f);
            gemm_kernel<false><<<dim3(8, gyb), blk256, 0, stream>>>(pairX, 0, 0, d_in[22], d_in[23], Q2, 0, NQ_, 512, 512, flag);

            ln_pair_kernel<<<NQ_, blk256, 0, stream>>>(d_in[0], d_in[1], o_tgt, tgt2, Q2, sel,
                                                       d_in[32], d_in[33], d_in[34], d_in[35], xbuf, query, flag);

            // ---- stage C
            bf16*  offb = (bf16*)A;
            float* awb  = (float*)(A + 460800);
            float* locb = (float*)(A + 921600);
            float* samp = (float*)(A + 1843200);
            float* vwt  = (float*)(A + 2764800);        // 262,144 B, dead before stage D h1
            gemm_kernel<false><<<dim3(4, gyb), blk256, 0, stream>>>(query, 0, 0, d_in[26], d_in[27], offb, 0, NQ_, 256, 256, flag);
            gemm_kernel<false><<<dim3(2, gyb), blk256, 0, stream>>>(query, 0, 0, d_in[28], d_in[29], awb, 1, NQ_, 128, 256, flag);
            aw_softmax_kernel<<<NQ_, 128, 0, stream>>>(awb, out, o_aw, flag);
            loc_kernel<<<NQ_, blk256, 0, stream>>>(d_in[2], o_refp, offb, locb, out, o_loc, flag);
            transpose_vw_kernel<<<256, blk256, 0, stream>>>(d_in[24], vwt, flag);
            deform_fused_kernel<<<NQ_, blk256, 0, stream>>>(d_in[3], o_src, vwt, d_in[25], locb, awb, samp, flag);

            // ---- stage D
            bf16*  ca  = (bf16*)A;
            float* x2  = (float*)(A + 460800);
            bf16*  ffn = (bf16*)(A + 1382400);
            bf16*  h1  = (bf16*)(A + 2764800);
            gemm_kernel<false><<<dim3(4, gyb), blk256, 0, stream>>>(samp, 2, 0, d_in[30], d_in[31], ca, 0, NQ_, 256, 256, flag);
            ln_add_kernel<<<NQ_, blk256, 0, stream>>>(xbuf, ca, d_in[32], d_in[33], x2, 1, 0, flag);
            gemm_kernel<true><<<dim3(16, gyb), blk256, 0, stream>>>(x2, 2, 0, d_in[38], d_in[39], h1, 0, NQ_, 1024, 256, flag);
            gemm_kernel<false><<<dim3(4, gyb), blk256, 0, stream>>>(h1, 0, 0, d_in[40], d_in[41], ffn, 0, NQ_, 256, 1024, flag);
            ln_add_kernel<<<NQ_, blk256, 0, stream>>>(x2, ffn, d_in[36], d_in[37], out, 0, o_outx, flag);
        }
    }
}

// Round 6
// 1439.540 us; speedup vs baseline: 4.7082x; 1.4251x over previous
//
#include <hip/hip_runtime.h>
#include <hip/hip_bf16.h>

#define D_   256
#define NH_  8
#define NL_  4
#define NP_  4
#define DFF_ 1024
#define BS_  8
#define NQ_  900
#define HD_  32
#define LS_  13294

static const int NE   = BS_ * NQ_ * D_;   // 1,843,200
static const int NEb  = NQ_ * D_;         //   230,400
static const int AWb  = NQ_ * 128;        //   115,200

typedef __hip_bfloat16 bf16;
typedef __attribute__((ext_vector_type(8))) short s8v;   // 8 bf16 (4 VGPRs)
typedef __attribute__((ext_vector_type(4))) float f4v;   // 4 f32 acc

__device__ __forceinline__ float to_f(bf16 x) { return __bfloat162float(x); }
__device__ __forceinline__ float us_to_f(unsigned short u) {
    return __uint_as_float((unsigned)u << 16);   // bf16 -> f32 is a shift
}
__device__ __forceinline__ float ld(const void* p, size_t i, int f32) {
    return f32 ? ((const float*)p)[i] : __bfloat162float(((const bf16*)p)[i]);
}
__device__ __forceinline__ void st_out(void* p, size_t i, int f32, float v) {
    if (f32) ((float*)p)[i] = v;
    else ((bf16*)p)[i] = __float2bfloat16(v);
}
__device__ __forceinline__ unsigned short f_to_us(float v) {
    return __bfloat16_as_ushort(__float2bfloat16(v));
}

// ---------------------------------------------------------------- dtype probe
__global__ __launch_bounds__(256) void probe_kernel(const unsigned short* __restrict__ t,
                                                    int* __restrict__ flag) {
    __shared__ int c;
    if (threadIdx.x == 0) c = 0;
    __syncthreads();
    unsigned short v = t[2 * threadIdx.x];   // even bf16-view slots
    int e = (v >> 7) & 0xFF;
    if (e < 90 || e > 140) atomicAdd(&c, 1); // implausible exponent for N(0,1)
    __syncthreads();
    if (threadIdx.x == 0) flag[0] = (c > 64) ? 1 : 0;  // 1 => storage is f32
}

// ---------------------------------------------------------------- prep: qps = tgt + qpos; tgtb = bf16(tgt)
__global__ __launch_bounds__(256) void prep_kernel(const void* __restrict__ tgt,
                                                   const void* __restrict__ qpos,
                                                   size_t ebase,
                                                   bf16* __restrict__ qps,
                                                   bf16* __restrict__ tgtb,
                                                   const int* __restrict__ flag) {
    int f = *flag;
    int e = blockIdx.x * 256 + threadIdx.x;
    float t = ld(tgt, ebase + e, f);
    qps[e] = __float2bfloat16(t + ld(qpos, ebase + e, f));
    tgtb[e] = __float2bfloat16(t);
}

// ---------------------------------------------------------------- MFMA GEMM: C[M,N] = A[M,K] @ W[N,K]^T + bias
// A: bf16 ws buffer. W/bias: flag-typed external (converted to bf16 at staging).
// BM=BN=64, BK=32. 4 waves in 2x2; each wave = 32x32 (2x2 fragments of 16x16x32 mfma).
// Frag layout (gfx950, HW-verified): A lane l: row=l&15, k=(l>>4)*8+0..7 (8 contiguous bf16);
// B lane l: col=l&15, same k; D lane l: col=l&15, row=(l>>4)*4+reg.
template <bool RELU>
__global__ __launch_bounds__(256) void gemm_mfma_kernel(const bf16* __restrict__ A,
                                                        const void* __restrict__ W,
                                                        const void* __restrict__ bias,
                                                        void* __restrict__ C, int c_f32,
                                                        int M, int N, int K,
                                                        const int* __restrict__ flag) {
    __shared__ short As[64][40];   // stride 40 shorts = 80B: 16B-aligned rows, 2-way-max conflicts
    __shared__ short Ws[64][40];
    int f = *flag;
    int tid = threadIdx.x;
    int wave = tid >> 6, lane = tid & 63;
    int wr = wave >> 1, wc = wave & 1;           // wave 2x2 position
    int row0 = blockIdx.y * 64, col0 = blockIdx.x * 64;
    int srow = tid >> 2;                          // staging row 0..63
    int schunk = (tid & 3) * 8;                   // staging k-chunk 0/8/16/24
    int fr = lane & 15, fg = lane >> 4;           // fragment row/col + group
    int fk = fg * 8;                              // fragment k offset

    f4v acc00 = {0.f, 0.f, 0.f, 0.f};
    f4v acc01 = {0.f, 0.f, 0.f, 0.f};
    f4v acc10 = {0.f, 0.f, 0.f, 0.f};
    f4v acc11 = {0.f, 0.f, 0.f, 0.f};

    for (int k0 = 0; k0 < K; k0 += 32) {
        // ---- stage A tile (clamp tail rows; outputs guarded at write)
        {
            int gr = row0 + srow;
            int ar = (gr < M) ? gr : (M - 1);
            const ushort* ap = (const ushort*)A + (size_t)ar * K + k0 + schunk;
            *(ushort4*)&As[srow][schunk]     = *(const ushort4*)ap;
            *(ushort4*)&As[srow][schunk + 4] = *(const ushort4*)(ap + 4);
            int gc = col0 + srow;                 // N multiple of 64
            if (f) {
                const float* wp = (const float*)W + (size_t)gc * K + k0 + schunk;
                float4 w0 = *(const float4*)wp;
                float4 w1 = *(const float4*)(wp + 4);
                ushort4 h0, h1;
                h0.x = f_to_us(w0.x); h0.y = f_to_us(w0.y); h0.z = f_to_us(w0.z); h0.w = f_to_us(w0.w);
                h1.x = f_to_us(w1.x); h1.y = f_to_us(w1.y); h1.z = f_to_us(w1.z); h1.w = f_to_us(w1.w);
                *(ushort4*)&Ws[srow][schunk]     = h0;
                *(ushort4*)&Ws[srow][schunk + 4] = h1;
            } else {
                const ushort* wp = (const ushort*)W + (size_t)gc * K + k0 + schunk;
                *(ushort4*)&Ws[srow][schunk]     = *(const ushort4*)wp;
                *(ushort4*)&Ws[srow][schunk + 4] = *(const ushort4*)(wp + 4);
            }
        }
        __syncthreads();
        s8v a0 = *(const s8v*)&As[wr * 32 + fr][fk];
        s8v a1 = *(const s8v*)&As[wr * 32 + 16 + fr][fk];
        s8v b0 = *(const s8v*)&Ws[wc * 32 + fr][fk];
        s8v b1 = *(const s8v*)&Ws[wc * 32 + 16 + fr][fk];
        acc00 = __builtin_amdgcn_mfma_f32_16x16x32_bf16(a0, b0, acc00, 0, 0, 0);
        acc01 = __builtin_amdgcn_mfma_f32_16x16x32_bf16(a0, b1, acc01, 0, 0, 0);
        acc10 = __builtin_amdgcn_mfma_f32_16x16x32_bf16(a1, b0, acc10, 0, 0, 0);
        acc11 = __builtin_amdgcn_mfma_f32_16x16x32_bf16(a1, b1, acc11, 0, 0, 0);
        __syncthreads();
    }

    // ---- epilogue: D col = lane&15, row = (lane>>4)*4 + reg
    int cA = col0 + wc * 32 + fr;        // j-tile 0
    int cB = cA + 16;                    // j-tile 1
    float bvA = ld(bias, cA, f);
    float bvB = ld(bias, cB, f);
#pragma unroll
    for (int i = 0; i < 2; i++) {
        int rbase = row0 + wr * 32 + i * 16 + fg * 4;
        f4v vj0 = (i == 0) ? acc00 : acc10;
        f4v vj1 = (i == 0) ? acc01 : acc11;
#pragma unroll
        for (int r = 0; r < 4; r++) {
            int row = rbase + r;
            if (row >= M) continue;
            float v0 = vj0[r] + bvA;
            float v1 = vj1[r] + bvB;
            if (RELU) { v0 = fmaxf(v0, 0.f); v1 = fmaxf(v1, 0.f); }
            if (c_f32) {
                ((float*)C)[(size_t)row * N + cA] = v0;
                ((float*)C)[(size_t)row * N + cB] = v1;
            } else {
                ((bf16*)C)[(size_t)row * N + cA] = __float2bfloat16(v0);
                ((bf16*)C)[(size_t)row * N + cB] = __float2bfloat16(v1);
            }
        }
    }
}

// ---------------------------------------------------------------- legacy FP32 GEMM (fallback path only)
template <bool RELU>
__global__ __launch_bounds__(256) void gemm_kernel(const void* __restrict__ A, int a_dyn, size_t aeb,
                                                   const void* __restrict__ W,
                                                   const void* __restrict__ bias,
                                                   void* __restrict__ C, int c_f32,
                                                   int M, int N, int K,
                                                   const int* __restrict__ flag) {
    __shared__ float As[16][68];
    __shared__ float Ws[16][68];
    int f = *flag;
    int a_f32 = (a_dyn == 2) || (a_dyn == 1 && f);
    int tid = threadIdx.x;
    int tx = tid & 15, ty = tid >> 4;
    int row0 = blockIdx.y * 64, col0 = blockIdx.x * 64;
    float acc[4][4] = {};
    for (int k0 = 0; k0 < K; k0 += 16) {
#pragma unroll
        for (int t = 0; t < 4; t++) {
            int e = tid + t * 256;
            int m = e >> 4, kk = e & 15;
            int gr = row0 + m;
            As[kk][m] = (gr < M) ? ld(A, aeb + (size_t)gr * K + k0 + kk, a_f32) : 0.f;
            int gc = col0 + m;  // N multiple of 64
            Ws[kk][m] = ld(W, (size_t)gc * K + k0 + kk, f);
        }
        __syncthreads();
#pragma unroll
        for (int kk = 0; kk < 16; kk++) {
            float4 a4 = *(const float4*)&As[kk][ty * 4];
            float4 b4 = *(const float4*)&Ws[kk][tx * 4];
            float a[4] = {a4.x, a4.y, a4.z, a4.w};
            float b[4] = {b4.x, b4.y, b4.z, b4.w};
#pragma unroll
            for (int i = 0; i < 4; i++)
#pragma unroll
                for (int j = 0; j < 4; j++) acc[i][j] += a[i] * b[j];
        }
        __syncthreads();
    }
    int cbase = col0 + tx * 4;
    float bs[4];
#pragma unroll
    for (int j = 0; j < 4; j++) bs[j] = ld(bias, cbase + j, f);
#pragma unroll
    for (int i = 0; i < 4; i++) {
        int r = row0 + ty * 4 + i;
        if (r >= M) continue;
        float v[4];
#pragma unroll
        for (int j = 0; j < 4; j++) {
            v[j] = acc[i][j] + bs[j];
            if (RELU) v[j] = fmaxf(v[j], 0.f);
        }
        if (c_f32) {
            *(float4*)&((float*)C)[(size_t)r * N + cbase] = make_float4(v[0], v[1], v[2], v[3]);
        } else {
            ushort4 h;
            h.x = f_to_us(v[0]); h.y = f_to_us(v[1]); h.z = f_to_us(v[2]); h.w = f_to_us(v[3]);
            *(ushort4*)&((bf16*)C)[(size_t)r * N + cbase] = h;
        }
    }
}

// ---------------------------------------------------------------- tiled flash attention (two-phase)
template <int HD>
__global__ __launch_bounds__(256) void attn_tiled_kernel(const bf16* __restrict__ Q,
                                                         const bf16* __restrict__ K,
                                                         const bf16* __restrict__ V,
                                                         bf16* __restrict__ O,
                                                         int H, int L, float scale) {
    constexpr int CH  = HD / 4;                // dims per lane (8 or 16)
    constexpr int CH4 = CH / 4;                // float4s per lane chunk (2 or 4)
    constexpr int TK  = 32;                    // keys per LDS tile
    constexpr int NC4 = TK * HD / 4;           // float4 chunks per tile (256 or 512)
    const int dm = H * HD;
    __shared__ float Ks[TK][HD];
    __shared__ float Vs[TK][HD];
    int tile = blockIdx.x, h = blockIdx.y, b = blockIdx.z;
    size_t hb = (size_t)b * L * dm + h * HD;   // row j of this (b,h) at hb + j*dm
    int tid = threadIdx.x;
    int lane = tid & 63, wave = tid >> 6;
    int qi = wave * 16 + (lane >> 2);          // local query 0..63
    int q = tile * 64 + qi;
    int c = (lane & 3) * CH;                   // dim chunk start
    int qrow = min(q, L - 1);
    float qreg[CH];
    {
        const bf16* qp = Q + hb + (size_t)qrow * dm + c;
#pragma unroll
        for (int d = 0; d < CH; d++) qreg[d] = to_f(qp[d]);
    }
    float m = -1e30f, s = 0.f;
    float acc[CH] = {};

    for (int j0 = 0; j0 < L; j0 += TK) {
        __syncthreads();   // protect prior-iteration reads
#pragma unroll
        for (int ci = tid; ci < NC4; ci += 256) {
            int e0 = ci * 4;
            int srow = e0 / HD, scol = e0 % HD;
            int gr = j0 + srow;
            if (gr >= L) gr = L - 1;           // clamp; masked in compute
            ushort4 ku = *(const ushort4*)(K + hb + (size_t)gr * dm + scol);
            ushort4 vu = *(const ushort4*)(V + hb + (size_t)gr * dm + scol);
            *(float4*)&Ks[srow][scol] = make_float4(us_to_f(ku.x), us_to_f(ku.y), us_to_f(ku.z), us_to_f(ku.w));
            *(float4*)&Vs[srow][scol] = make_float4(us_to_f(vu.x), us_to_f(vu.y), us_to_f(vu.z), us_to_f(vu.w));
        }
        __syncthreads();

        // ---- phase 1: scores for all TK keys
        float sc[TK];
        float tmax = -1e30f;
#pragma unroll
        for (int j = 0; j < TK; j++) {
            float dt = 0.f;
#pragma unroll
            for (int d4 = 0; d4 < CH4; d4++) {
                float4 kv = *(const float4*)&Ks[j][c + d4 * 4];
                dt += qreg[d4 * 4 + 0] * kv.x + qreg[d4 * 4 + 1] * kv.y
                    + qreg[d4 * 4 + 2] * kv.z + qreg[d4 * 4 + 3] * kv.w;
            }
            dt += __shfl_xor(dt, 1);
            dt += __shfl_xor(dt, 2);
            sc[j] = (j0 + j < L) ? dt * scale : -1e30f;
            tmax = fmaxf(tmax, sc[j]);
        }

        // ---- single rescale per tile
        float mn = fmaxf(m, tmax);
        float corr = __expf(m - mn);
        m = mn;
        float ssum = 0.f;
#pragma unroll
        for (int j = 0; j < TK; j++) {
            sc[j] = __expf(sc[j] - m);         // p_j (0 for masked)
            ssum += sc[j];
        }
        s = s * corr + ssum;
#pragma unroll
        for (int d = 0; d < CH; d++) acc[d] *= corr;

        // ---- phase 2: PV
#pragma unroll
        for (int j = 0; j < TK; j++) {
            float p = sc[j];
#pragma unroll
            for (int d4 = 0; d4 < CH4; d4++) {
                float4 vv = *(const float4*)&Vs[j][c + d4 * 4];
                acc[d4 * 4 + 0] += p * vv.x;
                acc[d4 * 4 + 1] += p * vv.y;
                acc[d4 * 4 + 2] += p * vv.z;
                acc[d4 * 4 + 3] += p * vv.w;
            }
        }
    }
    if (q < L) {
        float inv = 1.f / s;
        bf16* op = O + hb + (size_t)q * dm + c;
#pragma unroll
        for (int d = 0; d < CH; d++) op[d] = __float2bfloat16(acc[d] * inv);
    }
}

// ---------------------------------------------------------------- pairing
__global__ __launch_bounds__(64) void find_second_kernel(const void* __restrict__ gious,
                                                         const void* __restrict__ cxcys,
                                                         size_t ebase,
                                                         int* __restrict__ second,
                                                         int* __restrict__ sel,
                                                         const int* __restrict__ flag) {
    int f = *flag;
    int gi = blockIdx.x;
    int b = gi / NQ_;
    int i = gi - b * NQ_;
    size_t rb = ebase + (size_t)b * NQ_ * NQ_ + (size_t)i * NQ_;
    int lane = threadIdx.x;
    float best = -1e30f;
    int bidx = 1 << 30;
    for (int j = lane; j < NQ_; j += 64) {
        if (j == i) continue;
        float v = ld(gious, rb + j, f);
        if (v > best) { best = v; bidx = j; }
    }
#pragma unroll
    for (int o = 32; o; o >>= 1) {
        float v2 = __shfl_xor(best, o);
        int i2 = __shfl_xor(bidx, o);
        if (v2 > best || (v2 == best && i2 < bidx)) { best = v2; bidx = i2; }
    }
    if (lane == 0) {
        second[gi] = b * NQ_ + bidx;
        float c = ld(cxcys, rb + bidx, f);
        sel[gi] = (c == 0.f) ? 1 : 0;
    }
}

__global__ __launch_bounds__(256) void build_pair_kernel(const bf16* __restrict__ X,
                                                         const bf16* __restrict__ Y,
                                                         const int* __restrict__ second,
                                                         const int* __restrict__ sel,
                                                         bf16* __restrict__ out2) {
    int e = blockIdx.x * 256 + threadIdx.x;
    int d = e & 255;
    int i = e >> 8;
    int s = sel[i];
    int j = second[i];
    bf16 a = X[(size_t)i * 256 + d];
    bf16 c = Y[(size_t)j * 256 + d];
    size_t o = (size_t)i * 512 + d;
    out2[o]       = s ? a : c;
    out2[o + 256] = s ? c : a;
}

// ---------------------------------------------------------------- block reduction (256 threads)
__device__ __forceinline__ float block_sum_256(float v, float* sm) {
#pragma unroll
    for (int o = 32; o; o >>= 1) v += __shfl_down(v, o);
    int w = threadIdx.x >> 6, lane = threadIdx.x & 63;
    if (lane == 0) sm[w] = v;
    __syncthreads();
    float r = sm[0] + sm[1] + sm[2] + sm[3];
    __syncthreads();
    return r;
}

__global__ __launch_bounds__(256) void ln_pair_kernel(const void* __restrict__ tgt,
                                                      const void* __restrict__ qpos,
                                                      size_t ebase,
                                                      const bf16* __restrict__ tgt2,
                                                      const bf16* __restrict__ tgt3full,
                                                      const int* __restrict__ sel,
                                                      const void* __restrict__ g1, const void* __restrict__ b1,
                                                      const void* __restrict__ g12, const void* __restrict__ b12,
                                                      float* __restrict__ xbuf,
                                                      bf16* __restrict__ query_d,
                                                      const int* __restrict__ flag) {
    __shared__ float sm[4];
    int f = *flag;
    int i = blockIdx.x, d = threadIdx.x;
    size_t base = (size_t)i * 256;
    float t = ld(tgt, ebase + base + d, f);
    float a1 = t + to_f(tgt2[base + d]);
    int s = sel[i];
    float t3 = to_f(tgt3full[(size_t)i * 512 + (s ? 0 : 256) + d]);
    float a2 = t + t3;
    float m1 = block_sum_256(a1, sm) * (1.f / 256.f);
    float m2 = block_sum_256(a2, sm) * (1.f / 256.f);
    float d1 = a1 - m1, d2 = a2 - m2;
    float v1 = block_sum_256(d1 * d1, sm) * (1.f / 256.f);
    float v2 = block_sum_256(d2 * d2, sm) * (1.f / 256.f);
    float o1 = d1 * rsqrtf(v1 + 1e-5f) * ld(g1, d, f) + ld(b1, d, f);
    float o2 = d2 * rsqrtf(v2 + 1e-5f) * ld(g12, d, f) + ld(b12, d, f);
    float xv = o1 + o2;
    xbuf[base + d] = xv;
    query_d[base + d] = __float2bfloat16(xv + ld(qpos, ebase + base + d, f));
}

// out_mode: 1 = ws f32 (oeb=0), 0 = d_out flag-typed at element base oeb.
// dual (optional): bf16 copy of the normalized output.
__global__ __launch_bounds__(256) void ln_add_kernel(const float* __restrict__ A,
                                                     const bf16* __restrict__ Badd,
                                                     const void* __restrict__ g, const void* __restrict__ be,
                                                     void* __restrict__ out, int out_mode, size_t oeb,
                                                     bf16* __restrict__ dual,
                                                     const int* __restrict__ flag) {
    __shared__ float sm[4];
    int f = *flag;
    int i = blockIdx.x, d = threadIdx.x;
    size_t base = (size_t)i * 256;
    float v = A[base + d] + to_f(Badd[base + d]);
    float m = block_sum_256(v, sm) * (1.f / 256.f);
    float dv = v - m;
    float var = block_sum_256(dv * dv, sm) * (1.f / 256.f);
    float o = dv * rsqrtf(var + 1e-5f) * ld(g, d, f) + ld(be, d, f);
    if (out_mode == 1) ((float*)out)[base + d] = o;
    else st_out(out, oeb + base + d, f, o);
    if (dual) dual[base + d] = __float2bfloat16(o);
}

// ---------------------------------------------------------------- deformable attention pieces
__global__ __launch_bounds__(128) void aw_softmax_kernel(float* __restrict__ aw,
                                                         void* __restrict__ out_aw, size_t oeb,
                                                         const int* __restrict__ flag) {
    int f = *flag;
    int i = blockIdx.x, t = threadIdx.x;
    size_t idx = (size_t)i * 128 + t;
    float v = aw[idx];
    float mx = v;
#pragma unroll
    for (int o = 8; o; o >>= 1) mx = fmaxf(mx, __shfl_xor(mx, o, 16));
    float e = __expf(v - mx);
    float s = e;
#pragma unroll
    for (int o = 8; o; o >>= 1) s += __shfl_xor(s, o, 16);
    float r = e / s;
    aw[idx] = r;
    st_out(out_aw, oeb + idx, f, r);
}

__global__ __launch_bounds__(256) void loc_kernel(const void* __restrict__ refp, size_t rbase,
                                                  const bf16* __restrict__ off,
                                                  float* __restrict__ locbuf,
                                                  void* __restrict__ out_loc, size_t oeb,
                                                  const int* __restrict__ flag) {
    int f = *flag;
    int e = blockIdx.x * 256 + threadIdx.x;  // [rows, H,L,P,2]
    int c = e & 1;
    int l = (e >> 3) & 3;
    int i = e >> 8;
    const float norm[4] = {100.f, 50.f, 25.f, 13.f};  // W == H per level
    float rv = ld(refp, rbase + ((size_t)i * 4 + l) * 2 + c, f);
    float lv = rv + to_f(off[e]) / norm[l];
    locbuf[e] = lv;
    st_out(out_loc, oeb + e, f, lv);
}

// one-time transpose of the value-projection weight into f32 [k][c] layout
__global__ __launch_bounds__(256) void transpose_vw_kernel(const void* __restrict__ vw,
                                                           float* __restrict__ vwt,
                                                           const int* __restrict__ flag) {
    int f = *flag;
    int e = blockIdx.x * 256 + threadIdx.x;   // 65536
    int k = e >> 8, c = e & 255;
    vwt[(size_t)k * 256 + c] = ld(vw, (size_t)c * 256 + k, f);
}

// Fused bilinear-sample + value-projection + attention-weighting.
// obf: 1 = samp written as bf16, 0 = f32.
__global__ __launch_bounds__(256) void deform_fused_kernel(const void* __restrict__ src, size_t sbase,
                                                           const float* __restrict__ vwt,
                                                           const void* __restrict__ vb,
                                                           const float* __restrict__ locb,
                                                           const float* __restrict__ awb,
                                                           void* __restrict__ samp, int obf,
                                                           const int* __restrict__ flag) {
    int f = *flag;
    int q = blockIdx.x;
    int b = q / NQ_;
    size_t srow = sbase + (size_t)b * LS_ * 256;
    int t = threadIdx.x;
    __shared__ float G[8][257];
    __shared__ int   rowi[128][4];
    __shared__ float wc[128][4];
    __shared__ float wv_s[128];
    __shared__ float aw_s[128];
    if (t < 128) {
        const int HW[4] = {100, 50, 25, 13};
        const int ST[4] = {0, 10000, 12500, 13125};
        int le = t;                       // h*16 + l*4 + p
        int l = (le >> 2) & 3;
        int W = HW[l], H = W, st = ST[l];
        float lx = locb[(size_t)q * 256 + le * 2];
        float ly = locb[(size_t)q * 256 + le * 2 + 1];
        float x = lx * W - 0.5f, y = ly * H - 0.5f;
        float xf = floorf(x), yf = floorf(y);
        int x0 = (int)xf, y0 = (int)yf;
        float wx1 = x - xf, wy1 = y - yf;
        float wx0 = 1.f - wx1, wy0 = 1.f - wy1;
        bool xv0 = (x0 >= 0) && (x0 < W), xv1 = (x0 + 1 >= 0) && (x0 + 1 < W);
        bool yv0 = (y0 >= 0) && (y0 < H), yv1 = (y0 + 1 >= 0) && (y0 + 1 < H);
        int cx0 = min(max(x0, 0), W - 1), cx1 = min(max(x0 + 1, 0), W - 1);
        int cy0 = min(max(y0, 0), H - 1), cy1 = min(max(y0 + 1, 0), H - 1);
        rowi[le][0] = st + cy0 * W + cx0;  wc[le][0] = (xv0 && yv0) ? wx0 * wy0 : 0.f;
        rowi[le][1] = st + cy0 * W + cx1;  wc[le][1] = (xv1 && yv0) ? wx1 * wy0 : 0.f;
        rowi[le][2] = st + cy1 * W + cx0;  wc[le][2] = (xv0 && yv1) ? wx0 * wy1 : 0.f;
        rowi[le][3] = st + cy1 * W + cx1;  wc[le][3] = (xv1 && yv1) ? wx1 * wy1 : 0.f;
        wv_s[le] = wc[le][0] + wc[le][1] + wc[le][2] + wc[le][3];
        aw_s[le] = awb[(size_t)q * 128 + le];
    }
    __syncthreads();
#pragma unroll
    for (int h = 0; h < 8; h++) {
        float g = 0.f;
#pragma unroll 4
        for (int le2 = 0; le2 < 16; le2++) {
            int le = h * 16 + le2;
            float a  = aw_s[le];
            float w0 = wc[le][0], w1 = wc[le][1], w2 = wc[le][2], w3 = wc[le][3];
            float v = w0 * ld(src, srow + (size_t)rowi[le][0] * 256 + t, f)
                    + w1 * ld(src, srow + (size_t)rowi[le][1] * 256 + t, f)
                    + w2 * ld(src, srow + (size_t)rowi[le][2] * 256 + t, f)
                    + w3 * ld(src, srow + (size_t)rowi[le][3] * 256 + t, f);
            g += a * v;
        }
        G[h][t] = g;
    }
    __syncthreads();
    int c = t, h = c >> 5;
    float bscale = 0.f;
#pragma unroll
    for (int r = 0; r < 16; r++) bscale += aw_s[h * 16 + r] * wv_s[h * 16 + r];
    float acc = bscale * ld(vb, c, f);
#pragma unroll 8
    for (int k = 0; k < 256; k++) acc += G[h][k] * vwt[(size_t)k * 256 + c];
    if (obf) ((bf16*)samp)[(size_t)q * 256 + c] = __float2bfloat16(acc);
    else     ((float*)samp)[(size_t)q * 256 + c] = acc;
}

// ================================================================ launch
extern "C" void kernel_launch(void* const* d_in, const int* in_sizes, int n_in,
                              void* d_out, int out_size, void* d_ws, size_t ws_size,
                              hipStream_t stream) {
    (void)in_sizes; (void)n_in; (void)out_size;
    void* out = d_out;
    const dim3 blk256(256);
    const int nQT = (NQ_ + 63) / 64;   // 15 query tiles for attention

    // ---------------- fully-batched path (needs 55,353,856 B of ws) ----------------
    if (ws_size >= 55353856ull) {
        char* base = (char*)d_ws;
        int*   flag   = (int*)base;                           // 256 B
        float* xbuf   = (float*)(base + 256);                 // NE f32   7,372,800
        bf16*  query  = (bf16*)(base + 7373056);              // NE bf16  3,686,400
        bf16*  qps    = (bf16*)(base + 11059456);             // NE bf16
        bf16*  tgt2   = (bf16*)(base + 14745856);             // NE bf16
        int*   second = (int*)(base + 18432256);              // 28,800 B
        int*   sel    = second + BS_ * NQ_;                   // 28,800 B
        char*  A      = base + 18489856;                      // arena, peak 36,864,000 B

        const int M = BS_ * NQ_;              // 7200
        const int gy = (M + 63) / 64;         // 113

        // ---- stage A (arena: 4 x 3,686,400 + tgtb)
        bf16* Q1   = (bf16*)A;
        bf16* K1   = (bf16*)(A + 3686400);
        bf16* V1   = (bf16*)(A + 7372800);
        bf16* att1 = (bf16*)(A + 11059200);
        bf16* tgtb = (bf16*)(A + 14745600);   // bf16 copy of tgt (dies at stage B)

        probe_kernel<<<1, blk256, 0, stream>>>((const unsigned short*)d_in[0], flag);
        prep_kernel<<<NE / 256, blk256, 0, stream>>>(d_in[0], d_in[1], 0, qps, tgtb, flag);

        gemm_mfma_kernel<false><<<dim3(4, gy), blk256, 0, stream>>>(qps, d_in[8], d_in[9], Q1, 0, M, 256, 256, flag);
        gemm_mfma_kernel<false><<<dim3(4, gy), blk256, 0, stream>>>(qps, d_in[10], d_in[11], K1, 0, M, 256, 256, flag);
        gemm_mfma_kernel<false><<<dim3(4, gy), blk256, 0, stream>>>(tgtb, d_in[12], d_in[13], V1, 0, M, 256, 256, flag);
        attn_tiled_kernel<32><<<dim3(nQT, NH_, BS_), blk256, 0, stream>>>(Q1, K1, V1, att1, NH_, NQ_, 0.17677669529663687f);
        gemm_mfma_kernel<false><<<dim3(4, gy), blk256, 0, stream>>>(att1, d_in[14], d_in[15], tgt2, 0, M, 256, 256, flag);

        // ---- stage B (arena: 4 x 7,372,800 B)
        bf16* pairX = (bf16*)A;               // then att2
        bf16* Q2    = (bf16*)(A + 7372800);   // then tgt3
        bf16* K2    = (bf16*)(A + 14745600);
        bf16* V2    = (bf16*)(A + 22118400);
        find_second_kernel<<<M, 64, 0, stream>>>(d_in[7], d_in[6], 0, second, sel, flag);
        build_pair_kernel<<<M, blk256, 0, stream>>>(qps, qps, second, sel, pairX);
        gemm_mfma_kernel<false><<<dim3(8, gy), blk256, 0, stream>>>(pairX, d_in[16], d_in[17], Q2, 0, M, 512, 512, flag);
        build_pair_kernel<<<M, blk256, 0, stream>>>(qps, tgt2, second, sel, pairX);
        gemm_mfma_kernel<false><<<dim3(8, gy), blk256, 0, stream>>>(pairX, d_in[18], d_in[19], K2, 0, M, 512, 512, flag);
        build_pair_kernel<<<M, blk256, 0, stream>>>(tgt2, tgt2, second, sel, pairX);
        gemm_mfma_kernel<false><<<dim3(8, gy), blk256, 0, stream>>>(pairX, d_in[20], d_in[21], V2, 0, M, 512, 512, flag);
        attn_tiled_kernel<64><<<dim3(nQT, NH_, BS_), blk256, 0, stream>>>(Q2, K2, V2, pairX, NH_, NQ_, 0.125f);
        gemm_mfma_kernel<false><<<dim3(8, gy), blk256, 0, stream>>>(pairX, d_in[22], d_in[23], Q2, 0, M, 512, 512, flag);

        ln_pair_kernel<<<M, blk256, 0, stream>>>(d_in[0], d_in[1], 0, tgt2, Q2, sel,
                                                 d_in[32], d_in[33], d_in[34], d_in[35], xbuf, query, flag);

        // ---- stage C (arena: offb | awb | locb | sampb | vwt)
        bf16*  offb  = (bf16*)A;                       //  3,686,400 B
        float* awb   = (float*)(A + 3686400);          //  3,686,400 B
        float* locb  = (float*)(A + 7372800);          //  7,372,800 B
        bf16*  sampb = (bf16*)(A + 14745600);          //  3,686,400 B (lives into stage D)
        float* vwt   = (float*)(A + 22118400);         //    262,144 B (dead before h1)
        gemm_mfma_kernel<false><<<dim3(4, gy), blk256, 0, stream>>>(query, d_in[26], d_in[27], offb, 0, M, 256, 256, flag);
        gemm_mfma_kernel<false><<<dim3(2, gy), blk256, 0, stream>>>(query, d_in[28], d_in[29], awb, 1, M, 128, 256, flag);
        aw_softmax_kernel<<<M, 128, 0, stream>>>(awb, out, (size_t)2 * NE, flag);
        loc_kernel<<<M, blk256, 0, stream>>>(d_in[2], 0, offb, locb, out, (size_t)NE, flag);
        transpose_vw_kernel<<<256, blk256, 0, stream>>>(d_in[24], vwt, flag);
        deform_fused_kernel<<<M, blk256, 0, stream>>>(d_in[3], 0, vwt, d_in[25], locb, awb, sampb, 1, flag);

        // ---- stage D (ca | x2 | ffn | [sampb] | x2b | h1)
        bf16*  ca  = (bf16*)A;                         //  3,686,400 B
        float* x2  = (float*)(A + 3686400);            //  7,372,800 B (ends 11,059,200)
        bf16*  ffn = (bf16*)(A + 11059200);            //  3,686,400 B (ends 14,745,600)
        bf16*  x2b = (bf16*)(A + 18432000);            //  3,686,400 B (ends 22,118,400)
        bf16*  h1  = (bf16*)(A + 22118400);            // 14,745,600 B (after vwt dead)
        gemm_mfma_kernel<false><<<dim3(4, gy), blk256, 0, stream>>>(sampb, d_in[30], d_in[31], ca, 0, M, 256, 256, flag);
        ln_add_kernel<<<M, blk256, 0, stream>>>(xbuf, ca, d_in[32], d_in[33], x2, 1, 0, x2b, flag);
        gemm_mfma_kernel<true><<<dim3(16, gy), blk256, 0, stream>>>(x2b, d_in[38], d_in[39], h1, 0, M, 1024, 256, flag);
        gemm_mfma_kernel<false><<<dim3(4, gy), blk256, 0, stream>>>(h1, d_in[40], d_in[41], ffn, 0, M, 256, 1024, flag);
        ln_add_kernel<<<M, blk256, 0, stream>>>(x2, ffn, d_in[36], d_in[37], out, 0, 0, nullptr, flag);
        return;
    }

    // ---------------- fallback: per-batch loop (needs 6,920,448 B of ws) ----------------
    {
        char* base = (char*)d_ws;
        int*   flag   = (int*)base;                         // 256 B
        float* xbuf   = (float*)(base + 256);               // NEb f32   921,600 B
        bf16*  query  = (bf16*)(base + 256 + 921600);       // NEb bf16  460,800 B
        bf16*  qps    = (bf16*)(base + 256 + 1382400);      // NEb bf16
        bf16*  tgt2   = (bf16*)(base + 256 + 1843200);      // NEb bf16
        int*   second = (int*)(base + 256 + 2304000);       // 3,600 B
        int*   sel    = second + NQ_;                       // 3,600 B
        char*  A      = base + 2312448;                     // arena, peak 4,608,000 B

        const int gyb = (NQ_ + 63) / 64;   // 15

        probe_kernel<<<1, blk256, 0, stream>>>((const unsigned short*)d_in[0], flag);

        for (int b = 0; b < BS_; b++) {
            const size_t o_tgt  = (size_t)b * NEb;
            const size_t o_refp = (size_t)b * NQ_ * 8;
            const size_t o_src  = (size_t)b * LS_ * 256;
            const size_t o_gc   = (size_t)b * NQ_ * NQ_;
            const size_t o_outx = (size_t)b * NEb;
            const size_t o_loc  = (size_t)NE + (size_t)b * NEb;
            const size_t o_aw   = (size_t)2 * NE + (size_t)b * AWb;

            // ---- stage A
            bf16* Q1   = (bf16*)A;
            bf16* K1   = (bf16*)(A + 460800);
            bf16* V1   = (bf16*)(A + 921600);
            bf16* att1 = (bf16*)(A + 1382400);
            bf16* tgtb = (bf16*)(A + 1843200);
            prep_kernel<<<NEb / 256, blk256, 0, stream>>>(d_in[0], d_in[1], o_tgt, qps, tgtb, flag);
            gemm_kernel<false><<<dim3(4, gyb), blk256, 0, stream>>>(qps, 0, 0, d_in[8], d_in[9], Q1, 0, NQ_, 256, 256, flag);
            gemm_kernel<false><<<dim3(4, gyb), blk256, 0, stream>>>(qps, 0, 0, d_in[10], d_in[11], K1, 0, NQ_, 256, 256, flag);
            gemm_kernel<false><<<dim3(4, gyb), blk256, 0, stream>>>(d_in[0], 1, o_tgt, d_in[12], d_in[13], V1, 0, NQ_, 256, 256, flag);
            attn_tiled_kernel<32><<<dim3(gyb, NH_, 1), blk256, 0, stream>>>(Q1, K1, V1, att1, NH_, NQ_, 0.17677669529663687f);
            gemm_kernel<false><<<dim3(4, gyb), blk256, 0, stream>>>(att1, 0, 0, d_in[14], d_in[15], tgt2, 0, NQ_, 256, 256, flag);

            // ---- stage B
            bf16* pairX = (bf16*)A;
            bf16* Q2    = (bf16*)(A + 921600);
            bf16* K2    = (bf16*)(A + 1843200);
            bf16* V2    = (bf16*)(A + 2764800);
            find_second_kernel<<<NQ_, 64, 0, stream>>>(d_in[7], d_in[6], o_gc, second, sel, flag);
            build_pair_kernel<<<NQ_, blk256, 0, stream>>>(qps, qps, second, sel, pairX);
            gemm_kernel<false><<<dim3(8, gyb), blk256, 0, stream>>>(pairX, 0, 0, d_in[16], d_in[17], Q2, 0, NQ_, 512, 512, flag);
            build_pair_kernel<<<NQ_, blk256, 0, stream>>>(qps, tgt2, second, sel, pairX);
            gemm_kernel<false><<<dim3(8, gyb), blk256, 0, stream>>>(pairX, 0, 0, d_in[18], d_in[19], K2, 0, NQ_, 512, 512, flag);
            build_pair_kernel<<<NQ_, blk256, 0, stream>>>(tgt2, tgt2, second, sel, pairX);
            gemm_kernel<false><<<dim3(8, gyb), blk256, 0, stream>>>(pairX, 0, 0, d_in[20], d_in[21], V2, 0, NQ_, 512, 512, flag);
            attn_tiled_kernel<64><<<dim3(gyb, NH_, 1), blk256, 0, stream>>>(Q2, K2, V2, pairX, NH_, NQ_, 0.125f);
            gemm_kernel<false><<<dim3(8, gyb), blk256, 0, stream>>>(pairX, 0, 0, d_in[22], d_in[23], Q2, 0, NQ_, 512, 512, flag);

            ln_pair_kernel<<<NQ_, blk256, 0, stream>>>(d_in[0], d_in[1], o_tgt, tgt2, Q2, sel,
                                                       d_in[32], d_in[33], d_in[34], d_in[35], xbuf, query, flag);

            // ---- stage C
            bf16*  offb = (bf16*)A;
            float* awb  = (float*)(A + 460800);
            float* locb = (float*)(A + 921600);
            float* samp = (float*)(A + 1843200);
            float* vwt  = (float*)(A + 2764800);        // 262,144 B, dead before stage D h1
            gemm_kernel<false><<<dim3(4, gyb), blk256, 0, stream>>>(query, 0, 0, d_in[26], d_in[27], offb, 0, NQ_, 256, 256, flag);
            gemm_kernel<false><<<dim3(2, gyb), blk256, 0, stream>>>(query, 0, 0, d_in[28], d_in[29], awb, 1, NQ_, 128, 256, flag);
            aw_softmax_kernel<<<NQ_, 128, 0, stream>>>(awb, out, o_aw, flag);
            loc_kernel<<<NQ_, blk256, 0, stream>>>(d_in[2], o_refp, offb, locb, out, o_loc, flag);
            transpose_vw_kernel<<<256, blk256, 0, stream>>>(d_in[24], vwt, flag);
            deform_fused_kernel<<<NQ_, blk256, 0, stream>>>(d_in[3], o_src, vwt, d_in[25], locb, awb, samp, 0, flag);

            // ---- stage D
            bf16*  ca  = (bf16*)A;
            float* x2  = (float*)(A + 460800);
            bf16*  ffn = (bf16*)(A + 1382400);
            bf16*  h1  = (bf16*)(A + 2764800);
            gemm_kernel<false><<<dim3(4, gyb), blk256, 0, stream>>>(samp, 2, 0, d_in[30], d_in[31], ca, 0, NQ_, 256, 256, flag);
            ln_add_kernel<<<NQ_, blk256, 0, stream>>>(xbuf, ca, d_in[32], d_in[33], x2, 1, 0, nullptr, flag);
            gemm_kernel<true><<<dim3(16, gyb), blk256, 0, stream>>>(x2, 2, 0, d_in[38], d_in[39], h1, 0, NQ_, 1024, 256, flag);
            gemm_kernel<false><<<dim3(4, gyb), blk256, 0, stream>>>(h1, 0, 0, d_in[40], d_in[41], ffn, 0, NQ_, 256, 1024, flag);
            ln_add_kernel<<<NQ_, blk256, 0, stream>>>(x2, ffn, d_in[36], d_in[37], out, 0, o_outx, nullptr, flag);
        }
    }
}

// Round 7
// 888.608 us; speedup vs baseline: 7.6272x; 1.6200x over previous
//
#include <hip/hip_runtime.h>
#include <hip/hip_bf16.h>

#define D_   256
#define NH_  8
#define NL_  4
#define NP_  4
#define DFF_ 1024
#define BS_  8
#define NQ_  900
#define HD_  32
#define LS_  13294

static const int NE   = BS_ * NQ_ * D_;   // 1,843,200
static const int NEb  = NQ_ * D_;         //   230,400
static const int AWb  = NQ_ * 128;        //   115,200

typedef __hip_bfloat16 bf16;
typedef __attribute__((ext_vector_type(8))) short s8v;   // 8 bf16 (4 VGPRs)
typedef __attribute__((ext_vector_type(4))) float f4v;   // 4 f32 acc

__device__ __forceinline__ float to_f(bf16 x) { return __bfloat162float(x); }
__device__ __forceinline__ float us_to_f(unsigned short u) {
    return __uint_as_float((unsigned)u << 16);   // bf16 -> f32 is a shift
}
__device__ __forceinline__ float ld(const void* p, size_t i, int f32) {
    return f32 ? ((const float*)p)[i] : __bfloat162float(((const bf16*)p)[i]);
}
__device__ __forceinline__ void st_out(void* p, size_t i, int f32, float v) {
    if (f32) ((float*)p)[i] = v;
    else ((bf16*)p)[i] = __float2bfloat16(v);
}
__device__ __forceinline__ unsigned short f_to_us(float v) {
    return __bfloat16_as_ushort(__float2bfloat16(v));
}

// ---------------------------------------------------------------- dtype probe
__global__ __launch_bounds__(256) void probe_kernel(const unsigned short* __restrict__ t,
                                                    int* __restrict__ flag) {
    __shared__ int c;
    if (threadIdx.x == 0) c = 0;
    __syncthreads();
    unsigned short v = t[2 * threadIdx.x];   // even bf16-view slots
    int e = (v >> 7) & 0xFF;
    if (e < 90 || e > 140) atomicAdd(&c, 1); // implausible exponent for N(0,1)
    __syncthreads();
    if (threadIdx.x == 0) flag[0] = (c > 64) ? 1 : 0;  // 1 => storage is f32
}

// ---------------------------------------------------------------- prep: qps = tgt + qpos; tgtb = bf16(tgt)
__global__ __launch_bounds__(256) void prep_kernel(const void* __restrict__ tgt,
                                                   const void* __restrict__ qpos,
                                                   size_t ebase,
                                                   bf16* __restrict__ qps,
                                                   bf16* __restrict__ tgtb,
                                                   const int* __restrict__ flag) {
    int f = *flag;
    int e = blockIdx.x * 256 + threadIdx.x;
    float t = ld(tgt, ebase + e, f);
    qps[e] = __float2bfloat16(t + ld(qpos, ebase + e, f));
    tgtb[e] = __float2bfloat16(t);
}

// ---------------------------------------------------------------- MFMA GEMM: C[M,N] = A[M,K] @ W[N,K]^T + bias
template <bool RELU>
__global__ __launch_bounds__(256) void gemm_mfma_kernel(const bf16* __restrict__ A,
                                                        const void* __restrict__ W,
                                                        const void* __restrict__ bias,
                                                        void* __restrict__ C, int c_f32,
                                                        int M, int N, int K,
                                                        const int* __restrict__ flag) {
    __shared__ short As[64][40];   // stride 40 shorts = 80B: 16B-aligned rows
    __shared__ short Ws[64][40];
    int f = *flag;
    int tid = threadIdx.x;
    int wave = tid >> 6, lane = tid & 63;
    int wr = wave >> 1, wc = wave & 1;           // wave 2x2 position
    int row0 = blockIdx.y * 64, col0 = blockIdx.x * 64;
    int srow = tid >> 2;                          // staging row 0..63
    int schunk = (tid & 3) * 8;                   // staging k-chunk 0/8/16/24
    int fr = lane & 15, fg = lane >> 4;           // fragment row/col + group
    int fk = fg * 8;                              // fragment k offset

    f4v acc00 = {0.f, 0.f, 0.f, 0.f};
    f4v acc01 = {0.f, 0.f, 0.f, 0.f};
    f4v acc10 = {0.f, 0.f, 0.f, 0.f};
    f4v acc11 = {0.f, 0.f, 0.f, 0.f};

    for (int k0 = 0; k0 < K; k0 += 32) {
        {
            int gr = row0 + srow;
            int ar = (gr < M) ? gr : (M - 1);
            const ushort* ap = (const ushort*)A + (size_t)ar * K + k0 + schunk;
            *(ushort4*)&As[srow][schunk]     = *(const ushort4*)ap;
            *(ushort4*)&As[srow][schunk + 4] = *(const ushort4*)(ap + 4);
            int gc = col0 + srow;                 // N multiple of 64
            if (f) {
                const float* wp = (const float*)W + (size_t)gc * K + k0 + schunk;
                float4 w0 = *(const float4*)wp;
                float4 w1 = *(const float4*)(wp + 4);
                ushort4 h0, h1;
                h0.x = f_to_us(w0.x); h0.y = f_to_us(w0.y); h0.z = f_to_us(w0.z); h0.w = f_to_us(w0.w);
                h1.x = f_to_us(w1.x); h1.y = f_to_us(w1.y); h1.z = f_to_us(w1.z); h1.w = f_to_us(w1.w);
                *(ushort4*)&Ws[srow][schunk]     = h0;
                *(ushort4*)&Ws[srow][schunk + 4] = h1;
            } else {
                const ushort* wp = (const ushort*)W + (size_t)gc * K + k0 + schunk;
                *(ushort4*)&Ws[srow][schunk]     = *(const ushort4*)wp;
                *(ushort4*)&Ws[srow][schunk + 4] = *(const ushort4*)(wp + 4);
            }
        }
        __syncthreads();
        s8v a0 = *(const s8v*)&As[wr * 32 + fr][fk];
        s8v a1 = *(const s8v*)&As[wr * 32 + 16 + fr][fk];
        s8v b0 = *(const s8v*)&Ws[wc * 32 + fr][fk];
        s8v b1 = *(const s8v*)&Ws[wc * 32 + 16 + fr][fk];
        acc00 = __builtin_amdgcn_mfma_f32_16x16x32_bf16(a0, b0, acc00, 0, 0, 0);
        acc01 = __builtin_amdgcn_mfma_f32_16x16x32_bf16(a0, b1, acc01, 0, 0, 0);
        acc10 = __builtin_amdgcn_mfma_f32_16x16x32_bf16(a1, b0, acc10, 0, 0, 0);
        acc11 = __builtin_amdgcn_mfma_f32_16x16x32_bf16(a1, b1, acc11, 0, 0, 0);
        __syncthreads();
    }

    int cA = col0 + wc * 32 + fr;
    int cB = cA + 16;
    float bvA = ld(bias, cA, f);
    float bvB = ld(bias, cB, f);
#pragma unroll
    for (int i = 0; i < 2; i++) {
        int rbase = row0 + wr * 32 + i * 16 + fg * 4;
        f4v vj0 = (i == 0) ? acc00 : acc10;
        f4v vj1 = (i == 0) ? acc01 : acc11;
#pragma unroll
        for (int r = 0; r < 4; r++) {
            int row = rbase + r;
            if (row >= M) continue;
            float v0 = vj0[r] + bvA;
            float v1 = vj1[r] + bvB;
            if (RELU) { v0 = fmaxf(v0, 0.f); v1 = fmaxf(v1, 0.f); }
            if (c_f32) {
                ((float*)C)[(size_t)row * N + cA] = v0;
                ((float*)C)[(size_t)row * N + cB] = v1;
            } else {
                ((bf16*)C)[(size_t)row * N + cA] = __float2bfloat16(v0);
                ((bf16*)C)[(size_t)row * N + cB] = __float2bfloat16(v1);
            }
        }
    }
}

// ---------------------------------------------------------------- MFMA flash attention
// Block = 256 thr (4 waves); wave handles 16 queries over all keys in 32-key LDS tiles.
// S^T = mfma(K_frag, Q_frag): D col=lane&15=q, row=(lane>>4)*4+r = key -> lane owns 8 scores of one q.
// Online softmax: partners (lane xor 16/32) share q. P->bf16 in per-wave LDS [q][k] (stride 40).
// O^T += mfma(V^T_frag, P_frag): V^T via strided Vs reads (stride HD+2 -> 2-way banks, free);
// P_frag is one contiguous ds_read_b128. D col=q, row=d.
template <int HD>
__global__ __launch_bounds__(256) void attn_mfma_kernel(const bf16* __restrict__ Q,
                                                        const bf16* __restrict__ K,
                                                        const bf16* __restrict__ V,
                                                        bf16* __restrict__ O,
                                                        int H, int L, float scale) {
    constexpr int NS   = HD / 32;       // S^T k-steps (1 or 2)
    constexpr int NDB  = HD / 16;       // PV d-blocks (2 or 4)
    constexpr int KSTR = HD + 8;        // Ks row stride (shorts), 16B-multiple
    constexpr int VSTR = HD + 2;        // Vs row stride (shorts)
    constexpr int STH  = 4 * HD;        // staging threads (128 or 256)
    constexpr int RPT  = HD / 8;        // staging threads per key
    const int dm = H * HD;
    __shared__ short Ks[32 * KSTR];
    __shared__ short Vs[32 * VSTR];
    __shared__ short Ps[4][16 * 40];
    int tile = blockIdx.x, h = blockIdx.y, b = blockIdx.z;
    size_t hb = (size_t)b * L * dm + (size_t)h * HD;
    int tid = threadIdx.x;
    int w = tid >> 6, lane = tid & 63;
    int fr = lane & 15, g = lane >> 4;
    int q = tile * 64 + w * 16 + fr;
    int qr = (q < L) ? q : (L - 1);

    s8v qf[NS];
    {
        const short* qp = (const short*)Q + hb + (size_t)qr * dm + g * 8;
#pragma unroll
        for (int s = 0; s < NS; s++) qf[s] = *(const s8v*)(qp + s * 32);
    }
    f4v acc[NDB];
#pragma unroll
    for (int d = 0; d < NDB; d++) acc[d] = f4v{0.f, 0.f, 0.f, 0.f};
    float m = -1e30f, ssum = 0.f;

    int skey = tid / RPT;
    int sd0 = (tid % RPT) * 8;
    short* pw = &Ps[w][0];

    for (int k0 = 0; k0 < L; k0 += 32) {
        __syncthreads();   // protect prior-iteration reads
        if (tid < STH) {
            int gk = k0 + skey; if (gk >= L) gk = L - 1;
            const ushort* kp = (const ushort*)K + hb + (size_t)gk * dm + sd0;
            const ushort* vp = (const ushort*)V + hb + (size_t)gk * dm + sd0;
            ushort4 ka = *(const ushort4*)kp;
            ushort4 kb = *(const ushort4*)(kp + 4);
            ushort4 va = *(const ushort4*)vp;
            ushort4 vb = *(const ushort4*)(vp + 4);
            *(ushort4*)&Ks[skey * KSTR + sd0]     = ka;
            *(ushort4*)&Ks[skey * KSTR + sd0 + 4] = kb;
            ushort* vd = (ushort*)&Vs[skey * VSTR + sd0];   // 4B-aligned (VSTR even)
            *(ushort2*)(vd + 0) = make_ushort2(va.x, va.y);
            *(ushort2*)(vd + 2) = make_ushort2(va.z, va.w);
            *(ushort2*)(vd + 4) = make_ushort2(vb.x, vb.y);
            *(ushort2*)(vd + 6) = make_ushort2(vb.z, vb.w);
        }
        __syncthreads();

        // ---- S^T fragments (2 key-frags of 16)
        f4v s0 = {0.f, 0.f, 0.f, 0.f}, s1 = {0.f, 0.f, 0.f, 0.f};
#pragma unroll
        for (int s = 0; s < NS; s++) {
            s8v a0 = *(const s8v*)&Ks[fr * KSTR + s * 32 + g * 8];
            s8v a1 = *(const s8v*)&Ks[(16 + fr) * KSTR + s * 32 + g * 8];
            s0 = __builtin_amdgcn_mfma_f32_16x16x32_bf16(a0, qf[s], s0, 0, 0, 0);
            s1 = __builtin_amdgcn_mfma_f32_16x16x32_bf16(a1, qf[s], s1, 0, 0, 0);
        }

        // ---- masked scaled scores; online softmax (lane owns q=fr, keys g*4+r / +16)
        float sc[8];
        int kg = k0 + g * 4;
#pragma unroll
        for (int r = 0; r < 4; r++) {
            sc[r]     = (kg + r < L)      ? s0[r] * scale : -1e30f;
            sc[4 + r] = (kg + 16 + r < L) ? s1[r] * scale : -1e30f;
        }
        float mx = sc[0];
#pragma unroll
        for (int r = 1; r < 8; r++) mx = fmaxf(mx, sc[r]);
        mx = fmaxf(mx, __shfl_xor(mx, 16));
        mx = fmaxf(mx, __shfl_xor(mx, 32));
        float mn = fmaxf(m, mx);
        float corr = __expf(m - mn);
        float p[8];
        float psum = 0.f;
#pragma unroll
        for (int r = 0; r < 8; r++) { p[r] = __expf(sc[r] - mn); psum += p[r]; }
        psum += __shfl_xor(psum, 16);
        psum += __shfl_xor(psum, 32);
        ssum = ssum * corr + psum;
        m = mn;
#pragma unroll
        for (int d = 0; d < NDB; d++) acc[d] *= corr;

        // ---- P (bf16) -> per-wave LDS [q][k]
#pragma unroll
        for (int r = 0; r < 4; r++) {
            pw[fr * 40 + g * 4 + r]      = (short)f_to_us(p[r]);
            pw[fr * 40 + 16 + g * 4 + r] = (short)f_to_us(p[4 + r]);
        }

        // ---- PV: O^T[d][q] += V^T x P
        s8v pf = *(const s8v*)&pw[fr * 40 + g * 8];
#pragma unroll
        for (int db = 0; db < NDB; db++) {
            s8v vt;
#pragma unroll
            for (int i = 0; i < 8; i++)
                vt[i] = Vs[(g * 8 + i) * VSTR + db * 16 + fr];
            acc[db] = __builtin_amdgcn_mfma_f32_16x16x32_bf16(vt, pf, acc[db], 0, 0, 0);
        }
    }

    // ---- epilogue: lane writes O[q][db*16 + g*4 .. +3]
    if (q < L) {
        float inv = 1.f / ssum;
        short* op = (short*)O + hb + (size_t)q * dm + g * 4;
#pragma unroll
        for (int db = 0; db < NDB; db++) {
            ushort4 o4;
            o4.x = f_to_us(acc[db][0] * inv);
            o4.y = f_to_us(acc[db][1] * inv);
            o4.z = f_to_us(acc[db][2] * inv);
            o4.w = f_to_us(acc[db][3] * inv);
            *(ushort4*)(op + db * 16) = o4;
        }
    }
}

// ---------------------------------------------------------------- legacy FP32 GEMM (fallback path only)
template <bool RELU>
__global__ __launch_bounds__(256) void gemm_kernel(const void* __restrict__ A, int a_dyn, size_t aeb,
                                                   const void* __restrict__ W,
                                                   const void* __restrict__ bias,
                                                   void* __restrict__ C, int c_f32,
                                                   int M, int N, int K,
                                                   const int* __restrict__ flag) {
    __shared__ float As[16][68];
    __shared__ float Ws[16][68];
    int f = *flag;
    int a_f32 = (a_dyn == 2) || (a_dyn == 1 && f);
    int tid = threadIdx.x;
    int tx = tid & 15, ty = tid >> 4;
    int row0 = blockIdx.y * 64, col0 = blockIdx.x * 64;
    float acc[4][4] = {};
    for (int k0 = 0; k0 < K; k0 += 16) {
#pragma unroll
        for (int t = 0; t < 4; t++) {
            int e = tid + t * 256;
            int m = e >> 4, kk = e & 15;
            int gr = row0 + m;
            As[kk][m] = (gr < M) ? ld(A, aeb + (size_t)gr * K + k0 + kk, a_f32) : 0.f;
            int gc = col0 + m;  // N multiple of 64
            Ws[kk][m] = ld(W, (size_t)gc * K + k0 + kk, f);
        }
        __syncthreads();
#pragma unroll
        for (int kk = 0; kk < 16; kk++) {
            float4 a4 = *(const float4*)&As[kk][ty * 4];
            float4 b4 = *(const float4*)&Ws[kk][tx * 4];
            float a[4] = {a4.x, a4.y, a4.z, a4.w};
            float b[4] = {b4.x, b4.y, b4.z, b4.w};
#pragma unroll
            for (int i = 0; i < 4; i++)
#pragma unroll
                for (int j = 0; j < 4; j++) acc[i][j] += a[i] * b[j];
        }
        __syncthreads();
    }
    int cbase = col0 + tx * 4;
    float bs[4];
#pragma unroll
    for (int j = 0; j < 4; j++) bs[j] = ld(bias, cbase + j, f);
#pragma unroll
    for (int i = 0; i < 4; i++) {
        int r = row0 + ty * 4 + i;
        if (r >= M) continue;
        float v[4];
#pragma unroll
        for (int j = 0; j < 4; j++) {
            v[j] = acc[i][j] + bs[j];
            if (RELU) v[j] = fmaxf(v[j], 0.f);
        }
        if (c_f32) {
            *(float4*)&((float*)C)[(size_t)r * N + cbase] = make_float4(v[0], v[1], v[2], v[3]);
        } else {
            ushort4 h;
            h.x = f_to_us(v[0]); h.y = f_to_us(v[1]); h.z = f_to_us(v[2]); h.w = f_to_us(v[3]);
            *(ushort4*)&((bf16*)C)[(size_t)r * N + cbase] = h;
        }
    }
}

// ---------------------------------------------------------------- tiled flash attention (fallback path)
template <int HD>
__global__ __launch_bounds__(256) void attn_tiled_kernel(const bf16* __restrict__ Q,
                                                         const bf16* __restrict__ K,
                                                         const bf16* __restrict__ V,
                                                         bf16* __restrict__ O,
                                                         int H, int L, float scale) {
    constexpr int CH  = HD / 4;
    constexpr int CH4 = CH / 4;
    constexpr int TK  = 32;
    constexpr int NC4 = TK * HD / 4;
    const int dm = H * HD;
    __shared__ float Ks[TK][HD];
    __shared__ float Vs[TK][HD];
    int tile = blockIdx.x, h = blockIdx.y, b = blockIdx.z;
    size_t hb = (size_t)b * L * dm + h * HD;
    int tid = threadIdx.x;
    int lane = tid & 63, wave = tid >> 6;
    int qi = wave * 16 + (lane >> 2);
    int q = tile * 64 + qi;
    int c = (lane & 3) * CH;
    int qrow = min(q, L - 1);
    float qreg[CH];
    {
        const bf16* qp = Q + hb + (size_t)qrow * dm + c;
#pragma unroll
        for (int d = 0; d < CH; d++) qreg[d] = to_f(qp[d]);
    }
    float m = -1e30f, s = 0.f;
    float acc[CH] = {};

    for (int j0 = 0; j0 < L; j0 += TK) {
        __syncthreads();
#pragma unroll
        for (int ci = tid; ci < NC4; ci += 256) {
            int e0 = ci * 4;
            int srow = e0 / HD, scol = e0 % HD;
            int gr = j0 + srow;
            if (gr >= L) gr = L - 1;
            ushort4 ku = *(const ushort4*)(K + hb + (size_t)gr * dm + scol);
            ushort4 vu = *(const ushort4*)(V + hb + (size_t)gr * dm + scol);
            *(float4*)&Ks[srow][scol] = make_float4(us_to_f(ku.x), us_to_f(ku.y), us_to_f(ku.z), us_to_f(ku.w));
            *(float4*)&Vs[srow][scol] = make_float4(us_to_f(vu.x), us_to_f(vu.y), us_to_f(vu.z), us_to_f(vu.w));
        }
        __syncthreads();

        float sc[TK];
        float tmax = -1e30f;
#pragma unroll
        for (int j = 0; j < TK; j++) {
            float dt = 0.f;
#pragma unroll
            for (int d4 = 0; d4 < CH4; d4++) {
                float4 kv = *(const float4*)&Ks[j][c + d4 * 4];
                dt += qreg[d4 * 4 + 0] * kv.x + qreg[d4 * 4 + 1] * kv.y
                    + qreg[d4 * 4 + 2] * kv.z + qreg[d4 * 4 + 3] * kv.w;
            }
            dt += __shfl_xor(dt, 1);
            dt += __shfl_xor(dt, 2);
            sc[j] = (j0 + j < L) ? dt * scale : -1e30f;
            tmax = fmaxf(tmax, sc[j]);
        }

        float mn = fmaxf(m, tmax);
        float corr = __expf(m - mn);
        m = mn;
        float ssum = 0.f;
#pragma unroll
        for (int j = 0; j < TK; j++) {
            sc[j] = __expf(sc[j] - m);
            ssum += sc[j];
        }
        s = s * corr + ssum;
#pragma unroll
        for (int d = 0; d < CH; d++) acc[d] *= corr;

#pragma unroll
        for (int j = 0; j < TK; j++) {
            float p = sc[j];
#pragma unroll
            for (int d4 = 0; d4 < CH4; d4++) {
                float4 vv = *(const float4*)&Vs[j][c + d4 * 4];
                acc[d4 * 4 + 0] += p * vv.x;
                acc[d4 * 4 + 1] += p * vv.y;
                acc[d4 * 4 + 2] += p * vv.z;
                acc[d4 * 4 + 3] += p * vv.w;
            }
        }
    }
    if (q < L) {
        float inv = 1.f / s;
        bf16* op = O + hb + (size_t)q * dm + c;
#pragma unroll
        for (int d = 0; d < CH; d++) op[d] = __float2bfloat16(acc[d] * inv);
    }
}

// ---------------------------------------------------------------- pairing
__global__ __launch_bounds__(64) void find_second_kernel(const void* __restrict__ gious,
                                                         const void* __restrict__ cxcys,
                                                         size_t ebase,
                                                         int* __restrict__ second,
                                                         int* __restrict__ sel,
                                                         const int* __restrict__ flag) {
    int f = *flag;
    int gi = blockIdx.x;
    int b = gi / NQ_;
    int i = gi - b * NQ_;
    size_t rb = ebase + (size_t)b * NQ_ * NQ_ + (size_t)i * NQ_;
    int lane = threadIdx.x;
    float best = -1e30f;
    int bidx = 1 << 30;
    for (int j = lane; j < NQ_; j += 64) {
        if (j == i) continue;
        float v = ld(gious, rb + j, f);
        if (v > best) { best = v; bidx = j; }
    }
#pragma unroll
    for (int o = 32; o; o >>= 1) {
        float v2 = __shfl_xor(best, o);
        int i2 = __shfl_xor(bidx, o);
        if (v2 > best || (v2 == best && i2 < bidx)) { best = v2; bidx = i2; }
    }
    if (lane == 0) {
        second[gi] = b * NQ_ + bidx;
        float c = ld(cxcys, rb + bidx, f);
        sel[gi] = (c == 0.f) ? 1 : 0;
    }
}

__global__ __launch_bounds__(256) void build_pair_kernel(const bf16* __restrict__ X,
                                                         const bf16* __restrict__ Y,
                                                         const int* __restrict__ second,
                                                         const int* __restrict__ sel,
                                                         bf16* __restrict__ out2) {
    int e = blockIdx.x * 256 + threadIdx.x;
    int d = e & 255;
    int i = e >> 8;
    int s = sel[i];
    int j = second[i];
    bf16 a = X[(size_t)i * 256 + d];
    bf16 c = Y[(size_t)j * 256 + d];
    size_t o = (size_t)i * 512 + d;
    out2[o]       = s ? a : c;
    out2[o + 256] = s ? c : a;
}

// ---------------------------------------------------------------- block reduction (256 threads)
__device__ __forceinline__ float block_sum_256(float v, float* sm) {
#pragma unroll
    for (int o = 32; o; o >>= 1) v += __shfl_down(v, o);
    int w = threadIdx.x >> 6, lane = threadIdx.x & 63;
    if (lane == 0) sm[w] = v;
    __syncthreads();
    float r = sm[0] + sm[1] + sm[2] + sm[3];
    __syncthreads();
    return r;
}

__global__ __launch_bounds__(256) void ln_pair_kernel(const void* __restrict__ tgt,
                                                      const void* __restrict__ qpos,
                                                      size_t ebase,
                                                      const bf16* __restrict__ tgt2,
                                                      const bf16* __restrict__ tgt3full,
                                                      const int* __restrict__ sel,
                                                      const void* __restrict__ g1, const void* __restrict__ b1,
                                                      const void* __restrict__ g12, const void* __restrict__ b12,
                                                      float* __restrict__ xbuf,
                                                      bf16* __restrict__ query_d,
                                                      const int* __restrict__ flag) {
    __shared__ float sm[4];
    int f = *flag;
    int i = blockIdx.x, d = threadIdx.x;
    size_t base = (size_t)i * 256;
    float t = ld(tgt, ebase + base + d, f);
    float a1 = t + to_f(tgt2[base + d]);
    int s = sel[i];
    float t3 = to_f(tgt3full[(size_t)i * 512 + (s ? 0 : 256) + d]);
    float a2 = t + t3;
    float m1 = block_sum_256(a1, sm) * (1.f / 256.f);
    float m2 = block_sum_256(a2, sm) * (1.f / 256.f);
    float d1 = a1 - m1, d2 = a2 - m2;
    float v1 = block_sum_256(d1 * d1, sm) * (1.f / 256.f);
    float v2 = block_sum_256(d2 * d2, sm) * (1.f / 256.f);
    float o1 = d1 * rsqrtf(v1 + 1e-5f) * ld(g1, d, f) + ld(b1, d, f);
    float o2 = d2 * rsqrtf(v2 + 1e-5f) * ld(g12, d, f) + ld(b12, d, f);
    float xv = o1 + o2;
    xbuf[base + d] = xv;
    query_d[base + d] = __float2bfloat16(xv + ld(qpos, ebase + base + d, f));
}

__global__ __launch_bounds__(256) void ln_add_kernel(const float* __restrict__ A,
                                                     const bf16* __restrict__ Badd,
                                                     const void* __restrict__ g, const void* __restrict__ be,
                                                     void* __restrict__ out, int out_mode, size_t oeb,
                                                     bf16* __restrict__ dual,
                                                     const int* __restrict__ flag) {
    __shared__ float sm[4];
    int f = *flag;
    int i = blockIdx.x, d = threadIdx.x;
    size_t base = (size_t)i * 256;
    float v = A[base + d] + to_f(Badd[base + d]);
    float m = block_sum_256(v, sm) * (1.f / 256.f);
    float dv = v - m;
    float var = block_sum_256(dv * dv, sm) * (1.f / 256.f);
    float o = dv * rsqrtf(var + 1e-5f) * ld(g, d, f) + ld(be, d, f);
    if (out_mode == 1) ((float*)out)[base + d] = o;
    else st_out(out, oeb + base + d, f, o);
    if (dual) dual[base + d] = __float2bfloat16(o);
}

// ---------------------------------------------------------------- deformable attention pieces
__global__ __launch_bounds__(128) void aw_softmax_kernel(float* __restrict__ aw,
                                                         void* __restrict__ out_aw, size_t oeb,
                                                         const int* __restrict__ flag) {
    int f = *flag;
    int i = blockIdx.x, t = threadIdx.x;
    size_t idx = (size_t)i * 128 + t;
    float v = aw[idx];
    float mx = v;
#pragma unroll
    for (int o = 8; o; o >>= 1) mx = fmaxf(mx, __shfl_xor(mx, o, 16));
    float e = __expf(v - mx);
    float s = e;
#pragma unroll
    for (int o = 8; o; o >>= 1) s += __shfl_xor(s, o, 16);
    float r = e / s;
    aw[idx] = r;
    st_out(out_aw, oeb + idx, f, r);
}

__global__ __launch_bounds__(256) void loc_kernel(const void* __restrict__ refp, size_t rbase,
                                                  const bf16* __restrict__ off,
                                                  float* __restrict__ locbuf,
                                                  void* __restrict__ out_loc, size_t oeb,
                                                  const int* __restrict__ flag) {
    int f = *flag;
    int e = blockIdx.x * 256 + threadIdx.x;
    int c = e & 1;
    int l = (e >> 3) & 3;
    int i = e >> 8;
    const float norm[4] = {100.f, 50.f, 25.f, 13.f};
    float rv = ld(refp, rbase + ((size_t)i * 4 + l) * 2 + c, f);
    float lv = rv + to_f(off[e]) / norm[l];
    locbuf[e] = lv;
    st_out(out_loc, oeb + e, f, lv);
}

__global__ __launch_bounds__(256) void transpose_vw_kernel(const void* __restrict__ vw,
                                                           float* __restrict__ vwt,
                                                           const int* __restrict__ flag) {
    int f = *flag;
    int e = blockIdx.x * 256 + threadIdx.x;   // 65536
    int k = e >> 8, c = e & 255;
    vwt[(size_t)k * 256 + c] = ld(vw, (size_t)c * 256 + k, f);
}

__global__ __launch_bounds__(256) void deform_fused_kernel(const void* __restrict__ src, size_t sbase,
                                                           const float* __restrict__ vwt,
                                                           const void* __restrict__ vb,
                                                           const float* __restrict__ locb,
                                                           const float* __restrict__ awb,
                                                           void* __restrict__ samp, int obf,
                                                           const int* __restrict__ flag) {
    int f = *flag;
    int q = blockIdx.x;
    int b = q / NQ_;
    size_t srow = sbase + (size_t)b * LS_ * 256;
    int t = threadIdx.x;
    __shared__ float G[8][257];
    __shared__ int   rowi[128][4];
    __shared__ float wc[128][4];
    __shared__ float wv_s[128];
    __shared__ float aw_s[128];
    if (t < 128) {
        const int HW[4] = {100, 50, 25, 13};
        const int ST[4] = {0, 10000, 12500, 13125};
        int le = t;
        int l = (le >> 2) & 3;
        int W = HW[l], H = W, st = ST[l];
        float lx = locb[(size_t)q * 256 + le * 2];
        float ly = locb[(size_t)q * 256 + le * 2 + 1];
        float x = lx * W - 0.5f, y = ly * H - 0.5f;
        float xf = floorf(x), yf = floorf(y);
        int x0 = (int)xf, y0 = (int)yf;
        float wx1 = x - xf, wy1 = y - yf;
        float wx0 = 1.f - wx1, wy0 = 1.f - wy1;
        bool xv0 = (x0 >= 0) && (x0 < W), xv1 = (x0 + 1 >= 0) && (x0 + 1 < W);
        bool yv0 = (y0 >= 0) && (y0 < H), yv1 = (y0 + 1 >= 0) && (y0 + 1 < H);
        int cx0 = min(max(x0, 0), W - 1), cx1 = min(max(x0 + 1, 0), W - 1);
        int cy0 = min(max(y0, 0), H - 1), cy1 = min(max(y0 + 1, 0), H - 1);
        rowi[le][0] = st + cy0 * W + cx0;  wc[le][0] = (xv0 && yv0) ? wx0 * wy0 : 0.f;
        rowi[le][1] = st + cy0 * W + cx1;  wc[le][1] = (xv1 && yv0) ? wx1 * wy0 : 0.f;
        rowi[le][2] = st + cy1 * W + cx0;  wc[le][2] = (xv0 && yv1) ? wx0 * wy1 : 0.f;
        rowi[le][3] = st + cy1 * W + cx1;  wc[le][3] = (xv1 && yv1) ? wx1 * wy1 : 0.f;
        wv_s[le] = wc[le][0] + wc[le][1] + wc[le][2] + wc[le][3];
        aw_s[le] = awb[(size_t)q * 128 + le];
    }
    __syncthreads();
#pragma unroll
    for (int h = 0; h < 8; h++) {
        float g = 0.f;
#pragma unroll 4
        for (int le2 = 0; le2 < 16; le2++) {
            int le = h * 16 + le2;
            float a  = aw_s[le];
            float w0 = wc[le][0], w1 = wc[le][1], w2 = wc[le][2], w3 = wc[le][3];
            float v = w0 * ld(src, srow + (size_t)rowi[le][0] * 256 + t, f)
                    + w1 * ld(src, srow + (size_t)rowi[le][1] * 256 + t, f)
                    + w2 * ld(src, srow + (size_t)rowi[le][2] * 256 + t, f)
                    + w3 * ld(src, srow + (size_t)rowi[le][3] * 256 + t, f);
            g += a * v;
        }
        G[h][t] = g;
    }
    __syncthreads();
    int c = t, h = c >> 5;
    float bscale = 0.f;
#pragma unroll
    for (int r = 0; r < 16; r++) bscale += aw_s[h * 16 + r] * wv_s[h * 16 + r];
    float acc = bscale * ld(vb, c, f);
#pragma unroll 8
    for (int k = 0; k < 256; k++) acc += G[h][k] * vwt[(size_t)k * 256 + c];
    if (obf) ((bf16*)samp)[(size_t)q * 256 + c] = __float2bfloat16(acc);
    else     ((float*)samp)[(size_t)q * 256 + c] = acc;
}

// ================================================================ launch
extern "C" void kernel_launch(void* const* d_in, const int* in_sizes, int n_in,
                              void* d_out, int out_size, void* d_ws, size_t ws_size,
                              hipStream_t stream) {
    (void)in_sizes; (void)n_in; (void)out_size;
    void* out = d_out;
    const dim3 blk256(256);
    const int nQT = (NQ_ + 63) / 64;   // 15 query tiles for attention

    // ---------------- fully-batched path (needs 55,353,856 B of ws) ----------------
    if (ws_size >= 55353856ull) {
        char* base = (char*)d_ws;
        int*   flag   = (int*)base;                           // 256 B
        float* xbuf   = (float*)(base + 256);                 // NE f32   7,372,800
        bf16*  query  = (bf16*)(base + 7373056);              // NE bf16  3,686,400
        bf16*  qps    = (bf16*)(base + 11059456);             // NE bf16
        bf16*  tgt2   = (bf16*)(base + 14745856);             // NE bf16
        int*   second = (int*)(base + 18432256);              // 28,800 B
        int*   sel    = second + BS_ * NQ_;                   // 28,800 B
        char*  A      = base + 18489856;                      // arena, peak 36,864,000 B

        const int M = BS_ * NQ_;              // 7200
        const int gy = (M + 63) / 64;         // 113

        // ---- stage A
        bf16* Q1   = (bf16*)A;
        bf16* K1   = (bf16*)(A + 3686400);
        bf16* V1   = (bf16*)(A + 7372800);
        bf16* att1 = (bf16*)(A + 11059200);
        bf16* tgtb = (bf16*)(A + 14745600);   // bf16 copy of tgt (dies at stage B)

        probe_kernel<<<1, blk256, 0, stream>>>((const unsigned short*)d_in[0], flag);
        prep_kernel<<<NE / 256, blk256, 0, stream>>>(d_in[0], d_in[1], 0, qps, tgtb, flag);

        gemm_mfma_kernel<false><<<dim3(4, gy), blk256, 0, stream>>>(qps, d_in[8], d_in[9], Q1, 0, M, 256, 256, flag);
        gemm_mfma_kernel<false><<<dim3(4, gy), blk256, 0, stream>>>(qps, d_in[10], d_in[11], K1, 0, M, 256, 256, flag);
        gemm_mfma_kernel<false><<<dim3(4, gy), blk256, 0, stream>>>(tgtb, d_in[12], d_in[13], V1, 0, M, 256, 256, flag);
        attn_mfma_kernel<32><<<dim3(nQT, NH_, BS_), blk256, 0, stream>>>(Q1, K1, V1, att1, NH_, NQ_, 0.17677669529663687f);
        gemm_mfma_kernel<false><<<dim3(4, gy), blk256, 0, stream>>>(att1, d_in[14], d_in[15], tgt2, 0, M, 256, 256, flag);

        // ---- stage B
        bf16* pairX = (bf16*)A;               // then att2
        bf16* Q2    = (bf16*)(A + 7372800);   // then tgt3
        bf16* K2    = (bf16*)(A + 14745600);
        bf16* V2    = (bf16*)(A + 22118400);
        find_second_kernel<<<M, 64, 0, stream>>>(d_in[7], d_in[6], 0, second, sel, flag);
        build_pair_kernel<<<M, blk256, 0, stream>>>(qps, qps, second, sel, pairX);
        gemm_mfma_kernel<false><<<dim3(8, gy), blk256, 0, stream>>>(pairX, d_in[16], d_in[17], Q2, 0, M, 512, 512, flag);
        build_pair_kernel<<<M, blk256, 0, stream>>>(qps, tgt2, second, sel, pairX);
        gemm_mfma_kernel<false><<<dim3(8, gy), blk256, 0, stream>>>(pairX, d_in[18], d_in[19], K2, 0, M, 512, 512, flag);
        build_pair_kernel<<<M, blk256, 0, stream>>>(tgt2, tgt2, second, sel, pairX);
        gemm_mfma_kernel<false><<<dim3(8, gy), blk256, 0, stream>>>(pairX, d_in[20], d_in[21], V2, 0, M, 512, 512, flag);
        attn_mfma_kernel<64><<<dim3(nQT, NH_, BS_), blk256, 0, stream>>>(Q2, K2, V2, pairX, NH_, NQ_, 0.125f);
        gemm_mfma_kernel<false><<<dim3(8, gy), blk256, 0, stream>>>(pairX, d_in[22], d_in[23], Q2, 0, M, 512, 512, flag);

        ln_pair_kernel<<<M, blk256, 0, stream>>>(d_in[0], d_in[1], 0, tgt2, Q2, sel,
                                                 d_in[32], d_in[33], d_in[34], d_in[35], xbuf, query, flag);

        // ---- stage C
        bf16*  offb  = (bf16*)A;                       //  3,686,400 B
        float* awb   = (float*)(A + 3686400);          //  3,686,400 B
        float* locb  = (float*)(A + 7372800);          //  7,372,800 B
        bf16*  sampb = (bf16*)(A + 14745600);          //  3,686,400 B (lives into stage D)
        float* vwt   = (float*)(A + 22118400);         //    262,144 B (dead before h1)
        gemm_mfma_kernel<false><<<dim3(4, gy), blk256, 0, stream>>>(query, d_in[26], d_in[27], offb, 0, M, 256, 256, flag);
        gemm_mfma_kernel<false><<<dim3(2, gy), blk256, 0, stream>>>(query, d_in[28], d_in[29], awb, 1, M, 128, 256, flag);
        aw_softmax_kernel<<<M, 128, 0, stream>>>(awb, out, (size_t)2 * NE, flag);
        loc_kernel<<<M, blk256, 0, stream>>>(d_in[2], 0, offb, locb, out, (size_t)NE, flag);
        transpose_vw_kernel<<<256, blk256, 0, stream>>>(d_in[24], vwt, flag);
        deform_fused_kernel<<<M, blk256, 0, stream>>>(d_in[3], 0, vwt, d_in[25], locb, awb, sampb, 1, flag);

        // ---- stage D
        bf16*  ca  = (bf16*)A;                         //  3,686,400 B
        float* x2  = (float*)(A + 3686400);            //  7,372,800 B
        bf16*  ffn = (bf16*)(A + 11059200);            //  3,686,400 B
        bf16*  x2b = (bf16*)(A + 18432000);            //  3,686,400 B
        bf16*  h1  = (bf16*)(A + 22118400);            // 14,745,600 B
        gemm_mfma_kernel<false><<<dim3(4, gy), blk256, 0, stream>>>(sampb, d_in[30], d_in[31], ca, 0, M, 256, 256, flag);
        ln_add_kernel<<<M, blk256, 0, stream>>>(xbuf, ca, d_in[32], d_in[33], x2, 1, 0, x2b, flag);
        gemm_mfma_kernel<true><<<dim3(16, gy), blk256, 0, stream>>>(x2b, d_in[38], d_in[39], h1, 0, M, 1024, 256, flag);
        gemm_mfma_kernel<false><<<dim3(4, gy), blk256, 0, stream>>>(h1, d_in[40], d_in[41], ffn, 0, M, 256, 1024, flag);
        ln_add_kernel<<<M, blk256, 0, stream>>>(x2, ffn, d_in[36], d_in[37], out, 0, 0, nullptr, flag);
        return;
    }

    // ---------------- fallback: per-batch loop (needs 6,920,448 B of ws) ----------------
    {
        char* base = (char*)d_ws;
        int*   flag   = (int*)base;                         // 256 B
        float* xbuf   = (float*)(base + 256);               // NEb f32   921,600 B
        bf16*  query  = (bf16*)(base + 256 + 921600);       // NEb bf16  460,800 B
        bf16*  qps    = (bf16*)(base + 256 + 1382400);      // NEb bf16
        bf16*  tgt2   = (bf16*)(base + 256 + 1843200);      // NEb bf16
        int*   second = (int*)(base + 256 + 2304000);       // 3,600 B
        int*   sel    = second + NQ_;                       // 3,600 B
        char*  A      = base + 2312448;                     // arena, peak 4,608,000 B

        const int gyb = (NQ_ + 63) / 64;   // 15

        probe_kernel<<<1, blk256, 0, stream>>>((const unsigned short*)d_in[0], flag);

        for (int b = 0; b < BS_; b++) {
            const size_t o_tgt  = (size_t)b * NEb;
            const size_t o_refp = (size_t)b * NQ_ * 8;
            const size_t o_src  = (size_t)b * LS_ * 256;
            const size_t o_gc   = (size_t)b * NQ_ * NQ_;
            const size_t o_outx = (size_t)b * NEb;
            const size_t o_loc  = (size_t)NE + (size_t)b * NEb;
            const size_t o_aw   = (size_t)2 * NE + (size_t)b * AWb;

            // ---- stage A
            bf16* Q1   = (bf16*)A;
            bf16* K1   = (bf16*)(A + 460800);
            bf16* V1   = (bf16*)(A + 921600);
            bf16* att1 = (bf16*)(A + 1382400);
            bf16* tgtb = (bf16*)(A + 1843200);
            prep_kernel<<<NEb / 256, blk256, 0, stream>>>(d_in[0], d_in[1], o_tgt, qps, tgtb, flag);
            gemm_kernel<false><<<dim3(4, gyb), blk256, 0, stream>>>(qps, 0, 0, d_in[8], d_in[9], Q1, 0, NQ_, 256, 256, flag);
            gemm_kernel<false><<<dim3(4, gyb), blk256, 0, stream>>>(qps, 0, 0, d_in[10], d_in[11], K1, 0, NQ_, 256, 256, flag);
            gemm_kernel<false><<<dim3(4, gyb), blk256, 0, stream>>>(d_in[0], 1, o_tgt, d_in[12], d_in[13], V1, 0, NQ_, 256, 256, flag);
            attn_tiled_kernel<32><<<dim3(gyb, NH_, 1), blk256, 0, stream>>>(Q1, K1, V1, att1, NH_, NQ_, 0.17677669529663687f);
            gemm_kernel<false><<<dim3(4, gyb), blk256, 0, stream>>>(att1, 0, 0, d_in[14], d_in[15], tgt2, 0, NQ_, 256, 256, flag);

            // ---- stage B
            bf16* pairX = (bf16*)A;
            bf16* Q2    = (bf16*)(A + 921600);
            bf16* K2    = (bf16*)(A + 1843200);
            bf16* V2    = (bf16*)(A + 2764800);
            find_second_kernel<<<NQ_, 64, 0, stream>>>(d_in[7], d_in[6], o_gc, second, sel, flag);
            build_pair_kernel<<<NQ_, blk256, 0, stream>>>(qps, qps, second, sel, pairX);
            gemm_kernel<false><<<dim3(8, gyb), blk256, 0, stream>>>(pairX, 0, 0, d_in[16], d_in[17], Q2, 0, NQ_, 512, 512, flag);
            build_pair_kernel<<<NQ_, blk256, 0, stream>>>(qps, tgt2, second, sel, pairX);
            gemm_kernel<false><<<dim3(8, gyb), blk256, 0, stream>>>(pairX, 0, 0, d_in[18], d_in[19], K2, 0, NQ_, 512, 512, flag);
            build_pair_kernel<<<NQ_, blk256, 0, stream>>>(tgt2, tgt2, second, sel, pairX);
            gemm_kernel<false><<<dim3(8, gyb), blk256, 0, stream>>>(pairX, 0, 0, d_in[20], d_in[21], V2, 0, NQ_, 512, 512, flag);
            attn_tiled_kernel<64><<<dim3(gyb, NH_, 1), blk256, 0, stream>>>(Q2, K2, V2, pairX, NH_, NQ_, 0.125f);
            gemm_kernel<false><<<dim3(8, gyb), blk256, 0, stream>>>(pairX, 0, 0, d_in[22], d_in[23], Q2, 0, NQ_, 512, 512, flag);

            ln_pair_kernel<<<NQ_, blk256, 0, stream>>>(d_in[0], d_in[1], o_tgt, tgt2, Q2, sel,
                                                       d_in[32], d_in[33], d_in[34], d_in[35], xbuf, query, flag);

            // ---- stage C
            bf16*  offb = (bf16*)A;
            float* awb  = (float*)(A + 460800);
            float* locb = (float*)(A + 921600);
            float* samp = (float*)(A + 1843200);
            float* vwt  = (float*)(A + 2764800);        // 262,144 B, dead before stage D h1
            gemm_kernel<false><<<dim3(4, gyb), blk256, 0, stream>>>(query, 0, 0, d_in[26], d_in[27], offb, 0, NQ_, 256, 256, flag);
            gemm_kernel<false><<<dim3(2, gyb), blk256, 0, stream>>>(query, 0, 0, d_in[28], d_in[29], awb, 1, NQ_, 128, 256, flag);
            aw_softmax_kernel<<<NQ_, 128, 0, stream>>>(awb, out, o_aw, flag);
            loc_kernel<<<NQ_, blk256, 0, stream>>>(d_in[2], o_refp, offb, locb, out, o_loc, flag);
            transpose_vw_kernel<<<256, blk256, 0, stream>>>(d_in[24], vwt, flag);
            deform_fused_kernel<<<NQ_, blk256, 0, stream>>>(d_in[3], o_src, vwt, d_in[25], locb, awb, samp, 0, flag);

            // ---- stage D
            bf16*  ca  = (bf16*)A;
            float* x2  = (float*)(A + 460800);
            bf16*  ffn = (bf16*)(A + 1382400);
            bf16*  h1  = (bf16*)(A + 2764800);
            gemm_kernel<false><<<dim3(4, gyb), blk256, 0, stream>>>(samp, 2, 0, d_in[30], d_in[31], ca, 0, NQ_, 256, 256, flag);
            ln_add_kernel<<<NQ_, blk256, 0, stream>>>(xbuf, ca, d_in[32], d_in[33], x2, 1, 0, nullptr, flag);
            gemm_kernel<true><<<dim3(16, gyb), blk256, 0, stream>>>(x2, 2, 0, d_in[38], d_in[39], h1, 0, NQ_, 1024, 256, flag);
            gemm_kernel<false><<<dim3(4, gyb), blk256, 0, stream>>>(h1, 0, 0, d_in[40], d_in[41], ffn, 0, NQ_, 256, 1024, flag);
            ln_add_kernel<<<NQ_, blk256, 0, stream>>>(x2, ffn, d_in[36], d_in[37], out, 0, o_outx, nullptr, flag);
        }
    }
}